// Round 6
// baseline (13293.282 us; speedup 1.0000x reference)
//
#include <hip/hip_runtime.h>
#include <math.h>

#define NB 4
#define NE 64
#define BE 256          // NB*NE
#define LAT 256
#define NC 512          // channels == window
#define NT 128          // n_frames
#define NDEF 65536      // NC*NT
#define NIMP 4096
#define NF 16           // impulse frames
#define EPSN 1e-8f
#define SPB 4           // sequences per scan block
#define NSCAN 64        // scan blocks (BE/SPB)

typedef unsigned short ushort8 __attribute__((ext_vector_type(8)));
typedef short short8v __attribute__((ext_vector_type(8)));
typedef float f32x4 __attribute__((ext_vector_type(4)));

__device__ __forceinline__ unsigned short f2bf(float f) {
  const unsigned u = __float_as_uint(f);
  return (unsigned short)((u + 0x7FFFu + ((u >> 16) & 1u)) >> 16);  // RNE
}

// ---------------------------------------------------------------------------
// single-barrier block reduction: 512 threads each contribute v[NR]; every
// thread gets the block sum in out[NR]. red is a flat >=8*NR float buffer.
// Caller must ensure no other use of `red` races (alternate buffers).
// ---------------------------------------------------------------------------
template <int NR>
__device__ __forceinline__ void blk_reduce1(const float* v, float* out,
                                            float* red) {
  const int tid = threadIdx.x, wave = tid >> 6, lane = tid & 63;
  float s[NR];
#pragma unroll
  for (int i = 0; i < NR; ++i) s[i] = v[i];
#pragma unroll
  for (int off = 32; off; off >>= 1) {
#pragma unroll
    for (int i = 0; i < NR; ++i) s[i] += __shfl_down(s[i], off);
  }
  if (lane == 0) {
#pragma unroll
    for (int i = 0; i < NR; ++i) red[wave * NR + i] = s[i];
  }
  __syncthreads();
#pragma unroll
  for (int i = 0; i < NR; ++i) {
    float a = 0.f;
#pragma unroll
    for (int w = 0; w < 8; ++w) a += red[w * NR + i];
    out[i] = a;
  }
}

// ---------------------------------------------------------------------------
// K0: swizzle Ws_lat (4 x [512 k][512 n] f32) into LANE-MAJOR MFMA B-frag
// order, bf16 (R3's proven L1/L2-friendly per-lane-contiguous stream):
//   Wmf[ (layer*8+wv)*32768 + lane*512 + (kt*4+p)*8 + j ]
//     = bf16( W[layer][kt*32 + (lane>>4)*8 + j][wv*64 + p*16 + (lane&15)] )
// Each lane of wave wv streams 64 consecutive 16B fragments (1KB contiguous);
// every 128B line serves 8 consecutive loads of one lane -> L1 reuse x8.
// grid 2048 (= ((layer*8+wv)*16+kt)*4+p), block 64.
// ---------------------------------------------------------------------------
__global__ __launch_bounds__(64) void k_cvt(const float* __restrict__ W,
                                            unsigned short* __restrict__ Wmf) {
  const int lane = threadIdx.x;
  const int gg = blockIdx.x;
  const int p = gg & 3;
  const int kt = (gg >> 2) & 15;
  const int wv = (gg >> 6) & 7;
  const int layer = gg >> 9;
  const int col = wv * 64 + p * 16 + (lane & 15);
  const int k0 = kt * 32 + (lane >> 4) * 8;
  ushort8 o;
#pragma unroll
  for (int j = 0; j < 8; ++j)
    o[j] = f2bf(W[((size_t)layer * NC + k0 + j) * NC + col]);
  *reinterpret_cast<ushort8*>(Wmf + (size_t)(layer * 8 + wv) * 32768 +
                              lane * 512 + (kt * 4 + p) * 8) = o;
}

// ---------------------------------------------------------------------------
// K1: deform = embedding @ W_def + b_def      (256 x 256) @ (256 x 65536)
// ---------------------------------------------------------------------------
__global__ __launch_bounds__(256) void k_deform(
    const float* __restrict__ emb, const float* __restrict__ Wd,
    const float* __restrict__ bd, float* __restrict__ deform) {
  __shared__ float As[32][LAT];
  const int tid = threadIdx.x;
  const int c = blockIdx.x * 256 + tid;
  const int m0 = blockIdx.y * 32;
  for (int i = 0; i < 32; ++i) As[i][tid] = emb[(m0 + i) * LAT + tid];
  __syncthreads();
  float acc[32];
#pragma unroll
  for (int i = 0; i < 32; ++i) acc[i] = 0.f;
  for (int k = 0; k < LAT; k += 4) {
    const float w0 = Wd[(size_t)(k + 0) * NDEF + c];
    const float w1 = Wd[(size_t)(k + 1) * NDEF + c];
    const float w2 = Wd[(size_t)(k + 2) * NDEF + c];
    const float w3 = Wd[(size_t)(k + 3) * NDEF + c];
#pragma unroll
    for (int i = 0; i < 32; ++i) {
      const float4 a = *reinterpret_cast<const float4*>(&As[i][k]);
      acc[i] = fmaf(a.x, w0, acc[i]);
      acc[i] = fmaf(a.y, w1, acc[i]);
      acc[i] = fmaf(a.z, w2, acc[i]);
      acc[i] = fmaf(a.w, w3, acc[i]);
    }
  }
  const float bv = bd[c];
  for (int i = 0; i < 32; ++i)
    deform[(size_t)(m0 + i) * NDEF + c] = acc[i] + bv;
}

// ---------------------------------------------------------------------------
// K2: per-(be,t) rows of deform: unit_norm over channel dim, then
//   weights = x @ W_w + b_w ; biases = x @ W_b + b_b ; leak = sigmoid path.
// ---------------------------------------------------------------------------
__global__ __launch_bounds__(512) void k_wb(
    const float* __restrict__ deform, const float* __restrict__ Ww,
    const float* __restrict__ bw, const float* __restrict__ Wb,
    const float* __restrict__ bb, const float* __restrict__ Wl,
    const float* __restrict__ bl, float* __restrict__ weights,
    float* __restrict__ biases, float* __restrict__ leak) {
  __shared__ float xs[16][NC];
  __shared__ float rno[16], lks[16];
  const int tid = threadIdx.x;
  const int wave = tid >> 6, lane = tid & 63;
  const int be = blockIdx.x >> 3;
  const int t0 = (blockIdx.x & 7) * 16;
  const float* dbase = deform + (size_t)be * NDEF;
  for (int i = 0; i < 16; ++i)
    xs[i][tid] = dbase[(size_t)tid * NT + t0 + i];
  __syncthreads();
  for (int f = wave; f < 16; f += 8) {
    float s = 0.f;
#pragma unroll
    for (int j = 0; j < 8; ++j) {
      const float v = xs[f][lane + 64 * j];
      s = fmaf(v, v, s);
    }
#pragma unroll
    for (int off = 32; off; off >>= 1) s += __shfl_down(s, off);
    if (lane == 0) rno[f] = sqrtf(s);
  }
  __syncthreads();
#pragma unroll
  for (int i = 0; i < 16; ++i) xs[i][tid] = xs[i][tid] / (rno[i] + EPSN);
  __syncthreads();
  for (int f = wave; f < 16; f += 8) {
    float s = 0.f;
#pragma unroll
    for (int j = 0; j < 8; ++j)
      s = fmaf(xs[f][lane + 64 * j], Wl[lane + 64 * j], s);
#pragma unroll
    for (int off = 32; off; off >>= 1) s += __shfl_down(s, off);
    if (lane == 0) lks[f] = s;
  }
  __syncthreads();
  if (tid < 16) {
    const float v = lks[tid] + bl[0];
    leak[(size_t)be * NT + t0 + tid] = 0.1f + 0.98f / (1.f + expf(-v));
  }
  float accw[16], accb[16];
#pragma unroll
  for (int i = 0; i < 16; ++i) { accw[i] = 0.f; accb[i] = 0.f; }
  for (int k = 0; k < NC; k += 2) {
    const float w0 = Ww[(size_t)k * NC + tid];
    const float w1 = Ww[(size_t)(k + 1) * NC + tid];
    const float v0 = Wb[(size_t)k * NC + tid];
    const float v1 = Wb[(size_t)(k + 1) * NC + tid];
#pragma unroll
    for (int i = 0; i < 16; ++i) {
      const float2 a = *reinterpret_cast<const float2*>(&xs[i][k]);
      accw[i] = fmaf(a.x, w0, accw[i]);
      accw[i] = fmaf(a.y, w1, accw[i]);
      accb[i] = fmaf(a.x, v0, accb[i]);
      accb[i] = fmaf(a.y, v1, accb[i]);
    }
  }
  const float bwv = bw[tid], bbv = bb[tid];
  for (int i = 0; i < 16; ++i) {
    const size_t o = ((size_t)be * NT + t0 + i) * NC + tid;
    weights[o] = accw[i] + bwv;
    biases[o] = accb[i] + bbv;
  }
}

// ---------------------------------------------------------------------------
// 16-row tile x (512x512) GEMM helper: xs[16][512] in LDS, thread = column.
// ---------------------------------------------------------------------------
__device__ __forceinline__ void tile_gemm16(const float (*xs)[NC],
                                            const float* __restrict__ W,
                                            int tid, float acc[16]) {
#pragma unroll
  for (int i = 0; i < 16; ++i) acc[i] = 0.f;
  for (int k = 0; k < NC; k += 4) {
    const float w0 = W[(size_t)(k + 0) * NC + tid];
    const float w1 = W[(size_t)(k + 1) * NC + tid];
    const float w2 = W[(size_t)(k + 2) * NC + tid];
    const float w3 = W[(size_t)(k + 3) * NC + tid];
#pragma unroll
    for (int i = 0; i < 16; ++i) {
      const float4 a = *reinterpret_cast<const float4*>(&xs[i][k]);
      acc[i] = fmaf(a.x, w0, acc[i]);
      acc[i] = fmaf(a.y, w1, acc[i]);
      acc[i] = fmaf(a.z, w2, acc[i]);
      acc[i] = fmaf(a.w, w3, acc[i]);
    }
  }
}

// LN (+leaky) stats applied in-place on xs[16][NC]
__device__ __forceinline__ void ln_leaky16(float (*xs)[NC],
                                           const float* __restrict__ g,
                                           const float* __restrict__ bt,
                                           int layer, int tid, float* mu_s,
                                           float* rs_s) {
  const int wave = tid >> 6, lane = tid & 63;
  for (int f = wave; f < 16; f += 8) {
    float s = 0.f, s2 = 0.f;
#pragma unroll
    for (int j = 0; j < 8; ++j) {
      const float v = xs[f][lane + 64 * j];
      s += v;
      s2 = fmaf(v, v, s2);
    }
#pragma unroll
    for (int off = 32; off; off >>= 1) {
      s += __shfl_down(s, off);
      s2 += __shfl_down(s2, off);
    }
    if (lane == 0) {
      const float mu = s * (1.f / NC);
      mu_s[f] = mu;
      rs_s[f] = rsqrtf(s2 * (1.f / NC) - mu * mu + 1e-5f);
    }
  }
  __syncthreads();
  const float gv = g[layer * NC + tid], btv = bt[layer * NC + tid];
#pragma unroll
  for (int i = 0; i < 16; ++i) {
    const float y = (xs[i][tid] - mu_s[i]) * rs_s[i] * gv + btv;
    xs[i][tid] = y > 0.f ? y : 0.2f * y;
  }
  __syncthreads();
}

// ---------------------------------------------------------------------------
// K3: windowed impulse -> mlp_imp -> unit_norm * window-norm -> emb stream.
// ---------------------------------------------------------------------------
__global__ __launch_bounds__(512) void k_imp(
    const float* __restrict__ impulse, const float* __restrict__ Ws,
    const float* __restrict__ bs, const float* __restrict__ g,
    const float* __restrict__ bt, float* __restrict__ embo) {
  __shared__ float xs[16][NC];
  __shared__ float wno[16], mu_s[16], rs_s[16], ono[16];
  const int tid = threadIdx.x;
  const int wave = tid >> 6, lane = tid & 63;
  const int be = blockIdx.x;
  const float* ib = impulse + (size_t)be * NIMP;
  for (int f = 0; f < 16; ++f) {
    const int s = f * 256 + tid;
    xs[f][tid] = (s < NIMP) ? ib[s] : 0.f;
  }
  __syncthreads();
  for (int f = wave; f < 16; f += 8) {
    float s = 0.f;
#pragma unroll
    for (int j = 0; j < 8; ++j) {
      const float v = xs[f][lane + 64 * j];
      s = fmaf(v, v, s);
    }
#pragma unroll
    for (int off = 32; off; off >>= 1) s += __shfl_down(s, off);
    if (lane == 0) wno[f] = sqrtf(s);
  }
  __syncthreads();
  float acc[16];
  for (int layer = 0; layer < 4; ++layer) {
    tile_gemm16(xs, Ws + (size_t)layer * NC * NC, tid, acc);
    __syncthreads();
    const float bv = bs[layer * NC + tid];
#pragma unroll
    for (int i = 0; i < 16; ++i) xs[i][tid] = acc[i] + bv;
    __syncthreads();
    if (layer < 3) ln_leaky16(xs, g, bt, layer, tid, mu_s, rs_s);
  }
  for (int f = wave; f < 16; f += 8) {
    float s = 0.f;
#pragma unroll
    for (int j = 0; j < 8; ++j) {
      const float v = xs[f][lane + 64 * j];
      s = fmaf(v, v, s);
    }
#pragma unroll
    for (int off = 32; off; off >>= 1) s += __shfl_down(s, off);
    if (lane == 0) ono[f] = sqrtf(s);
  }
  __syncthreads();
  for (int f = 0; f < 16; ++f)
    embo[((size_t)be * NF + f) * NC + tid] =
        xs[f][tid] / (ono[f] + EPSN) * wno[f];
}

// ---------------------------------------------------------------------------
// K4 helper: 16x512x512 bf16 MFMA GEMM for one layer slice of one wave.
// wl = this lane's contiguous 1KB weight stream (lane-major layout);
// fragment (kt,p) at wl + kt*32 + p*8 (ushort units) -> all loads are
// base + immediate-offset. 2-deep register double-buffer on A and B frags.
// ---------------------------------------------------------------------------
__device__ __forceinline__ void scan_gemm(f32x4 acc[4],
                                          const unsigned short* __restrict__ wl,
                                          const unsigned short* A_lds,
                                          int abase, int akoff, int axor) {
  const char* ab = (const char*)A_lds;
#define LDA_(KT) \
  (*(const short8v*)(ab + abase + ((((KT)*64) + akoff) ^ axor)))
  short8v b0[4], b1[4], a0, a1;
#pragma unroll
  for (int p = 0; p < 4; ++p)
    b0[p] = *(const short8v*)(wl + p * 8);
  a0 = LDA_(0);
#pragma unroll
  for (int p = 0; p < 4; ++p)
    b1[p] = *(const short8v*)(wl + 32 + p * 8);
  a1 = LDA_(1);
#pragma unroll
  for (int kt = 0; kt < 16; ++kt) {
    if ((kt & 1) == 0) {
#pragma unroll
      for (int p = 0; p < 4; ++p)
        acc[p] = __builtin_amdgcn_mfma_f32_16x16x32_bf16(a0, b0[p], acc[p],
                                                         0, 0, 0);
      if (kt + 2 < 16) {
#pragma unroll
        for (int p = 0; p < 4; ++p)
          b0[p] = *(const short8v*)(wl + (kt + 2) * 32 + p * 8);
        a0 = LDA_(kt + 2);
      }
    } else {
#pragma unroll
      for (int p = 0; p < 4; ++p)
        acc[p] = __builtin_amdgcn_mfma_f32_16x16x32_bf16(a1, b1[p], acc[p],
                                                         0, 0, 0);
      if (kt + 2 < 16) {
#pragma unroll
        for (int p = 0; p < 4; ++p)
          b1[p] = *(const short8v*)(wl + (kt + 2) * 32 + p * 8);
        a1 = LDA_(kt + 2);
      }
    }
  }
#undef LDA_
}

// ---------------------------------------------------------------------------
// K4: the sequential scan, MFMA v4 (lane-major weight stream).
// 64 blocks x 512 threads; 4 seqs/block (rows 4..15 of the M=16 tile zero).
// Wave w owns output cols [w*64, w*64+64). weights/biases/embw prefetched one
// t ahead; leak staged in LDS; cn carried across steps (cn' = |cn-on|).
// ---------------------------------------------------------------------------
__global__ __launch_bounds__(512) void k_scan(
    const float* __restrict__ weights, const float* __restrict__ biases,
    const float* __restrict__ leak, const float* __restrict__ embw,
    const unsigned short* __restrict__ Wmf, const float* __restrict__ bs,
    const float* __restrict__ g, const float* __restrict__ bt,
    float* __restrict__ olb, float* __restrict__ onb) {
  __shared__ __align__(16) unsigned short A_lds[16 * NC];  // 16KB
  __shared__ float ol_lds[SPB][NC];                        // 8KB
  __shared__ float redA[64];
  __shared__ float redB[32];
  __shared__ float st1[8][SPB], st2[8][SPB];
  __shared__ float lk_lds[SPB][NT];

  const int tid = threadIdx.x;
  const int wave = tid >> 6, lane = tid & 63;
  const int seq0 = blockIdx.x * SPB;

  // stage leak slice (one element per thread)
  {
    const int r = tid >> 7, tt = tid & 127;
    lk_lds[r][tt] = leak[(size_t)(seq0 + r) * NT + tt];
  }
  // zero the pad rows 4..15 of A (never written again)
  {
    unsigned* z = (unsigned*)(A_lds + SPB * NC);
    for (int i = tid; i < (16 - SPB) * NC / 2; i += 512) z[i] = 0u;
  }

  // per-lane MFMA geometry
  const int arow = lane & 15;
  const int kgrp = lane >> 4;
  const int abase = arow * (NC * 2);
  const int axor = (arow & 7) << 4;
  const int akoff = kgrp * 16;
  const bool crow = (kgrp == 0);  // lanes holding C rows 0..3

  // hoist per-lane (t-invariant) bias / LN params for this wave's 4 n-tiles
  float bsv[4][4], gv[3][4], btv[3][4];
#pragma unroll
  for (int p = 0; p < 4; ++p) {
    const int cp = wave * 64 + p * 16 + (lane & 15);
#pragma unroll
    for (int l = 0; l < 4; ++l) bsv[l][p] = bs[l * NC + cp];
#pragma unroll
    for (int l = 0; l < 3; ++l) {
      gv[l][p] = g[l * NC + cp];
      btv[l][p] = bt[l * NC + cp];
    }
  }
  // this lane's weight stream bases (lane-major layout)
  const unsigned short* wlane = Wmf + (size_t)wave * 32768 + lane * 512;
  // + layer*8*32768 selects the layer

  // initial prefetch for t=0
  float wpre[SPB], bpre[SPB], epre[SPB];
#pragma unroll
  for (int r = 0; r < SPB; ++r) {
    const size_t o = ((size_t)(seq0 + r) * NT) * NC + tid;
    wpre[r] = weights[o];
    bpre[r] = biases[o];
    epre[r] = embw[((size_t)(seq0 + r) * NF) * NC + tid];
  }

  __syncthreads();

  float h[SPB], cn[SPB];
#pragma unroll
  for (int r = 0; r < SPB; ++r) { h[r] = 0.f; cn[r] = 0.f; }

#pragma unroll 1
  for (int t = 0; t < NT; ++t) {
    float hw[SPB];
    if (t < NF) {
#pragma unroll
      for (int r = 0; r < SPB; ++r) h[r] += epre[r];
      if (t + 1 < NF) {
#pragma unroll
        for (int r = 0; r < SPB; ++r)
          epre[r] = embw[((size_t)(seq0 + r) * NF + t + 1) * NC + tid];
      }
      float v8[8], s8[8];
#pragma unroll
      for (int r = 0; r < SPB; ++r) {
        hw[r] = fmaf(h[r], wpre[r], bpre[r]);
        v8[r] = h[r] * h[r];
        v8[SPB + r] = hw[r] * hw[r];
      }
      blk_reduce1<8>(v8, s8, redA);
#pragma unroll
      for (int r = 0; r < SPB; ++r) {
        cn[r] = sqrtf(s8[r]);
        h[r] = hw[r] * (cn[r] / (sqrtf(s8[SPB + r]) + EPSN));
      }
    } else {
      float v4[SPB], s4[SPB];
#pragma unroll
      for (int r = 0; r < SPB; ++r) {
        hw[r] = fmaf(h[r], wpre[r], bpre[r]);
        v4[r] = hw[r] * hw[r];
      }
      blk_reduce1<SPB>(v4, s4, redA);
#pragma unroll
      for (int r = 0; r < SPB; ++r)
        h[r] = hw[r] * (cn[r] / (sqrtf(s4[r]) + EPSN));
    }
    // prefetch weights/biases for t+1 (overlaps the MFMA phase)
    if (t + 1 < NT) {
#pragma unroll
      for (int r = 0; r < SPB; ++r) {
        const size_t o = ((size_t)(seq0 + r) * NT + t + 1) * NC + tid;
        wpre[r] = weights[o];
        bpre[r] = biases[o];
      }
    }
    // pack x -> A rows 0..3 (bf16, swizzled)
    {
      char* ab = (char*)A_lds;
#pragma unroll
      for (int r = 0; r < SPB; ++r)
        *(unsigned short*)(ab + r * 1024 + ((tid * 2) ^ ((r & 7) << 4))) =
            f2bf(h[r]);
    }
    __syncthreads();

    // ---- 3 hidden layers ----
#pragma unroll
    for (int layer = 0; layer < 3; ++layer) {
      f32x4 acc[4];
#pragma unroll
      for (int p = 0; p < 4; ++p) acc[p] = (f32x4){0.f, 0.f, 0.f, 0.f};
      scan_gemm(acc, wlane + (size_t)layer * 262144, A_lds, abase, akoff,
                axor);
      float s1[SPB], s2[SPB];
#pragma unroll
      for (int q = 0; q < SPB; ++q) { s1[q] = 0.f; s2[q] = 0.f; }
#pragma unroll
      for (int p = 0; p < 4; ++p) {
#pragma unroll
        for (int q = 0; q < SPB; ++q) {
          const float y = acc[p][q] + bsv[layer][p];
          acc[p][q] = y;
          s1[q] += y;
          s2[q] = fmaf(y, y, s2[q]);
        }
      }
#pragma unroll
      for (int off = 1; off < 16; off <<= 1) {
#pragma unroll
        for (int q = 0; q < SPB; ++q) {
          s1[q] += __shfl_xor(s1[q], off);
          s2[q] += __shfl_xor(s2[q], off);
        }
      }
      if (lane == 0) {
#pragma unroll
        for (int q = 0; q < SPB; ++q) {
          st1[wave][q] = s1[q];
          st2[wave][q] = s2[q];
        }
      }
      __syncthreads();
      float mu[SPB], rs[SPB];
#pragma unroll
      for (int q = 0; q < SPB; ++q) {
        float a1 = 0.f, a2 = 0.f;
#pragma unroll
        for (int w = 0; w < 8; ++w) {
          a1 += st1[w][q];
          a2 += st2[w][q];
        }
        mu[q] = a1 * (1.f / NC);
        rs[q] = rsqrtf(a2 * (1.f / NC) - mu[q] * mu[q] + 1e-5f);
      }
      if (crow) {
        char* ab = (char*)A_lds;
#pragma unroll
        for (int q = 0; q < SPB; ++q) {
#pragma unroll
          for (int p = 0; p < 4; ++p) {
            float y = (acc[p][q] - mu[q]) * rs[q] * gv[layer][p] +
                      btv[layer][p];
            y = y > 0.f ? y : 0.2f * y;
            const int cp = wave * 64 + p * 16 + (lane & 15);
            *(unsigned short*)(ab + q * 1024 +
                               ((cp * 2) ^ ((q & 7) << 4))) = f2bf(y);
          }
        }
      }
      __syncthreads();
    }

    // ---- final linear -> ol; epilogue ----
    {
      f32x4 acc[4];
#pragma unroll
      for (int p = 0; p < 4; ++p) acc[p] = (f32x4){0.f, 0.f, 0.f, 0.f};
      scan_gemm(acc, wlane + (size_t)3 * 262144, A_lds, abase, akoff, axor);
      float s2[SPB];
#pragma unroll
      for (int q = 0; q < SPB; ++q) s2[q] = 0.f;
#pragma unroll
      for (int p = 0; p < 4; ++p) {
#pragma unroll
        for (int q = 0; q < SPB; ++q) {
          const float y = acc[p][q] + bsv[3][p];
          acc[p][q] = y;
          s2[q] = fmaf(y, y, s2[q]);
        }
      }
#pragma unroll
      for (int off = 1; off < 16; off <<= 1) {
#pragma unroll
        for (int q = 0; q < SPB; ++q) s2[q] += __shfl_xor(s2[q], off);
      }
      if (lane == 0) {
#pragma unroll
        for (int q = 0; q < SPB; ++q) st2[wave][q] = s2[q];
      }
      if (crow) {
#pragma unroll
        for (int q = 0; q < SPB; ++q) {
#pragma unroll
          for (int p = 0; p < 4; ++p)
            ol_lds[q][wave * 64 + p * 16 + (lane & 15)] = acc[p][q];
        }
      }
      __syncthreads();
      float sc[SPB], on[SPB];
#pragma unroll
      for (int r = 0; r < SPB; ++r) {
        float a2 = 0.f;
#pragma unroll
        for (int w = 0; w < 8; ++w) a2 += st2[w][r];
        const float no = sqrtf(a2);
        sc[r] = cn[r] * lk_lds[r][t] / (no + EPSN);
        on[r] = no * sc[r];
      }
      if (tid < SPB) onb[(size_t)(seq0 + tid) * NT + t] = on[tid];
      float v4[SPB], s4[SPB];
#pragma unroll
      for (int r = 0; r < SPB; ++r) {
        const float olv = ol_lds[r][tid] * sc[r];
        olb[((size_t)(seq0 + r) * NT + t) * NC + tid] = olv;
        h[r] -= olv;
        v4[r] = h[r] * h[r];
      }
      blk_reduce1<SPB>(v4, s4, redB);
#pragma unroll
      for (int r = 0; r < SPB; ++r) {
        h[r] *= (cn[r] - on[r]) / (sqrtf(s4[r]) + EPSN);
        cn[r] = fabsf(cn[r] - on[r]);  // ||h|| carried exactly
      }
    }
  }
}

// ---------------------------------------------------------------------------
// K5: batched out-MLP on all 32768 ol rows: of = unit_norm(mlp_out(ol)*ham)*on
// ---------------------------------------------------------------------------
__global__ __launch_bounds__(512) void k_out(
    const float* __restrict__ olb, const float* __restrict__ onb,
    const float* __restrict__ Ws, const float* __restrict__ bs,
    const float* __restrict__ g, const float* __restrict__ bt,
    float* __restrict__ ofb) {
  __shared__ float xs[16][NC];
  __shared__ float mu_s[16], rs_s[16], ono[16];
  const int tid = threadIdx.x;
  const int wave = tid >> 6, lane = tid & 63;
  const int m0 = blockIdx.x * 16;
  for (int i = 0; i < 16; ++i)
    xs[i][tid] = olb[(size_t)(m0 + i) * NC + tid];
  __syncthreads();
  float acc[16];
  for (int layer = 0; layer < 4; ++layer) {
    tile_gemm16(xs, Ws + (size_t)layer * NC * NC, tid, acc);
    __syncthreads();
    const float bv = bs[layer * NC + tid];
#pragma unroll
    for (int i = 0; i < 16; ++i) xs[i][tid] = acc[i] + bv;
    __syncthreads();
    if (layer < 3) ln_leaky16(xs, g, bt, layer, tid, mu_s, rs_s);
  }
  const float ham =
      0.54f - 0.46f * cosf(6.283185307179586f * (float)tid / (float)NC);
#pragma unroll
  for (int i = 0; i < 16; ++i) xs[i][tid] *= ham;
  __syncthreads();
  for (int f = wave; f < 16; f += 8) {
    float s = 0.f;
#pragma unroll
    for (int j = 0; j < 8; ++j) {
      const float vv = xs[f][lane + 64 * j];
      s = fmaf(vv, vv, s);
    }
#pragma unroll
    for (int off = 32; off; off >>= 1) s += __shfl_down(s, off);
    if (lane == 0) ono[f] = sqrtf(s);
  }
  __syncthreads();
  for (int i = 0; i < 16; ++i) {
    const float onv = onb[m0 + i];
    ofb[(size_t)(m0 + i) * NC + tid] = xs[i][tid] / (ono[i] + EPSN) * onv;
  }
}

// ---------------------------------------------------------------------------
// K6: overlap-add at hop 256, trim to 32768.
// ---------------------------------------------------------------------------
__global__ __launch_bounds__(256) void k_oa(const float* __restrict__ ofb,
                                            float* __restrict__ out) {
  const int idx = blockIdx.x * 256 + threadIdx.x;
  if (idx >= BE * 32768) return;
  const int be = idx >> 15;
  const int s = idx & 32767;
  const int t1 = s >> 8;
  float v = ofb[((size_t)be * NT + t1) * NC + (s - (t1 << 8))];
  if (t1 >= 1)
    v += ofb[((size_t)be * NT + (t1 - 1)) * NC + (s - ((t1 - 1) << 8))];
  out[idx] = v;
}

// ---------------------------------------------------------------------------
// Workspace (< 256 MiB): region A (deform->olb) 64 MiB, region B
// (weights->ofb) 64 MiB, region C (biases) 64 MiB, small buffers ~12 MiB.
// ---------------------------------------------------------------------------
extern "C" void kernel_launch(void* const* d_in, const int* in_sizes, int n_in,
                              void* d_out, int out_size, void* d_ws,
                              size_t ws_size, hipStream_t stream) {
  const float* embedding = (const float*)d_in[0];
  const float* impulse = (const float*)d_in[1];
  const float* W_def = (const float*)d_in[2];
  const float* b_def = (const float*)d_in[3];
  const float* W_w = (const float*)d_in[4];
  const float* b_w = (const float*)d_in[5];
  const float* W_b = (const float*)d_in[6];
  const float* b_b = (const float*)d_in[7];
  const float* W_l = (const float*)d_in[8];
  const float* b_l = (const float*)d_in[9];
  const float* Ws_imp = (const float*)d_in[10];
  const float* bs_imp = (const float*)d_in[11];
  const float* g_imp = (const float*)d_in[12];
  const float* bt_imp = (const float*)d_in[13];
  const float* Ws_lat = (const float*)d_in[14];
  const float* bs_lat = (const float*)d_in[15];
  const float* g_lat = (const float*)d_in[16];
  const float* bt_lat = (const float*)d_in[17];
  const float* Ws_out = (const float*)d_in[18];
  const float* bs_out = (const float*)d_in[19];
  const float* g_out = (const float*)d_in[20];
  const float* bt_out = (const float*)d_in[21];
  float* out = (float*)d_out;

  float* ws = (float*)d_ws;
  float* deform = ws;                  // region A (reused as olb)
  float* weights = deform + 16777216;  // region B (reused as ofb)
  float* biases = weights + 16777216;  // region C
  float* leakb = biases + 16777216;    // 32,768 f
  float* embw = leakb + 32768;         // 2,097,152 f
  float* onb = embw + 2097152;         // 32,768 f
  unsigned short* wmf = (unsigned short*)(onb + 32768);  // 2,097,152 us
  float* olb = deform;                 // alias: deform dead after k_wb
  float* ofb = weights;                // alias: weights dead after k_scan

  k_cvt<<<2048, 64, 0, stream>>>(Ws_lat, wmf);
  k_deform<<<dim3(256, 8), 256, 0, stream>>>(embedding, W_def, b_def, deform);
  k_wb<<<2048, 512, 0, stream>>>(deform, W_w, b_w, W_b, b_b, W_l, b_l,
                                 weights, biases, leakb);
  k_imp<<<256, 512, 0, stream>>>(impulse, Ws_imp, bs_imp, g_imp, bt_imp, embw);
  k_scan<<<NSCAN, 512, 0, stream>>>(weights, biases, leakb, embw, wmf, bs_lat,
                                    g_lat, bt_lat, olb, onb);
  k_out<<<2048, 512, 0, stream>>>(olb, onb, Ws_out, bs_out, g_out, bt_out,
                                  ofb);
  k_oa<<<32768, 256, 0, stream>>>(ofb, out);
}

// Round 7
// 13284.401 us; speedup vs baseline: 1.0007x; 1.0007x over previous
//
#include <hip/hip_runtime.h>
#include <math.h>

#define NB 4
#define NE 64
#define BE 256          // NB*NE
#define LAT 256
#define NC 512          // channels == window
#define NT 128          // n_frames
#define NDEF 65536      // NC*NT
#define NIMP 4096
#define NF 16           // impulse frames
#define EPSN 1e-8f
#define SPB 4           // sequences per scan block
#define NSCAN 64        // scan blocks (BE/SPB)

typedef unsigned short ushort8 __attribute__((ext_vector_type(8)));
typedef short short8v __attribute__((ext_vector_type(8)));
typedef float f32x4 __attribute__((ext_vector_type(4)));

__device__ __forceinline__ unsigned short f2bf(float f) {
  const unsigned u = __float_as_uint(f);
  return (unsigned short)((u + 0x7FFFu + ((u >> 16) & 1u)) >> 16);  // RNE
}

// ---------------------------------------------------------------------------
// single-barrier block reduction: 512 threads each contribute v[NR]; every
// thread gets the block sum in out[NR]. red is a flat >=8*NR float buffer.
// ---------------------------------------------------------------------------
template <int NR>
__device__ __forceinline__ void blk_reduce1(const float* v, float* out,
                                            float* red) {
  const int tid = threadIdx.x, wave = tid >> 6, lane = tid & 63;
  float s[NR];
#pragma unroll
  for (int i = 0; i < NR; ++i) s[i] = v[i];
#pragma unroll
  for (int off = 32; off; off >>= 1) {
#pragma unroll
    for (int i = 0; i < NR; ++i) s[i] += __shfl_down(s[i], off);
  }
  if (lane == 0) {
#pragma unroll
    for (int i = 0; i < NR; ++i) red[wave * NR + i] = s[i];
  }
  __syncthreads();
#pragma unroll
  for (int i = 0; i < NR; ++i) {
    float a = 0.f;
#pragma unroll
    for (int w = 0; w < 8; ++w) a += red[w * NR + i];
    out[i] = a;
  }
}

// ---------------------------------------------------------------------------
// K0: swizzle Ws_lat (4 x [512 k][512 n] f32) into fragment-major MFMA B-frag
// order, bf16. Fragment (layer, wv, kt, p) lives at
//   Wmf[ ((layer*8+wv)*64 + kt*4 + p)*512 + lane*8 + j ]
//     = bf16( W[layer][kt*32 + (lane>>4)*8 + j][wv*64 + p*16 + (lane&15)] )
// Each fragment load in k_scan = contiguous 1KB, wave-coalesced (8 lines).
// grid 2048 (= ((layer*8+wv)*16+kt)*4+p), block 64.
// ---------------------------------------------------------------------------
__global__ __launch_bounds__(64) void k_cvt(const float* __restrict__ W,
                                            unsigned short* __restrict__ Wmf) {
  const int lane = threadIdx.x;
  const int gg = blockIdx.x;
  const int p = gg & 3;
  const int kt = (gg >> 2) & 15;
  const int wv = (gg >> 6) & 7;
  const int layer = gg >> 9;
  const int col = wv * 64 + p * 16 + (lane & 15);
  const int k0 = kt * 32 + (lane >> 4) * 8;
  ushort8 o;
#pragma unroll
  for (int j = 0; j < 8; ++j)
    o[j] = f2bf(W[((size_t)layer * NC + k0 + j) * NC + col]);
  *reinterpret_cast<ushort8*>(Wmf + ((size_t)gg * 64 + lane) * 8) = o;
}

// ---------------------------------------------------------------------------
// K1: deform = embedding @ W_def + b_def      (256 x 256) @ (256 x 65536)
// ---------------------------------------------------------------------------
__global__ __launch_bounds__(256) void k_deform(
    const float* __restrict__ emb, const float* __restrict__ Wd,
    const float* __restrict__ bd, float* __restrict__ deform) {
  __shared__ float As[32][LAT];
  const int tid = threadIdx.x;
  const int c = blockIdx.x * 256 + tid;
  const int m0 = blockIdx.y * 32;
  for (int i = 0; i < 32; ++i) As[i][tid] = emb[(m0 + i) * LAT + tid];
  __syncthreads();
  float acc[32];
#pragma unroll
  for (int i = 0; i < 32; ++i) acc[i] = 0.f;
  for (int k = 0; k < LAT; k += 4) {
    const float w0 = Wd[(size_t)(k + 0) * NDEF + c];
    const float w1 = Wd[(size_t)(k + 1) * NDEF + c];
    const float w2 = Wd[(size_t)(k + 2) * NDEF + c];
    const float w3 = Wd[(size_t)(k + 3) * NDEF + c];
#pragma unroll
    for (int i = 0; i < 32; ++i) {
      const float4 a = *reinterpret_cast<const float4*>(&As[i][k]);
      acc[i] = fmaf(a.x, w0, acc[i]);
      acc[i] = fmaf(a.y, w1, acc[i]);
      acc[i] = fmaf(a.z, w2, acc[i]);
      acc[i] = fmaf(a.w, w3, acc[i]);
    }
  }
  const float bv = bd[c];
  for (int i = 0; i < 32; ++i)
    deform[(size_t)(m0 + i) * NDEF + c] = acc[i] + bv;
}

// ---------------------------------------------------------------------------
// K2: per-(be,t) rows of deform: unit_norm over channel dim, then
//   weights = x @ W_w + b_w ; biases = x @ W_b + b_b ; leak = sigmoid path.
// ---------------------------------------------------------------------------
__global__ __launch_bounds__(512) void k_wb(
    const float* __restrict__ deform, const float* __restrict__ Ww,
    const float* __restrict__ bw, const float* __restrict__ Wb,
    const float* __restrict__ bb, const float* __restrict__ Wl,
    const float* __restrict__ bl, float* __restrict__ weights,
    float* __restrict__ biases, float* __restrict__ leak) {
  __shared__ float xs[16][NC];
  __shared__ float rno[16], lks[16];
  const int tid = threadIdx.x;
  const int wave = tid >> 6, lane = tid & 63;
  const int be = blockIdx.x >> 3;
  const int t0 = (blockIdx.x & 7) * 16;
  const float* dbase = deform + (size_t)be * NDEF;
  for (int i = 0; i < 16; ++i)
    xs[i][tid] = dbase[(size_t)tid * NT + t0 + i];
  __syncthreads();
  for (int f = wave; f < 16; f += 8) {
    float s = 0.f;
#pragma unroll
    for (int j = 0; j < 8; ++j) {
      const float v = xs[f][lane + 64 * j];
      s = fmaf(v, v, s);
    }
#pragma unroll
    for (int off = 32; off; off >>= 1) s += __shfl_down(s, off);
    if (lane == 0) rno[f] = sqrtf(s);
  }
  __syncthreads();
#pragma unroll
  for (int i = 0; i < 16; ++i) xs[i][tid] = xs[i][tid] / (rno[i] + EPSN);
  __syncthreads();
  for (int f = wave; f < 16; f += 8) {
    float s = 0.f;
#pragma unroll
    for (int j = 0; j < 8; ++j)
      s = fmaf(xs[f][lane + 64 * j], Wl[lane + 64 * j], s);
#pragma unroll
    for (int off = 32; off; off >>= 1) s += __shfl_down(s, off);
    if (lane == 0) lks[f] = s;
  }
  __syncthreads();
  if (tid < 16) {
    const float v = lks[tid] + bl[0];
    leak[(size_t)be * NT + t0 + tid] = 0.1f + 0.98f / (1.f + expf(-v));
  }
  float accw[16], accb[16];
#pragma unroll
  for (int i = 0; i < 16; ++i) { accw[i] = 0.f; accb[i] = 0.f; }
  for (int k = 0; k < NC; k += 2) {
    const float w0 = Ww[(size_t)k * NC + tid];
    const float w1 = Ww[(size_t)(k + 1) * NC + tid];
    const float v0 = Wb[(size_t)k * NC + tid];
    const float v1 = Wb[(size_t)(k + 1) * NC + tid];
#pragma unroll
    for (int i = 0; i < 16; ++i) {
      const float2 a = *reinterpret_cast<const float2*>(&xs[i][k]);
      accw[i] = fmaf(a.x, w0, accw[i]);
      accw[i] = fmaf(a.y, w1, accw[i]);
      accb[i] = fmaf(a.x, v0, accb[i]);
      accb[i] = fmaf(a.y, v1, accb[i]);
    }
  }
  const float bwv = bw[tid], bbv = bb[tid];
  for (int i = 0; i < 16; ++i) {
    const size_t o = ((size_t)be * NT + t0 + i) * NC + tid;
    weights[o] = accw[i] + bwv;
    biases[o] = accb[i] + bbv;
  }
}

// ---------------------------------------------------------------------------
// 16-row tile x (512x512) GEMM helper: xs[16][512] in LDS, thread = column.
// ---------------------------------------------------------------------------
__device__ __forceinline__ void tile_gemm16(const float (*xs)[NC],
                                            const float* __restrict__ W,
                                            int tid, float acc[16]) {
#pragma unroll
  for (int i = 0; i < 16; ++i) acc[i] = 0.f;
  for (int k = 0; k < NC; k += 4) {
    const float w0 = W[(size_t)(k + 0) * NC + tid];
    const float w1 = W[(size_t)(k + 1) * NC + tid];
    const float w2 = W[(size_t)(k + 2) * NC + tid];
    const float w3 = W[(size_t)(k + 3) * NC + tid];
#pragma unroll
    for (int i = 0; i < 16; ++i) {
      const float4 a = *reinterpret_cast<const float4*>(&xs[i][k]);
      acc[i] = fmaf(a.x, w0, acc[i]);
      acc[i] = fmaf(a.y, w1, acc[i]);
      acc[i] = fmaf(a.z, w2, acc[i]);
      acc[i] = fmaf(a.w, w3, acc[i]);
    }
  }
}

// LN (+leaky) stats applied in-place on xs[16][NC]
__device__ __forceinline__ void ln_leaky16(float (*xs)[NC],
                                           const float* __restrict__ g,
                                           const float* __restrict__ bt,
                                           int layer, int tid, float* mu_s,
                                           float* rs_s) {
  const int wave = tid >> 6, lane = tid & 63;
  for (int f = wave; f < 16; f += 8) {
    float s = 0.f, s2 = 0.f;
#pragma unroll
    for (int j = 0; j < 8; ++j) {
      const float v = xs[f][lane + 64 * j];
      s += v;
      s2 = fmaf(v, v, s2);
    }
#pragma unroll
    for (int off = 32; off; off >>= 1) {
      s += __shfl_down(s, off);
      s2 += __shfl_down(s2, off);
    }
    if (lane == 0) {
      const float mu = s * (1.f / NC);
      mu_s[f] = mu;
      rs_s[f] = rsqrtf(s2 * (1.f / NC) - mu * mu + 1e-5f);
    }
  }
  __syncthreads();
  const float gv = g[layer * NC + tid], btv = bt[layer * NC + tid];
#pragma unroll
  for (int i = 0; i < 16; ++i) {
    const float y = (xs[i][tid] - mu_s[i]) * rs_s[i] * gv + btv;
    xs[i][tid] = y > 0.f ? y : 0.2f * y;
  }
  __syncthreads();
}

// ---------------------------------------------------------------------------
// K3: windowed impulse -> mlp_imp -> unit_norm * window-norm -> emb stream.
// ---------------------------------------------------------------------------
__global__ __launch_bounds__(512) void k_imp(
    const float* __restrict__ impulse, const float* __restrict__ Ws,
    const float* __restrict__ bs, const float* __restrict__ g,
    const float* __restrict__ bt, float* __restrict__ embo) {
  __shared__ float xs[16][NC];
  __shared__ float wno[16], mu_s[16], rs_s[16], ono[16];
  const int tid = threadIdx.x;
  const int wave = tid >> 6, lane = tid & 63;
  const int be = blockIdx.x;
  const float* ib = impulse + (size_t)be * NIMP;
  for (int f = 0; f < 16; ++f) {
    const int s = f * 256 + tid;
    xs[f][tid] = (s < NIMP) ? ib[s] : 0.f;
  }
  __syncthreads();
  for (int f = wave; f < 16; f += 8) {
    float s = 0.f;
#pragma unroll
    for (int j = 0; j < 8; ++j) {
      const float v = xs[f][lane + 64 * j];
      s = fmaf(v, v, s);
    }
#pragma unroll
    for (int off = 32; off; off >>= 1) s += __shfl_down(s, off);
    if (lane == 0) wno[f] = sqrtf(s);
  }
  __syncthreads();
  float acc[16];
  for (int layer = 0; layer < 4; ++layer) {
    tile_gemm16(xs, Ws + (size_t)layer * NC * NC, tid, acc);
    __syncthreads();
    const float bv = bs[layer * NC + tid];
#pragma unroll
    for (int i = 0; i < 16; ++i) xs[i][tid] = acc[i] + bv;
    __syncthreads();
    if (layer < 3) ln_leaky16(xs, g, bt, layer, tid, mu_s, rs_s);
  }
  for (int f = wave; f < 16; f += 8) {
    float s = 0.f;
#pragma unroll
    for (int j = 0; j < 8; ++j) {
      const float v = xs[f][lane + 64 * j];
      s = fmaf(v, v, s);
    }
#pragma unroll
    for (int off = 32; off; off >>= 1) s += __shfl_down(s, off);
    if (lane == 0) ono[f] = sqrtf(s);
  }
  __syncthreads();
  for (int f = 0; f < 16; ++f)
    embo[((size_t)be * NF + f) * NC + tid] =
        xs[f][tid] / (ono[f] + EPSN) * wno[f];
}

// ---------------------------------------------------------------------------
// K4 helper: 16x512x512 bf16 MFMA GEMM for one layer slice of one wave.
// wl = Wmf + (layer*8+wave)*32768 + lane*8; fragment (kt,p) at +(kt*4+p)*512.
// 3-slot rotating register pipeline on A and B frags (all indices static
// after full unroll). In-flight: up to 12KB/wave of B + 3 A-frags.
// ---------------------------------------------------------------------------
__device__ __forceinline__ void scan_gemm(f32x4 acc[4],
                                          const unsigned short* __restrict__ wl,
                                          const unsigned short* A_lds,
                                          int abase, int akoff, int axor) {
  const char* ab = (const char*)A_lds;
#define LDA_(KT) \
  (*(const short8v*)(ab + abase + ((((KT)*64) + akoff) ^ axor)))
#define LDB_(KT, P) (*(const short8v*)(wl + ((KT)*4 + (P)) * 512))
  short8v b[3][4];
  short8v a[3];
#pragma unroll
  for (int s = 0; s < 3; ++s) {
#pragma unroll
    for (int p = 0; p < 4; ++p) b[s][p] = LDB_(s, p);
    a[s] = LDA_(s);
  }
#pragma unroll
  for (int kt = 0; kt < 16; ++kt) {
    const int s = kt % 3;
#pragma unroll
    for (int p = 0; p < 4; ++p)
      acc[p] =
          __builtin_amdgcn_mfma_f32_16x16x32_bf16(a[s], b[s][p], acc[p], 0, 0, 0);
    if (kt + 3 < 16) {
#pragma unroll
      for (int p = 0; p < 4; ++p) b[s][p] = LDB_(kt + 3, p);
      a[s] = LDA_(kt + 3);
    }
  }
#undef LDA_
#undef LDB_
}

// ---------------------------------------------------------------------------
// K4: the sequential scan, MFMA v5.
// 64 blocks x 512 threads (8 waves = 2/SIMD). __launch_bounds__(512,2) allows
// up to 256 VGPR -> the hoisted params + 3-deep gemm pipeline stay in
// registers (R4-R6 were silently spilling at the 128-VGPR cap; the spill
// reloads were ~1MB/block/t of scratch reads = the entire FETCH_SIZE).
// ---------------------------------------------------------------------------
__global__ __launch_bounds__(512, 2) void k_scan(
    const float* __restrict__ weights, const float* __restrict__ biases,
    const float* __restrict__ leak, const float* __restrict__ embw,
    const unsigned short* __restrict__ Wmf, const float* __restrict__ bs,
    const float* __restrict__ g, const float* __restrict__ bt,
    float* __restrict__ olb, float* __restrict__ onb) {
  __shared__ __align__(16) unsigned short A_lds[16 * NC];  // 16KB
  __shared__ float ol_lds[SPB][NC];                        // 8KB
  __shared__ float redA[64];
  __shared__ float redB[32];
  __shared__ float st1[8][SPB], st2[8][SPB];
  __shared__ float lk_lds[SPB][NT];

  const int tid = threadIdx.x;
  const int wave = tid >> 6, lane = tid & 63;
  const int seq0 = blockIdx.x * SPB;

  // stage leak slice (one element per thread)
  {
    const int r = tid >> 7, tt = tid & 127;
    lk_lds[r][tt] = leak[(size_t)(seq0 + r) * NT + tt];
  }
  // zero the pad rows 4..15 of A (never written again)
  {
    unsigned* z = (unsigned*)(A_lds + SPB * NC);
    for (int i = tid; i < (16 - SPB) * NC / 2; i += 512) z[i] = 0u;
  }

  // per-lane MFMA geometry
  const int arow = lane & 15;
  const int kgrp = lane >> 4;
  const int abase = arow * (NC * 2);
  const int axor = (arow & 7) << 4;
  const int akoff = kgrp * 16;
  const bool crow = (kgrp == 0);  // lanes holding C rows 0..3

  // hoist per-lane (t-invariant) bias / LN params for this wave's 4 n-tiles
  float bsv[4][4], gv[3][4], btv[3][4];
#pragma unroll
  for (int p = 0; p < 4; ++p) {
    const int cp = wave * 64 + p * 16 + (lane & 15);
#pragma unroll
    for (int l = 0; l < 4; ++l) bsv[l][p] = bs[l * NC + cp];
#pragma unroll
    for (int l = 0; l < 3; ++l) {
      gv[l][p] = g[l * NC + cp];
      btv[l][p] = bt[l * NC + cp];
    }
  }
  // this wave's fragment stream base (fragment-major layout)
  const unsigned short* wlane = Wmf + (size_t)wave * 32768 + lane * 8;
  // + layer*262144 selects the layer

  // initial prefetch for t=0
  float wpre[SPB], bpre[SPB], epre[SPB];
#pragma unroll
  for (int r = 0; r < SPB; ++r) {
    const size_t o = ((size_t)(seq0 + r) * NT) * NC + tid;
    wpre[r] = weights[o];
    bpre[r] = biases[o];
    epre[r] = embw[((size_t)(seq0 + r) * NF) * NC + tid];
  }

  __syncthreads();

  float h[SPB], cn[SPB];
#pragma unroll
  for (int r = 0; r < SPB; ++r) { h[r] = 0.f; cn[r] = 0.f; }

#pragma unroll 1
  for (int t = 0; t < NT; ++t) {
    float hw[SPB];
    if (t < NF) {
#pragma unroll
      for (int r = 0; r < SPB; ++r) h[r] += epre[r];
      if (t + 1 < NF) {
#pragma unroll
        for (int r = 0; r < SPB; ++r)
          epre[r] = embw[((size_t)(seq0 + r) * NF + t + 1) * NC + tid];
      }
      float v8[8], s8[8];
#pragma unroll
      for (int r = 0; r < SPB; ++r) {
        hw[r] = fmaf(h[r], wpre[r], bpre[r]);
        v8[r] = h[r] * h[r];
        v8[SPB + r] = hw[r] * hw[r];
      }
      blk_reduce1<8>(v8, s8, redA);
#pragma unroll
      for (int r = 0; r < SPB; ++r) {
        cn[r] = sqrtf(s8[r]);
        h[r] = hw[r] * (cn[r] / (sqrtf(s8[SPB + r]) + EPSN));
      }
    } else {
      float v4[SPB], s4[SPB];
#pragma unroll
      for (int r = 0; r < SPB; ++r) {
        hw[r] = fmaf(h[r], wpre[r], bpre[r]);
        v4[r] = hw[r] * hw[r];
      }
      blk_reduce1<SPB>(v4, s4, redA);
#pragma unroll
      for (int r = 0; r < SPB; ++r)
        h[r] = hw[r] * (cn[r] / (sqrtf(s4[r]) + EPSN));
    }
    // prefetch weights/biases for t+1 (overlaps the MFMA phase)
    if (t + 1 < NT) {
#pragma unroll
      for (int r = 0; r < SPB; ++r) {
        const size_t o = ((size_t)(seq0 + r) * NT + t + 1) * NC + tid;
        wpre[r] = weights[o];
        bpre[r] = biases[o];
      }
    }
    // pack x -> A rows 0..3 (bf16, swizzled)
    {
      char* ab = (char*)A_lds;
#pragma unroll
      for (int r = 0; r < SPB; ++r)
        *(unsigned short*)(ab + r * 1024 + ((tid * 2) ^ ((r & 7) << 4))) =
            f2bf(h[r]);
    }
    __syncthreads();

    // ---- 3 hidden layers ----
#pragma unroll
    for (int layer = 0; layer < 3; ++layer) {
      f32x4 acc[4];
#pragma unroll
      for (int p = 0; p < 4; ++p) acc[p] = (f32x4){0.f, 0.f, 0.f, 0.f};
      scan_gemm(acc, wlane + (size_t)layer * 262144, A_lds, abase, akoff,
                axor);
      float s1[SPB], s2[SPB];
#pragma unroll
      for (int q = 0; q < SPB; ++q) { s1[q] = 0.f; s2[q] = 0.f; }
#pragma unroll
      for (int p = 0; p < 4; ++p) {
#pragma unroll
        for (int q = 0; q < SPB; ++q) {
          const float y = acc[p][q] + bsv[layer][p];
          acc[p][q] = y;
          s1[q] += y;
          s2[q] = fmaf(y, y, s2[q]);
        }
      }
#pragma unroll
      for (int off = 1; off < 16; off <<= 1) {
#pragma unroll
        for (int q = 0; q < SPB; ++q) {
          s1[q] += __shfl_xor(s1[q], off);
          s2[q] += __shfl_xor(s2[q], off);
        }
      }
      if (lane == 0) {
#pragma unroll
        for (int q = 0; q < SPB; ++q) {
          st1[wave][q] = s1[q];
          st2[wave][q] = s2[q];
        }
      }
      __syncthreads();
      float mu[SPB], rs[SPB];
#pragma unroll
      for (int q = 0; q < SPB; ++q) {
        float a1 = 0.f, a2 = 0.f;
#pragma unroll
        for (int w = 0; w < 8; ++w) {
          a1 += st1[w][q];
          a2 += st2[w][q];
        }
        mu[q] = a1 * (1.f / NC);
        rs[q] = rsqrtf(a2 * (1.f / NC) - mu[q] * mu[q] + 1e-5f);
      }
      if (crow) {
        char* ab = (char*)A_lds;
#pragma unroll
        for (int q = 0; q < SPB; ++q) {
#pragma unroll
          for (int p = 0; p < 4; ++p) {
            float y = (acc[p][q] - mu[q]) * rs[q] * gv[layer][p] +
                      btv[layer][p];
            y = y > 0.f ? y : 0.2f * y;
            const int cp = wave * 64 + p * 16 + (lane & 15);
            *(unsigned short*)(ab + q * 1024 +
                               ((cp * 2) ^ ((q & 7) << 4))) = f2bf(y);
          }
        }
      }
      __syncthreads();
    }

    // ---- final linear -> ol; epilogue ----
    {
      f32x4 acc[4];
#pragma unroll
      for (int p = 0; p < 4; ++p) acc[p] = (f32x4){0.f, 0.f, 0.f, 0.f};
      scan_gemm(acc, wlane + (size_t)3 * 262144, A_lds, abase, akoff, axor);
      float s2[SPB];
#pragma unroll
      for (int q = 0; q < SPB; ++q) s2[q] = 0.f;
#pragma unroll
      for (int p = 0; p < 4; ++p) {
#pragma unroll
        for (int q = 0; q < SPB; ++q) {
          const float y = acc[p][q] + bsv[3][p];
          acc[p][q] = y;
          s2[q] = fmaf(y, y, s2[q]);
        }
      }
#pragma unroll
      for (int off = 1; off < 16; off <<= 1) {
#pragma unroll
        for (int q = 0; q < SPB; ++q) s2[q] += __shfl_xor(s2[q], off);
      }
      if (lane == 0) {
#pragma unroll
        for (int q = 0; q < SPB; ++q) st2[wave][q] = s2[q];
      }
      if (crow) {
#pragma unroll
        for (int q = 0; q < SPB; ++q) {
#pragma unroll
          for (int p = 0; p < 4; ++p)
            ol_lds[q][wave * 64 + p * 16 + (lane & 15)] = acc[p][q];
        }
      }
      __syncthreads();
      float sc[SPB], on[SPB];
#pragma unroll
      for (int r = 0; r < SPB; ++r) {
        float a2 = 0.f;
#pragma unroll
        for (int w = 0; w < 8; ++w) a2 += st2[w][r];
        const float no = sqrtf(a2);
        sc[r] = cn[r] * lk_lds[r][t] / (no + EPSN);
        on[r] = no * sc[r];
      }
      if (tid < SPB) onb[(size_t)(seq0 + tid) * NT + t] = on[tid];
      float v4[SPB], s4[SPB];
#pragma unroll
      for (int r = 0; r < SPB; ++r) {
        const float olv = ol_lds[r][tid] * sc[r];
        olb[((size_t)(seq0 + r) * NT + t) * NC + tid] = olv;
        h[r] -= olv;
        v4[r] = h[r] * h[r];
      }
      blk_reduce1<SPB>(v4, s4, redB);
#pragma unroll
      for (int r = 0; r < SPB; ++r) {
        h[r] *= (cn[r] - on[r]) / (sqrtf(s4[r]) + EPSN);
        cn[r] = fabsf(cn[r] - on[r]);  // ||h|| carried exactly
      }
    }
  }
}

// ---------------------------------------------------------------------------
// K5: batched out-MLP on all 32768 ol rows: of = unit_norm(mlp_out(ol)*ham)*on
// ---------------------------------------------------------------------------
__global__ __launch_bounds__(512) void k_out(
    const float* __restrict__ olb, const float* __restrict__ onb,
    const float* __restrict__ Ws, const float* __restrict__ bs,
    const float* __restrict__ g, const float* __restrict__ bt,
    float* __restrict__ ofb) {
  __shared__ float xs[16][NC];
  __shared__ float mu_s[16], rs_s[16], ono[16];
  const int tid = threadIdx.x;
  const int wave = tid >> 6, lane = tid & 63;
  const int m0 = blockIdx.x * 16;
  for (int i = 0; i < 16; ++i)
    xs[i][tid] = olb[(size_t)(m0 + i) * NC + tid];
  __syncthreads();
  float acc[16];
  for (int layer = 0; layer < 4; ++layer) {
    tile_gemm16(xs, Ws + (size_t)layer * NC * NC, tid, acc);
    __syncthreads();
    const float bv = bs[layer * NC + tid];
#pragma unroll
    for (int i = 0; i < 16; ++i) xs[i][tid] = acc[i] + bv;
    __syncthreads();
    if (layer < 3) ln_leaky16(xs, g, bt, layer, tid, mu_s, rs_s);
  }
  const float ham =
      0.54f - 0.46f * cosf(6.283185307179586f * (float)tid / (float)NC);
#pragma unroll
  for (int i = 0; i < 16; ++i) xs[i][tid] *= ham;
  __syncthreads();
  for (int f = wave; f < 16; f += 8) {
    float s = 0.f;
#pragma unroll
    for (int j = 0; j < 8; ++j) {
      const float vv = xs[f][lane + 64 * j];
      s = fmaf(vv, vv, s);
    }
#pragma unroll
    for (int off = 32; off; off >>= 1) s += __shfl_down(s, off);
    if (lane == 0) ono[f] = sqrtf(s);
  }
  __syncthreads();
  for (int i = 0; i < 16; ++i) {
    const float onv = onb[m0 + i];
    ofb[(size_t)(m0 + i) * NC + tid] = xs[i][tid] / (ono[i] + EPSN) * onv;
  }
}

// ---------------------------------------------------------------------------
// K6: overlap-add at hop 256, trim to 32768.
// ---------------------------------------------------------------------------
__global__ __launch_bounds__(256) void k_oa(const float* __restrict__ ofb,
                                            float* __restrict__ out) {
  const int idx = blockIdx.x * 256 + threadIdx.x;
  if (idx >= BE * 32768) return;
  const int be = idx >> 15;
  const int s = idx & 32767;
  const int t1 = s >> 8;
  float v = ofb[((size_t)be * NT + t1) * NC + (s - (t1 << 8))];
  if (t1 >= 1)
    v += ofb[((size_t)be * NT + (t1 - 1)) * NC + (s - ((t1 - 1) << 8))];
  out[idx] = v;
}

// ---------------------------------------------------------------------------
// Workspace (< 256 MiB): region A (deform->olb) 64 MiB, region B
// (weights->ofb) 64 MiB, region C (biases) 64 MiB, small buffers ~12 MiB.
// ---------------------------------------------------------------------------
extern "C" void kernel_launch(void* const* d_in, const int* in_sizes, int n_in,
                              void* d_out, int out_size, void* d_ws,
                              size_t ws_size, hipStream_t stream) {
  const float* embedding = (const float*)d_in[0];
  const float* impulse = (const float*)d_in[1];
  const float* W_def = (const float*)d_in[2];
  const float* b_def = (const float*)d_in[3];
  const float* W_w = (const float*)d_in[4];
  const float* b_w = (const float*)d_in[5];
  const float* W_b = (const float*)d_in[6];
  const float* b_b = (const float*)d_in[7];
  const float* W_l = (const float*)d_in[8];
  const float* b_l = (const float*)d_in[9];
  const float* Ws_imp = (const float*)d_in[10];
  const float* bs_imp = (const float*)d_in[11];
  const float* g_imp = (const float*)d_in[12];
  const float* bt_imp = (const float*)d_in[13];
  const float* Ws_lat = (const float*)d_in[14];
  const float* bs_lat = (const float*)d_in[15];
  const float* g_lat = (const float*)d_in[16];
  const float* bt_lat = (const float*)d_in[17];
  const float* Ws_out = (const float*)d_in[18];
  const float* bs_out = (const float*)d_in[19];
  const float* g_out = (const float*)d_in[20];
  const float* bt_out = (const float*)d_in[21];
  float* out = (float*)d_out;

  float* ws = (float*)d_ws;
  float* deform = ws;                  // region A (reused as olb)
  float* weights = deform + 16777216;  // region B (reused as ofb)
  float* biases = weights + 16777216;  // region C
  float* leakb = biases + 16777216;    // 32,768 f
  float* embw = leakb + 32768;         // 2,097,152 f
  float* onb = embw + 2097152;         // 32,768 f
  unsigned short* wmf = (unsigned short*)(onb + 32768);  // 1,048,576 us
  float* olb = deform;                 // alias: deform dead after k_wb
  float* ofb = weights;                // alias: weights dead after k_scan

  k_cvt<<<2048, 64, 0, stream>>>(Ws_lat, wmf);
  k_deform<<<dim3(256, 8), 256, 0, stream>>>(embedding, W_def, b_def, deform);
  k_wb<<<2048, 512, 0, stream>>>(deform, W_w, b_w, W_b, b_b, W_l, b_l,
                                 weights, biases, leakb);
  k_imp<<<256, 512, 0, stream>>>(impulse, Ws_imp, bs_imp, g_imp, bt_imp, embw);
  k_scan<<<NSCAN, 512, 0, stream>>>(weights, biases, leakb, embw, wmf, bs_lat,
                                    g_lat, bt_lat, olb, onb);
  k_out<<<2048, 512, 0, stream>>>(olb, onb, Ws_out, bs_out, g_out, bt_out,
                                  ofb);
  k_oa<<<32768, 256, 0, stream>>>(ofb, out);
}

// Round 8
// 6675.213 us; speedup vs baseline: 1.9914x; 1.9901x over previous
//
#include <hip/hip_runtime.h>
#include <math.h>

#define NB 4
#define NE 64
#define BE 256          // NB*NE
#define LAT 256
#define NC 512          // channels == window
#define NT 128          // n_frames
#define NDEF 65536      // NC*NT
#define NIMP 4096
#define NF 16           // impulse frames
#define EPSN 1e-8f
#define SPB 4           // sequences per scan block
#define NSCAN 64        // scan blocks (BE/SPB)

typedef unsigned short ushort8 __attribute__((ext_vector_type(8)));
typedef short short8v __attribute__((ext_vector_type(8)));
typedef float f32x4 __attribute__((ext_vector_type(4)));

__device__ __forceinline__ unsigned short f2bf(float f) {
  const unsigned u = __float_as_uint(f);
  return (unsigned short)((u + 0x7FFFu + ((u >> 16) & 1u)) >> 16);  // RNE
}

// ---------------------------------------------------------------------------
// single-barrier block reduction: 512 threads each contribute v[NR]; every
// thread gets the block sum in out[NR]. red is a flat >=8*NR float buffer.
// ---------------------------------------------------------------------------
template <int NR>
__device__ __forceinline__ void blk_reduce1(const float* v, float* out,
                                            float* red) {
  const int tid = threadIdx.x, wave = tid >> 6, lane = tid & 63;
  float s[NR];
#pragma unroll
  for (int i = 0; i < NR; ++i) s[i] = v[i];
#pragma unroll
  for (int off = 32; off; off >>= 1) {
#pragma unroll
    for (int i = 0; i < NR; ++i) s[i] += __shfl_down(s[i], off);
  }
  if (lane == 0) {
#pragma unroll
    for (int i = 0; i < NR; ++i) red[wave * NR + i] = s[i];
  }
  __syncthreads();
#pragma unroll
  for (int i = 0; i < NR; ++i) {
    float a = 0.f;
#pragma unroll
    for (int w = 0; w < 8; ++w) a += red[w * NR + i];
    out[i] = a;
  }
}

// ---------------------------------------------------------------------------
// K0: swizzle Ws_lat (4 x [512 k][512 n] f32) into fragment-major MFMA B-frag
// order, bf16. Fragment (layer, wv, kt, p) lives at
//   Wmf[ ((layer*8+wv)*64 + kt*4 + p)*512 + lane*8 + j ]
//     = bf16( W[layer][kt*32 + (lane>>4)*8 + j][wv*64 + p*16 + (lane&15)] )
// Each fragment = contiguous 1KB -> one global_load_lds(width16) per frag.
// grid 2048 (= ((layer*8+wv)*16+kt)*4+p), block 64.
// ---------------------------------------------------------------------------
__global__ __launch_bounds__(64) void k_cvt(const float* __restrict__ W,
                                            unsigned short* __restrict__ Wmf) {
  const int lane = threadIdx.x;
  const int gg = blockIdx.x;
  const int p = gg & 3;
  const int kt = (gg >> 2) & 15;
  const int wv = (gg >> 6) & 7;
  const int layer = gg >> 9;
  const int col = wv * 64 + p * 16 + (lane & 15);
  const int k0 = kt * 32 + (lane >> 4) * 8;
  ushort8 o;
#pragma unroll
  for (int j = 0; j < 8; ++j)
    o[j] = f2bf(W[((size_t)layer * NC + k0 + j) * NC + col]);
  *reinterpret_cast<ushort8*>(Wmf + ((size_t)gg * 64 + lane) * 8) = o;
}

// ---------------------------------------------------------------------------
// K1: deform = embedding @ W_def + b_def      (256 x 256) @ (256 x 65536)
// ---------------------------------------------------------------------------
__global__ __launch_bounds__(256) void k_deform(
    const float* __restrict__ emb, const float* __restrict__ Wd,
    const float* __restrict__ bd, float* __restrict__ deform) {
  __shared__ float As[32][LAT];
  const int tid = threadIdx.x;
  const int c = blockIdx.x * 256 + tid;
  const int m0 = blockIdx.y * 32;
  for (int i = 0; i < 32; ++i) As[i][tid] = emb[(m0 + i) * LAT + tid];
  __syncthreads();
  float acc[32];
#pragma unroll
  for (int i = 0; i < 32; ++i) acc[i] = 0.f;
  for (int k = 0; k < LAT; k += 4) {
    const float w0 = Wd[(size_t)(k + 0) * NDEF + c];
    const float w1 = Wd[(size_t)(k + 1) * NDEF + c];
    const float w2 = Wd[(size_t)(k + 2) * NDEF + c];
    const float w3 = Wd[(size_t)(k + 3) * NDEF + c];
#pragma unroll
    for (int i = 0; i < 32; ++i) {
      const float4 a = *reinterpret_cast<const float4*>(&As[i][k]);
      acc[i] = fmaf(a.x, w0, acc[i]);
      acc[i] = fmaf(a.y, w1, acc[i]);
      acc[i] = fmaf(a.z, w2, acc[i]);
      acc[i] = fmaf(a.w, w3, acc[i]);
    }
  }
  const float bv = bd[c];
  for (int i = 0; i < 32; ++i)
    deform[(size_t)(m0 + i) * NDEF + c] = acc[i] + bv;
}

// ---------------------------------------------------------------------------
// K2: per-(be,t) rows of deform: unit_norm over channel dim, then
//   weights = x @ W_w + b_w ; biases = x @ W_b + b_b ; leak = sigmoid path.
// ---------------------------------------------------------------------------
__global__ __launch_bounds__(512) void k_wb(
    const float* __restrict__ deform, const float* __restrict__ Ww,
    const float* __restrict__ bw, const float* __restrict__ Wb,
    const float* __restrict__ bb, const float* __restrict__ Wl,
    const float* __restrict__ bl, float* __restrict__ weights,
    float* __restrict__ biases, float* __restrict__ leak) {
  __shared__ float xs[16][NC];
  __shared__ float rno[16], lks[16];
  const int tid = threadIdx.x;
  const int wave = tid >> 6, lane = tid & 63;
  const int be = blockIdx.x >> 3;
  const int t0 = (blockIdx.x & 7) * 16;
  const float* dbase = deform + (size_t)be * NDEF;
  for (int i = 0; i < 16; ++i)
    xs[i][tid] = dbase[(size_t)tid * NT + t0 + i];
  __syncthreads();
  for (int f = wave; f < 16; f += 8) {
    float s = 0.f;
#pragma unroll
    for (int j = 0; j < 8; ++j) {
      const float v = xs[f][lane + 64 * j];
      s = fmaf(v, v, s);
    }
#pragma unroll
    for (int off = 32; off; off >>= 1) s += __shfl_down(s, off);
    if (lane == 0) rno[f] = sqrtf(s);
  }
  __syncthreads();
#pragma unroll
  for (int i = 0; i < 16; ++i) xs[i][tid] = xs[i][tid] / (rno[i] + EPSN);
  __syncthreads();
  for (int f = wave; f < 16; f += 8) {
    float s = 0.f;
#pragma unroll
    for (int j = 0; j < 8; ++j)
      s = fmaf(xs[f][lane + 64 * j], Wl[lane + 64 * j], s);
#pragma unroll
    for (int off = 32; off; off >>= 1) s += __shfl_down(s, off);
    if (lane == 0) lks[f] = s;
  }
  __syncthreads();
  if (tid < 16) {
    const float v = lks[tid] + bl[0];
    leak[(size_t)be * NT + t0 + tid] = 0.1f + 0.98f / (1.f + expf(-v));
  }
  float accw[16], accb[16];
#pragma unroll
  for (int i = 0; i < 16; ++i) { accw[i] = 0.f; accb[i] = 0.f; }
  for (int k = 0; k < NC; k += 2) {
    const float w0 = Ww[(size_t)k * NC + tid];
    const float w1 = Ww[(size_t)(k + 1) * NC + tid];
    const float v0 = Wb[(size_t)k * NC + tid];
    const float v1 = Wb[(size_t)(k + 1) * NC + tid];
#pragma unroll
    for (int i = 0; i < 16; ++i) {
      const float2 a = *reinterpret_cast<const float2*>(&xs[i][k]);
      accw[i] = fmaf(a.x, w0, accw[i]);
      accw[i] = fmaf(a.y, w1, accw[i]);
      accb[i] = fmaf(a.x, v0, accb[i]);
      accb[i] = fmaf(a.y, v1, accb[i]);
    }
  }
  const float bwv = bw[tid], bbv = bb[tid];
  for (int i = 0; i < 16; ++i) {
    const size_t o = ((size_t)be * NT + t0 + i) * NC + tid;
    weights[o] = accw[i] + bwv;
    biases[o] = accb[i] + bbv;
  }
}

// ---------------------------------------------------------------------------
// 16-row tile x (512x512) GEMM helper: xs[16][512] in LDS, thread = column.
// ---------------------------------------------------------------------------
__device__ __forceinline__ void tile_gemm16(const float (*xs)[NC],
                                            const float* __restrict__ W,
                                            int tid, float acc[16]) {
#pragma unroll
  for (int i = 0; i < 16; ++i) acc[i] = 0.f;
  for (int k = 0; k < NC; k += 4) {
    const float w0 = W[(size_t)(k + 0) * NC + tid];
    const float w1 = W[(size_t)(k + 1) * NC + tid];
    const float w2 = W[(size_t)(k + 2) * NC + tid];
    const float w3 = W[(size_t)(k + 3) * NC + tid];
#pragma unroll
    for (int i = 0; i < 16; ++i) {
      const float4 a = *reinterpret_cast<const float4*>(&xs[i][k]);
      acc[i] = fmaf(a.x, w0, acc[i]);
      acc[i] = fmaf(a.y, w1, acc[i]);
      acc[i] = fmaf(a.z, w2, acc[i]);
      acc[i] = fmaf(a.w, w3, acc[i]);
    }
  }
}

// LN (+leaky) stats applied in-place on xs[16][NC]
__device__ __forceinline__ void ln_leaky16(float (*xs)[NC],
                                           const float* __restrict__ g,
                                           const float* __restrict__ bt,
                                           int layer, int tid, float* mu_s,
                                           float* rs_s) {
  const int wave = tid >> 6, lane = tid & 63;
  for (int f = wave; f < 16; f += 8) {
    float s = 0.f, s2 = 0.f;
#pragma unroll
    for (int j = 0; j < 8; ++j) {
      const float v = xs[f][lane + 64 * j];
      s += v;
      s2 = fmaf(v, v, s2);
    }
#pragma unroll
    for (int off = 32; off; off >>= 1) {
      s += __shfl_down(s, off);
      s2 += __shfl_down(s2, off);
    }
    if (lane == 0) {
      const float mu = s * (1.f / NC);
      mu_s[f] = mu;
      rs_s[f] = rsqrtf(s2 * (1.f / NC) - mu * mu + 1e-5f);
    }
  }
  __syncthreads();
  const float gv = g[layer * NC + tid], btv = bt[layer * NC + tid];
#pragma unroll
  for (int i = 0; i < 16; ++i) {
    const float y = (xs[i][tid] - mu_s[i]) * rs_s[i] * gv + btv;
    xs[i][tid] = y > 0.f ? y : 0.2f * y;
  }
  __syncthreads();
}

// ---------------------------------------------------------------------------
// K3: windowed impulse -> mlp_imp -> unit_norm * window-norm -> emb stream.
// ---------------------------------------------------------------------------
__global__ __launch_bounds__(512) void k_imp(
    const float* __restrict__ impulse, const float* __restrict__ Ws,
    const float* __restrict__ bs, const float* __restrict__ g,
    const float* __restrict__ bt, float* __restrict__ embo) {
  __shared__ float xs[16][NC];
  __shared__ float wno[16], mu_s[16], rs_s[16], ono[16];
  const int tid = threadIdx.x;
  const int wave = tid >> 6, lane = tid & 63;
  const int be = blockIdx.x;
  const float* ib = impulse + (size_t)be * NIMP;
  for (int f = 0; f < 16; ++f) {
    const int s = f * 256 + tid;
    xs[f][tid] = (s < NIMP) ? ib[s] : 0.f;
  }
  __syncthreads();
  for (int f = wave; f < 16; f += 8) {
    float s = 0.f;
#pragma unroll
    for (int j = 0; j < 8; ++j) {
      const float v = xs[f][lane + 64 * j];
      s = fmaf(v, v, s);
    }
#pragma unroll
    for (int off = 32; off; off >>= 1) s += __shfl_down(s, off);
    if (lane == 0) wno[f] = sqrtf(s);
  }
  __syncthreads();
  float acc[16];
  for (int layer = 0; layer < 4; ++layer) {
    tile_gemm16(xs, Ws + (size_t)layer * NC * NC, tid, acc);
    __syncthreads();
    const float bv = bs[layer * NC + tid];
#pragma unroll
    for (int i = 0; i < 16; ++i) xs[i][tid] = acc[i] + bv;
    __syncthreads();
    if (layer < 3) ln_leaky16(xs, g, bt, layer, tid, mu_s, rs_s);
  }
  for (int f = wave; f < 16; f += 8) {
    float s = 0.f;
#pragma unroll
    for (int j = 0; j < 8; ++j) {
      const float v = xs[f][lane + 64 * j];
      s = fmaf(v, v, s);
    }
#pragma unroll
    for (int off = 32; off; off >>= 1) s += __shfl_down(s, off);
    if (lane == 0) ono[f] = sqrtf(s);
  }
  __syncthreads();
  for (int f = 0; f < 16; ++f)
    embo[((size_t)be * NF + f) * NC + tid] =
        xs[f][tid] / (ono[f] + EPSN) * wno[f];
}

// ---------------------------------------------------------------------------
// K4: the sequential scan, MFMA v6: async global_load_lds weight staging.
// 64 blocks x 512 threads; 4 seqs/block. Per wave, the B-fragment stream is
// DMA'd into 3 rotating private LDS slots (chunk = 4 frags = 4KB, one
// global_load_lds width-16 per frag), counted vmcnt(8/4/0) keeps 2 chunks in
// flight across the MFMA consumption (T3/T4 pattern) -- the compiler cannot
// serialize these as it did the register-pipeline versions (R4-R7 all ran at
// 256 serial miss-latencies/t = 84us/t regardless of source pipelining).
// Slot reuse (kt+3 -> slot (kt-1)%3) is safe: issued after chunk kt's
// ds_reads, and the LDS queue is in-order.
// ---------------------------------------------------------------------------
__global__ __launch_bounds__(512) void k_scan(
    const float* __restrict__ weights, const float* __restrict__ biases,
    const float* __restrict__ leak, const float* __restrict__ embw,
    const unsigned short* __restrict__ Wmf, const float* __restrict__ bs,
    const float* __restrict__ g, const float* __restrict__ bt,
    float* __restrict__ olb, float* __restrict__ onb) {
  __shared__ __align__(16) unsigned short A_lds[16 * NC];     // 16KB
  __shared__ __align__(16) unsigned short B_lds[8][3][2048];  // 96KB
  __shared__ float ol_lds[SPB][NC];                           // 8KB
  __shared__ float redA[64];
  __shared__ float redB[32];
  __shared__ float st1[8][SPB], st2[8][SPB];
  __shared__ float lk_lds[SPB][NT];

  const int tid = threadIdx.x;
  const int wave = tid >> 6, lane = tid & 63;
  const int seq0 = blockIdx.x * SPB;

  // stage leak slice (one element per thread)
  {
    const int r = tid >> 7, tt = tid & 127;
    lk_lds[r][tt] = leak[(size_t)(seq0 + r) * NT + tt];
  }
  // zero the pad rows 4..15 of A (never written again)
  {
    unsigned* z = (unsigned*)(A_lds + SPB * NC);
    for (int i = tid; i < (16 - SPB) * NC / 2; i += 512) z[i] = 0u;
  }

  // per-lane MFMA geometry
  const int arow = lane & 15;
  const int kgrp = lane >> 4;
  const int abase = arow * (NC * 2);
  const int axor = (arow & 7) << 4;
  const int akoff = kgrp * 16;
  const bool crow = (kgrp == 0);  // lanes holding C rows 0..3

  // hoist per-lane (t-invariant) bias / LN params for this wave's 4 n-tiles
  float bsv[4][4], gv[3][4], btv[3][4];
#pragma unroll
  for (int p = 0; p < 4; ++p) {
    const int cp = wave * 64 + p * 16 + (lane & 15);
#pragma unroll
    for (int l = 0; l < 4; ++l) bsv[l][p] = bs[l * NC + cp];
#pragma unroll
    for (int l = 0; l < 3; ++l) {
      gv[l][p] = g[l * NC + cp];
      btv[l][p] = bt[l * NC + cp];
    }
  }
  // this wave's fragment stream: fragment (layer,kt,p) at
  //   wfrag + layer*262144 + (kt*4+p)*512   (per-lane 16B at +lane*8)
  const unsigned short* wfrag = Wmf + (size_t)wave * 32768 + lane * 8;

  // DMA one 4KB chunk (4 fragments) of (layer,kt) into slot kt%3
  auto issue_chunk = [&](int layer, int kt) {
    const int slot = kt % 3;
#pragma unroll
    for (int p = 0; p < 4; ++p) {
      __builtin_amdgcn_global_load_lds(
          (const unsigned int*)(wfrag + (size_t)layer * 262144 +
                                (kt * 4 + p) * 512),
          (unsigned int*)&B_lds[wave][slot][p * 512], 16, 0, 0);
    }
  };

  // one 16x512x512 layer GEMM, DMA-pipelined
  auto do_layer = [&](int layer, f32x4 (&acc)[4]) {
#pragma unroll
    for (int p = 0; p < 4; ++p) acc[p] = (f32x4){0.f, 0.f, 0.f, 0.f};
    issue_chunk(layer, 0);
    issue_chunk(layer, 1);
    issue_chunk(layer, 2);
#pragma unroll
    for (int kt = 0; kt < 16; ++kt) {
      if (kt < 14) {
        asm volatile("s_waitcnt vmcnt(8)" ::: "memory");
      } else if (kt == 14) {
        asm volatile("s_waitcnt vmcnt(4)" ::: "memory");
      } else {
        asm volatile("s_waitcnt vmcnt(0)" ::: "memory");
      }
      const short8v a = *(const short8v*)((const char*)A_lds + abase +
                                          (((kt * 64) + akoff) ^ axor));
      const int slot = kt % 3;
#pragma unroll
      for (int p = 0; p < 4; ++p) {
        const short8v b = *(const short8v*)((const char*)&B_lds[wave][slot][0] +
                                            p * 1024 + lane * 16);
        acc[p] = __builtin_amdgcn_mfma_f32_16x16x32_bf16(a, b, acc[p], 0, 0, 0);
      }
      if (kt + 3 < 16) issue_chunk(layer, kt + 3);
    }
  };

  // initial prefetch for t=0
  float wpre[SPB], bpre[SPB], epre[SPB];
#pragma unroll
  for (int r = 0; r < SPB; ++r) {
    const size_t o = ((size_t)(seq0 + r) * NT) * NC + tid;
    wpre[r] = weights[o];
    bpre[r] = biases[o];
    epre[r] = embw[((size_t)(seq0 + r) * NF) * NC + tid];
  }

  __syncthreads();

  float h[SPB], cn[SPB];
#pragma unroll
  for (int r = 0; r < SPB; ++r) { h[r] = 0.f; cn[r] = 0.f; }

#pragma unroll 1
  for (int t = 0; t < NT; ++t) {
    float hw[SPB];
    if (t < NF) {
#pragma unroll
      for (int r = 0; r < SPB; ++r) h[r] += epre[r];
      if (t + 1 < NF) {
#pragma unroll
        for (int r = 0; r < SPB; ++r)
          epre[r] = embw[((size_t)(seq0 + r) * NF + t + 1) * NC + tid];
      }
      float v8[8], s8[8];
#pragma unroll
      for (int r = 0; r < SPB; ++r) {
        hw[r] = fmaf(h[r], wpre[r], bpre[r]);
        v8[r] = h[r] * h[r];
        v8[SPB + r] = hw[r] * hw[r];
      }
      blk_reduce1<8>(v8, s8, redA);
#pragma unroll
      for (int r = 0; r < SPB; ++r) {
        cn[r] = sqrtf(s8[r]);
        h[r] = hw[r] * (cn[r] / (sqrtf(s8[SPB + r]) + EPSN));
      }
    } else {
      float v4[SPB], s4[SPB];
#pragma unroll
      for (int r = 0; r < SPB; ++r) {
        hw[r] = fmaf(h[r], wpre[r], bpre[r]);
        v4[r] = hw[r] * hw[r];
      }
      blk_reduce1<SPB>(v4, s4, redA);
#pragma unroll
      for (int r = 0; r < SPB; ++r)
        h[r] = hw[r] * (cn[r] / (sqrtf(s4[r]) + EPSN));
    }
    // prefetch weights/biases for t+1 (hidden under pack + layer 0 prologue)
    if (t + 1 < NT) {
#pragma unroll
      for (int r = 0; r < SPB; ++r) {
        const size_t o = ((size_t)(seq0 + r) * NT + t + 1) * NC + tid;
        wpre[r] = weights[o];
        bpre[r] = biases[o];
      }
    }
    // pack x -> A rows 0..3 (bf16, swizzled)
    {
      char* ab = (char*)A_lds;
#pragma unroll
      for (int r = 0; r < SPB; ++r)
        *(unsigned short*)(ab + r * 1024 + ((tid * 2) ^ ((r & 7) << 4))) =
            f2bf(h[r]);
    }
    __syncthreads();

    // ---- 3 hidden layers ----
#pragma unroll 1
    for (int layer = 0; layer < 3; ++layer) {
      f32x4 acc[4];
      do_layer(layer, acc);
      float s1[SPB], s2[SPB];
#pragma unroll
      for (int q = 0; q < SPB; ++q) { s1[q] = 0.f; s2[q] = 0.f; }
#pragma unroll
      for (int p = 0; p < 4; ++p) {
#pragma unroll
        for (int q = 0; q < SPB; ++q) {
          const float y = acc[p][q] + bsv[layer][p];
          acc[p][q] = y;
          s1[q] += y;
          s2[q] = fmaf(y, y, s2[q]);
        }
      }
#pragma unroll
      for (int off = 1; off < 16; off <<= 1) {
#pragma unroll
        for (int q = 0; q < SPB; ++q) {
          s1[q] += __shfl_xor(s1[q], off);
          s2[q] += __shfl_xor(s2[q], off);
        }
      }
      if (lane == 0) {
#pragma unroll
        for (int q = 0; q < SPB; ++q) {
          st1[wave][q] = s1[q];
          st2[wave][q] = s2[q];
        }
      }
      __syncthreads();
      float mu[SPB], rs[SPB];
#pragma unroll
      for (int q = 0; q < SPB; ++q) {
        float a1 = 0.f, a2 = 0.f;
#pragma unroll
        for (int w = 0; w < 8; ++w) {
          a1 += st1[w][q];
          a2 += st2[w][q];
        }
        mu[q] = a1 * (1.f / NC);
        rs[q] = rsqrtf(a2 * (1.f / NC) - mu[q] * mu[q] + 1e-5f);
      }
      if (crow) {
        char* ab = (char*)A_lds;
#pragma unroll
        for (int q = 0; q < SPB; ++q) {
#pragma unroll
          for (int p = 0; p < 4; ++p) {
            float y = (acc[p][q] - mu[q]) * rs[q] * gv[layer][p] +
                      btv[layer][p];
            y = y > 0.f ? y : 0.2f * y;
            const int cp = wave * 64 + p * 16 + (lane & 15);
            *(unsigned short*)(ab + q * 1024 +
                               ((cp * 2) ^ ((q & 7) << 4))) = f2bf(y);
          }
        }
      }
      __syncthreads();
    }

    // ---- final linear -> ol; epilogue ----
    {
      f32x4 acc[4];
      do_layer(3, acc);
      float s2[SPB];
#pragma unroll
      for (int q = 0; q < SPB; ++q) s2[q] = 0.f;
#pragma unroll
      for (int p = 0; p < 4; ++p) {
#pragma unroll
        for (int q = 0; q < SPB; ++q) {
          const float y = acc[p][q] + bsv[3][p];
          acc[p][q] = y;
          s2[q] = fmaf(y, y, s2[q]);
        }
      }
#pragma unroll
      for (int off = 1; off < 16; off <<= 1) {
#pragma unroll
        for (int q = 0; q < SPB; ++q) s2[q] += __shfl_xor(s2[q], off);
      }
      if (lane == 0) {
#pragma unroll
        for (int q = 0; q < SPB; ++q) st2[wave][q] = s2[q];
      }
      if (crow) {
#pragma unroll
        for (int q = 0; q < SPB; ++q) {
#pragma unroll
          for (int p = 0; p < 4; ++p)
            ol_lds[q][wave * 64 + p * 16 + (lane & 15)] = acc[p][q];
        }
      }
      __syncthreads();
      float sc[SPB], on[SPB];
#pragma unroll
      for (int r = 0; r < SPB; ++r) {
        float a2 = 0.f;
#pragma unroll
        for (int w = 0; w < 8; ++w) a2 += st2[w][r];
        const float no = sqrtf(a2);
        sc[r] = cn[r] * lk_lds[r][t] / (no + EPSN);
        on[r] = no * sc[r];
      }
      if (tid < SPB) onb[(size_t)(seq0 + tid) * NT + t] = on[tid];
      float v4[SPB], s4[SPB];
#pragma unroll
      for (int r = 0; r < SPB; ++r) {
        const float olv = ol_lds[r][tid] * sc[r];
        olb[((size_t)(seq0 + r) * NT + t) * NC + tid] = olv;
        h[r] -= olv;
        v4[r] = h[r] * h[r];
      }
      blk_reduce1<SPB>(v4, s4, redB);
#pragma unroll
      for (int r = 0; r < SPB; ++r) {
        h[r] *= (cn[r] - on[r]) / (sqrtf(s4[r]) + EPSN);
        cn[r] = fabsf(cn[r] - on[r]);  // ||h|| carried exactly
      }
    }
  }
}

// ---------------------------------------------------------------------------
// K5: batched out-MLP on all 32768 ol rows: of = unit_norm(mlp_out(ol)*ham)*on
// ---------------------------------------------------------------------------
__global__ __launch_bounds__(512) void k_out(
    const float* __restrict__ olb, const float* __restrict__ onb,
    const float* __restrict__ Ws, const float* __restrict__ bs,
    const float* __restrict__ g, const float* __restrict__ bt,
    float* __restrict__ ofb) {
  __shared__ float xs[16][NC];
  __shared__ float mu_s[16], rs_s[16], ono[16];
  const int tid = threadIdx.x;
  const int wave = tid >> 6, lane = tid & 63;
  const int m0 = blockIdx.x * 16;
  for (int i = 0; i < 16; ++i)
    xs[i][tid] = olb[(size_t)(m0 + i) * NC + tid];
  __syncthreads();
  float acc[16];
  for (int layer = 0; layer < 4; ++layer) {
    tile_gemm16(xs, Ws + (size_t)layer * NC * NC, tid, acc);
    __syncthreads();
    const float bv = bs[layer * NC + tid];
#pragma unroll
    for (int i = 0; i < 16; ++i) xs[i][tid] = acc[i] + bv;
    __syncthreads();
    if (layer < 3) ln_leaky16(xs, g, bt, layer, tid, mu_s, rs_s);
  }
  const float ham =
      0.54f - 0.46f * cosf(6.283185307179586f * (float)tid / (float)NC);
#pragma unroll
  for (int i = 0; i < 16; ++i) xs[i][tid] *= ham;
  __syncthreads();
  for (int f = wave; f < 16; f += 8) {
    float s = 0.f;
#pragma unroll
    for (int j = 0; j < 8; ++j) {
      const float vv = xs[f][lane + 64 * j];
      s = fmaf(vv, vv, s);
    }
#pragma unroll
    for (int off = 32; off; off >>= 1) s += __shfl_down(s, off);
    if (lane == 0) ono[f] = sqrtf(s);
  }
  __syncthreads();
  for (int i = 0; i < 16; ++i) {
    const float onv = onb[m0 + i];
    ofb[(size_t)(m0 + i) * NC + tid] = xs[i][tid] / (ono[i] + EPSN) * onv;
  }
}

// ---------------------------------------------------------------------------
// K6: overlap-add at hop 256, trim to 32768.
// ---------------------------------------------------------------------------
__global__ __launch_bounds__(256) void k_oa(const float* __restrict__ ofb,
                                            float* __restrict__ out) {
  const int idx = blockIdx.x * 256 + threadIdx.x;
  if (idx >= BE * 32768) return;
  const int be = idx >> 15;
  const int s = idx & 32767;
  const int t1 = s >> 8;
  float v = ofb[((size_t)be * NT + t1) * NC + (s - (t1 << 8))];
  if (t1 >= 1)
    v += ofb[((size_t)be * NT + (t1 - 1)) * NC + (s - ((t1 - 1) << 8))];
  out[idx] = v;
}

// ---------------------------------------------------------------------------
// Workspace (< 256 MiB): region A (deform->olb) 64 MiB, region B
// (weights->ofb) 64 MiB, region C (biases) 64 MiB, small buffers ~12 MiB.
// ---------------------------------------------------------------------------
extern "C" void kernel_launch(void* const* d_in, const int* in_sizes, int n_in,
                              void* d_out, int out_size, void* d_ws,
                              size_t ws_size, hipStream_t stream) {
  const float* embedding = (const float*)d_in[0];
  const float* impulse = (const float*)d_in[1];
  const float* W_def = (const float*)d_in[2];
  const float* b_def = (const float*)d_in[3];
  const float* W_w = (const float*)d_in[4];
  const float* b_w = (const float*)d_in[5];
  const float* W_b = (const float*)d_in[6];
  const float* b_b = (const float*)d_in[7];
  const float* W_l = (const float*)d_in[8];
  const float* b_l = (const float*)d_in[9];
  const float* Ws_imp = (const float*)d_in[10];
  const float* bs_imp = (const float*)d_in[11];
  const float* g_imp = (const float*)d_in[12];
  const float* bt_imp = (const float*)d_in[13];
  const float* Ws_lat = (const float*)d_in[14];
  const float* bs_lat = (const float*)d_in[15];
  const float* g_lat = (const float*)d_in[16];
  const float* bt_lat = (const float*)d_in[17];
  const float* Ws_out = (const float*)d_in[18];
  const float* bs_out = (const float*)d_in[19];
  const float* g_out = (const float*)d_in[20];
  const float* bt_out = (const float*)d_in[21];
  float* out = (float*)d_out;

  float* ws = (float*)d_ws;
  float* deform = ws;                  // region A (reused as olb)
  float* weights = deform + 16777216;  // region B (reused as ofb)
  float* biases = weights + 16777216;  // region C
  float* leakb = biases + 16777216;    // 32,768 f
  float* embw = leakb + 32768;         // 2,097,152 f
  float* onb = embw + 2097152;         // 32,768 f
  unsigned short* wmf = (unsigned short*)(onb + 32768);  // 1,048,576 us
  float* olb = deform;                 // alias: deform dead after k_wb
  float* ofb = weights;                // alias: weights dead after k_scan

  k_cvt<<<2048, 64, 0, stream>>>(Ws_lat, wmf);
  k_deform<<<dim3(256, 8), 256, 0, stream>>>(embedding, W_def, b_def, deform);
  k_wb<<<2048, 512, 0, stream>>>(deform, W_w, b_w, W_b, b_b, W_l, b_l,
                                 weights, biases, leakb);
  k_imp<<<256, 512, 0, stream>>>(impulse, Ws_imp, bs_imp, g_imp, bt_imp, embw);
  k_scan<<<NSCAN, 512, 0, stream>>>(weights, biases, leakb, embw, wmf, bs_lat,
                                    g_lat, bt_lat, olb, onb);
  k_out<<<2048, 512, 0, stream>>>(olb, onb, Ws_out, bs_out, g_out, bt_out,
                                  ofb);
  k_oa<<<32768, 256, 0, stream>>>(ofb, out);
}

// Round 10
// 5999.339 us; speedup vs baseline: 2.2158x; 1.1127x over previous
//
#include <hip/hip_runtime.h>
#include <math.h>

#define NB 4
#define NE 64
#define BE 256          // NB*NE
#define LAT 256
#define NC 512          // channels == window
#define NT 128          // n_frames
#define NDEF 65536      // NC*NT
#define NIMP 4096
#define NF 16           // impulse frames
#define EPSN 1e-8f
#define SPB 4           // sequences per scan block
#define NSCAN 64        // scan blocks (BE/SPB)

typedef unsigned short ushort8 __attribute__((ext_vector_type(8)));
typedef short short8v __attribute__((ext_vector_type(8)));
typedef float f32x4 __attribute__((ext_vector_type(4)));

__device__ __forceinline__ unsigned short f2bf(float f) {
  const unsigned u = __float_as_uint(f);
  return (unsigned short)((u + 0x7FFFu + ((u >> 16) & 1u)) >> 16);  // RNE
}

// raw barrier WITHOUT the vmcnt(0) drain __syncthreads emits: ds-writes are
// made visible via lgkmcnt(0); in-flight global_load_lds DMA (wave-private
// destinations) stays in flight. sched_barrier(0) pins ordering (rule #18).
__device__ __forceinline__ void bar_nodrain() {
  asm volatile("s_waitcnt lgkmcnt(0)" ::: "memory");
  __builtin_amdgcn_s_barrier();
  __builtin_amdgcn_sched_barrier(0);
}

// ---------------------------------------------------------------------------
// single-raw-barrier block reduction (used only inside k_scan's t-loop).
// ---------------------------------------------------------------------------
template <int NR>
__device__ __forceinline__ void blk_reduce1(const float* v, float* out,
                                            float* red) {
  const int tid = threadIdx.x, wave = tid >> 6, lane = tid & 63;
  float s[NR];
#pragma unroll
  for (int i = 0; i < NR; ++i) s[i] = v[i];
#pragma unroll
  for (int off = 32; off; off >>= 1) {
#pragma unroll
    for (int i = 0; i < NR; ++i) s[i] += __shfl_down(s[i], off);
  }
  if (lane == 0) {
#pragma unroll
    for (int i = 0; i < NR; ++i) red[wave * NR + i] = s[i];
  }
  bar_nodrain();
#pragma unroll
  for (int i = 0; i < NR; ++i) {
    float a = 0.f;
#pragma unroll
    for (int w = 0; w < 8; ++w) a += red[w * NR + i];
    out[i] = a;
  }
}

// ---------------------------------------------------------------------------
// K0: swizzle Ws_lat (4 x [512 k][512 n] f32) into fragment-major MFMA B-frag
// order, bf16. Fragment (layer, wv, kt, p) lives at
//   Wmf[ ((layer*8+wv)*64 + kt*4 + p)*512 + lane*8 + j ]
//     = bf16( W[layer][kt*32 + (lane>>4)*8 + j][wv*64 + p*16 + (lane&15)] )
// Each fragment = contiguous 1KB -> one global_load_lds(width16) per frag.
// grid 2048, block 64.
// ---------------------------------------------------------------------------
__global__ __launch_bounds__(64) void k_cvt(const float* __restrict__ W,
                                            unsigned short* __restrict__ Wmf) {
  const int lane = threadIdx.x;
  const int gg = blockIdx.x;
  const int p = gg & 3;
  const int kt = (gg >> 2) & 15;
  const int wv = (gg >> 6) & 7;
  const int layer = gg >> 9;
  const int col = wv * 64 + p * 16 + (lane & 15);
  const int k0 = kt * 32 + (lane >> 4) * 8;
  ushort8 o;
#pragma unroll
  for (int j = 0; j < 8; ++j)
    o[j] = f2bf(W[((size_t)layer * NC + k0 + j) * NC + col]);
  *reinterpret_cast<ushort8*>(Wmf + ((size_t)gg * 64 + lane) * 8) = o;
}

// ---------------------------------------------------------------------------
// K1: deform = embedding @ W_def + b_def      (256 x 256) @ (256 x 65536)
// ---------------------------------------------------------------------------
__global__ __launch_bounds__(256) void k_deform(
    const float* __restrict__ emb, const float* __restrict__ Wd,
    const float* __restrict__ bd, float* __restrict__ deform) {
  __shared__ float As[32][LAT];
  const int tid = threadIdx.x;
  const int c = blockIdx.x * 256 + tid;
  const int m0 = blockIdx.y * 32;
  for (int i = 0; i < 32; ++i) As[i][tid] = emb[(m0 + i) * LAT + tid];
  __syncthreads();
  float acc[32];
#pragma unroll
  for (int i = 0; i < 32; ++i) acc[i] = 0.f;
  for (int k = 0; k < LAT; k += 4) {
    const float w0 = Wd[(size_t)(k + 0) * NDEF + c];
    const float w1 = Wd[(size_t)(k + 1) * NDEF + c];
    const float w2 = Wd[(size_t)(k + 2) * NDEF + c];
    const float w3 = Wd[(size_t)(k + 3) * NDEF + c];
#pragma unroll
    for (int i = 0; i < 32; ++i) {
      const float4 a = *reinterpret_cast<const float4*>(&As[i][k]);
      acc[i] = fmaf(a.x, w0, acc[i]);
      acc[i] = fmaf(a.y, w1, acc[i]);
      acc[i] = fmaf(a.z, w2, acc[i]);
      acc[i] = fmaf(a.w, w3, acc[i]);
    }
  }
  const float bv = bd[c];
  for (int i = 0; i < 32; ++i)
    deform[(size_t)(m0 + i) * NDEF + c] = acc[i] + bv;
}

// ---------------------------------------------------------------------------
// K2: per-(be,t) rows of deform: unit_norm over channel dim, then
//   weights = x @ W_w + b_w ; biases = x @ W_b + b_b ; leak = sigmoid path.
// ---------------------------------------------------------------------------
__global__ __launch_bounds__(512) void k_wb(
    const float* __restrict__ deform, const float* __restrict__ Ww,
    const float* __restrict__ bw, const float* __restrict__ Wb,
    const float* __restrict__ bb, const float* __restrict__ Wl,
    const float* __restrict__ bl, float* __restrict__ weights,
    float* __restrict__ biases, float* __restrict__ leak) {
  __shared__ float xs[16][NC];
  __shared__ float rno[16], lks[16];
  const int tid = threadIdx.x;
  const int wave = tid >> 6, lane = tid & 63;
  const int be = blockIdx.x >> 3;
  const int t0 = (blockIdx.x & 7) * 16;
  const float* dbase = deform + (size_t)be * NDEF;
  for (int i = 0; i < 16; ++i)
    xs[i][tid] = dbase[(size_t)tid * NT + t0 + i];
  __syncthreads();
  for (int f = wave; f < 16; f += 8) {
    float s = 0.f;
#pragma unroll
    for (int j = 0; j < 8; ++j) {
      const float v = xs[f][lane + 64 * j];
      s = fmaf(v, v, s);
    }
#pragma unroll
    for (int off = 32; off; off >>= 1) s += __shfl_down(s, off);
    if (lane == 0) rno[f] = sqrtf(s);
  }
  __syncthreads();
#pragma unroll
  for (int i = 0; i < 16; ++i) xs[i][tid] = xs[i][tid] / (rno[i] + EPSN);
  __syncthreads();
  for (int f = wave; f < 16; f += 8) {
    float s = 0.f;
#pragma unroll
    for (int j = 0; j < 8; ++j)
      s = fmaf(xs[f][lane + 64 * j], Wl[lane + 64 * j], s);
#pragma unroll
    for (int off = 32; off; off >>= 1) s += __shfl_down(s, off);
    if (lane == 0) lks[f] = s;
  }
  __syncthreads();
  if (tid < 16) {
    const float v = lks[tid] + bl[0];
    leak[(size_t)be * NT + t0 + tid] = 0.1f + 0.98f / (1.f + expf(-v));
  }
  float accw[16], accb[16];
#pragma unroll
  for (int i = 0; i < 16; ++i) { accw[i] = 0.f; accb[i] = 0.f; }
  for (int k = 0; k < NC; k += 2) {
    const float w0 = Ww[(size_t)k * NC + tid];
    const float w1 = Ww[(size_t)(k + 1) * NC + tid];
    const float v0 = Wb[(size_t)k * NC + tid];
    const float v1 = Wb[(size_t)(k + 1) * NC + tid];
#pragma unroll
    for (int i = 0; i < 16; ++i) {
      const float2 a = *reinterpret_cast<const float2*>(&xs[i][k]);
      accw[i] = fmaf(a.x, w0, accw[i]);
      accw[i] = fmaf(a.y, w1, accw[i]);
      accb[i] = fmaf(a.x, v0, accb[i]);
      accb[i] = fmaf(a.y, v1, accb[i]);
    }
  }
  const float bwv = bw[tid], bbv = bb[tid];
  for (int i = 0; i < 16; ++i) {
    const size_t o = ((size_t)be * NT + t0 + i) * NC + tid;
    weights[o] = accw[i] + bwv;
    biases[o] = accb[i] + bbv;
  }
}

// ---------------------------------------------------------------------------
// 16-row tile x (512x512) GEMM helper (f32, used by k_imp and k_out).
// ---------------------------------------------------------------------------
__device__ __forceinline__ void tile_gemm16(const float (*xs)[NC],
                                            const float* __restrict__ W,
                                            int tid, float acc[16]) {
#pragma unroll
  for (int i = 0; i < 16; ++i) acc[i] = 0.f;
  for (int k = 0; k < NC; k += 4) {
    const float w0 = W[(size_t)(k + 0) * NC + tid];
    const float w1 = W[(size_t)(k + 1) * NC + tid];
    const float w2 = W[(size_t)(k + 2) * NC + tid];
    const float w3 = W[(size_t)(k + 3) * NC + tid];
#pragma unroll
    for (int i = 0; i < 16; ++i) {
      const float4 a = *reinterpret_cast<const float4*>(&xs[i][k]);
      acc[i] = fmaf(a.x, w0, acc[i]);
      acc[i] = fmaf(a.y, w1, acc[i]);
      acc[i] = fmaf(a.z, w2, acc[i]);
      acc[i] = fmaf(a.w, w3, acc[i]);
    }
  }
}

// LN (+leaky) stats applied in-place on xs[16][NC]
__device__ __forceinline__ void ln_leaky16(float (*xs)[NC],
                                           const float* __restrict__ g,
                                           const float* __restrict__ bt,
                                           int layer, int tid, float* mu_s,
                                           float* rs_s) {
  const int wave = tid >> 6, lane = tid & 63;
  for (int f = wave; f < 16; f += 8) {
    float s = 0.f, s2 = 0.f;
#pragma unroll
    for (int j = 0; j < 8; ++j) {
      const float v = xs[f][lane + 64 * j];
      s += v;
      s2 = fmaf(v, v, s2);
    }
#pragma unroll
    for (int off = 32; off; off >>= 1) {
      s += __shfl_down(s, off);
      s2 += __shfl_down(s2, off);
    }
    if (lane == 0) {
      const float mu = s * (1.f / NC);
      mu_s[f] = mu;
      rs_s[f] = rsqrtf(s2 * (1.f / NC) - mu * mu + 1e-5f);
    }
  }
  __syncthreads();
  const float gv = g[layer * NC + tid], btv = bt[layer * NC + tid];
#pragma unroll
  for (int i = 0; i < 16; ++i) {
    const float y = (xs[i][tid] - mu_s[i]) * rs_s[i] * gv + btv;
    xs[i][tid] = y > 0.f ? y : 0.2f * y;
  }
  __syncthreads();
}

// ---------------------------------------------------------------------------
// K3: windowed impulse -> mlp_imp -> unit_norm * window-norm -> emb stream.
// ---------------------------------------------------------------------------
__global__ __launch_bounds__(512) void k_imp(
    const float* __restrict__ impulse, const float* __restrict__ Ws,
    const float* __restrict__ bs, const float* __restrict__ g,
    const float* __restrict__ bt, float* __restrict__ embo) {
  __shared__ float xs[16][NC];
  __shared__ float wno[16], mu_s[16], rs_s[16], ono[16];
  const int tid = threadIdx.x;
  const int wave = tid >> 6, lane = tid & 63;
  const int be = blockIdx.x;
  const float* ib = impulse + (size_t)be * NIMP;
  for (int f = 0; f < 16; ++f) {
    const int s = f * 256 + tid;
    xs[f][tid] = (s < NIMP) ? ib[s] : 0.f;
  }
  __syncthreads();
  for (int f = wave; f < 16; f += 8) {
    float s = 0.f;
#pragma unroll
    for (int j = 0; j < 8; ++j) {
      const float v = xs[f][lane + 64 * j];
      s = fmaf(v, v, s);
    }
#pragma unroll
    for (int off = 32; off; off >>= 1) s += __shfl_down(s, off);
    if (lane == 0) wno[f] = sqrtf(s);
  }
  __syncthreads();
  float acc[16];
  for (int layer = 0; layer < 4; ++layer) {
    tile_gemm16(xs, Ws + (size_t)layer * NC * NC, tid, acc);
    __syncthreads();
    const float bv = bs[layer * NC + tid];
#pragma unroll
    for (int i = 0; i < 16; ++i) xs[i][tid] = acc[i] + bv;
    __syncthreads();
    if (layer < 3) ln_leaky16(xs, g, bt, layer, tid, mu_s, rs_s);
  }
  for (int f = wave; f < 16; f += 8) {
    float s = 0.f;
#pragma unroll
    for (int j = 0; j < 8; ++j) {
      const float v = xs[f][lane + 64 * j];
      s = fmaf(v, v, s);
    }
#pragma unroll
    for (int off = 32; off; off >>= 1) s += __shfl_down(s, off);
    if (lane == 0) ono[f] = sqrtf(s);
  }
  __syncthreads();
  for (int f = 0; f < 16; ++f)
    embo[((size_t)be * NF + f) * NC + tid] =
        xs[f][tid] / (ono[f] + EPSN) * wno[f];
}

// ---------------------------------------------------------------------------
// K4: the sequential scan, MFMA v8: HARDENED continuous DMA ring.
// 4 LDS slots/wave but only 3 chunks in flight: prime chunks 0,1,2; at ring
// step cc consume slot cc&3 then issue chunk cc+3, which overwrites the slot
// read at step cc-1 (one full iteration of distance, vs distance-0 in
// R8/R9 — closes the LDS-pipe write-vs-queued-read window). Steady wait
// vmcnt(8) = 2 chunks outstanding; extra interleaved vm ops (prefetch,
// stores) only add conservatism. Raw no-drain barriers keep DMA flowing
// through LN/reduce phases.
// ---------------------------------------------------------------------------
__global__ __launch_bounds__(512) void k_scan(
    const float* __restrict__ weights, const float* __restrict__ biases,
    const float* __restrict__ leak, const float* __restrict__ embw,
    const unsigned short* __restrict__ Wmf, const float* __restrict__ bs,
    const float* __restrict__ g, const float* __restrict__ bt,
    float* __restrict__ olb, float* __restrict__ onb) {
  __shared__ __align__(16) unsigned short A_lds[16 * NC];     // 16KB
  __shared__ __align__(16) unsigned short B_lds[8][4][2048];  // 128KB
  __shared__ float ol_lds[SPB][NC];                           // 8KB
  __shared__ float redA[64];
  __shared__ float redB[32];
  __shared__ float st1[8][SPB], st2[8][SPB];
  __shared__ float lk_lds[SPB][NT];

  const int tid = threadIdx.x;
  const int wave = tid >> 6, lane = tid & 63;
  const int seq0 = blockIdx.x * SPB;

  // stage leak slice (one element per thread)
  {
    const int r = tid >> 7, tt = tid & 127;
    lk_lds[r][tt] = leak[(size_t)(seq0 + r) * NT + tt];
  }
  // zero the pad rows 4..15 of A (never written again)
  {
    unsigned* z = (unsigned*)(A_lds + SPB * NC);
    for (int i = tid; i < (16 - SPB) * NC / 2; i += 512) z[i] = 0u;
  }

  // per-lane MFMA geometry
  const int arow = lane & 15;
  const int kgrp = lane >> 4;
  const int abase = arow * (NC * 2);
  const int axor = (arow & 7) << 4;
  const int akoff = kgrp * 16;
  const bool crow = (kgrp == 0);  // lanes holding C rows 0..3

  // hoist per-lane (t-invariant) bias / LN params for this wave's 4 n-tiles
  float bsv[4][4], gv[3][4], btv[3][4];
#pragma unroll
  for (int p = 0; p < 4; ++p) {
    const int cp = wave * 64 + p * 16 + (lane & 15);
#pragma unroll
    for (int l = 0; l < 4; ++l) bsv[l][p] = bs[l * NC + cp];
#pragma unroll
    for (int l = 0; l < 3; ++l) {
      gv[l][p] = g[l * NC + cp];
      btv[l][p] = bt[l * NC + cp];
    }
  }
  // this wave's fragment stream: fragment (layer,kt,p) at
  //   wfrag + layer*262144 + (kt*4+p)*512   (per-lane 16B at +lane*8)
  const unsigned short* wfrag = Wmf + (size_t)wave * 32768 + lane * 8;

  // DMA one 4KB chunk of the unified 64-chunk ring into slot cc&3
  auto issue_chunk = [&](int cc) {
    const int layer = cc >> 4, kt = cc & 15, slot = cc & 3;
#pragma unroll
    for (int p = 0; p < 4; ++p) {
      __builtin_amdgcn_global_load_lds(
          (const unsigned int*)(wfrag + (size_t)layer * 262144 +
                                (kt * 4 + p) * 512),
          (unsigned int*)&B_lds[wave][slot][p * 512], 16, 0, 0);
    }
  };

  // initial prefetch for t=0
  float wpre[SPB], bpre[SPB], epre[SPB];
#pragma unroll
  for (int r = 0; r < SPB; ++r) {
    const size_t o = ((size_t)(seq0 + r) * NT) * NC + tid;
    wpre[r] = weights[o];
    bpre[r] = biases[o];
    epre[r] = embw[((size_t)(seq0 + r) * NF) * NC + tid];
  }

  __syncthreads();

  // prime the ring (3 chunks in flight)
  issue_chunk(0);
  issue_chunk(1);
  issue_chunk(2);

  float h[SPB], cn[SPB];
#pragma unroll
  for (int r = 0; r < SPB; ++r) { h[r] = 0.f; cn[r] = 0.f; }

#pragma unroll 1
  for (int t = 0; t < NT; ++t) {
    float hw[SPB];
    if (t < NF) {
#pragma unroll
      for (int r = 0; r < SPB; ++r) h[r] += epre[r];
      if (t + 1 < NF) {
#pragma unroll
        for (int r = 0; r < SPB; ++r)
          epre[r] = embw[((size_t)(seq0 + r) * NF + t + 1) * NC + tid];
      }
      float v8[8], s8[8];
#pragma unroll
      for (int r = 0; r < SPB; ++r) {
        hw[r] = fmaf(h[r], wpre[r], bpre[r]);
        v8[r] = h[r] * h[r];
        v8[SPB + r] = hw[r] * hw[r];
      }
      blk_reduce1<8>(v8, s8, redA);
#pragma unroll
      for (int r = 0; r < SPB; ++r) {
        cn[r] = sqrtf(s8[r]);
        h[r] = hw[r] * (cn[r] / (sqrtf(s8[SPB + r]) + EPSN));
      }
    } else {
      float v4[SPB], s4[SPB];
#pragma unroll
      for (int r = 0; r < SPB; ++r) {
        hw[r] = fmaf(h[r], wpre[r], bpre[r]);
        v4[r] = hw[r] * hw[r];
      }
      blk_reduce1<SPB>(v4, s4, redA);
#pragma unroll
      for (int r = 0; r < SPB; ++r)
        h[r] = hw[r] * (cn[r] / (sqrtf(s4[r]) + EPSN));
    }
    // prefetch weights/biases for t+1 (flies under the MFMA phase)
    if (t + 1 < NT) {
#pragma unroll
      for (int r = 0; r < SPB; ++r) {
        const size_t o = ((size_t)(seq0 + r) * NT + t + 1) * NC + tid;
        wpre[r] = weights[o];
        bpre[r] = biases[o];
      }
    }
    // pack x -> A rows 0..3 (bf16, swizzled)
    {
      char* ab = (char*)A_lds;
#pragma unroll
      for (int r = 0; r < SPB; ++r)
        *(unsigned short*)(ab + r * 1024 + ((tid * 2) ^ ((r & 7) << 4))) =
            f2bf(h[r]);
    }
    bar_nodrain();

    // ---- 4 layers, unified DMA ring ----
#pragma unroll 1
    for (int layer = 0; layer < 4; ++layer) {
      f32x4 acc[4];
#pragma unroll
      for (int p = 0; p < 4; ++p) acc[p] = (f32x4){0.f, 0.f, 0.f, 0.f};
#pragma unroll
      for (int kt = 0; kt < 16; ++kt) {
        asm volatile("s_waitcnt vmcnt(8)" ::: "memory");
        const short8v a = *(const short8v*)((const char*)A_lds + abase +
                                            (((kt * 64) + akoff) ^ axor));
        const int slot = kt & 3;
#pragma unroll
        for (int p = 0; p < 4; ++p) {
          const short8v b =
              *(const short8v*)((const char*)&B_lds[wave][slot][0] + p * 1024 +
                                lane * 16);
          acc[p] =
              __builtin_amdgcn_mfma_f32_16x16x32_bf16(a, b, acc[p], 0, 0, 0);
        }
        issue_chunk((layer * 16 + kt + 3) & 63);
      }

      if (layer < 3) {
        float s1[SPB], s2[SPB];
#pragma unroll
        for (int q = 0; q < SPB; ++q) { s1[q] = 0.f; s2[q] = 0.f; }
#pragma unroll
        for (int p = 0; p < 4; ++p) {
#pragma unroll
          for (int q = 0; q < SPB; ++q) {
            const float y = acc[p][q] + bsv[layer][p];
            acc[p][q] = y;
            s1[q] += y;
            s2[q] = fmaf(y, y, s2[q]);
          }
        }
#pragma unroll
        for (int off = 1; off < 16; off <<= 1) {
#pragma unroll
          for (int q = 0; q < SPB; ++q) {
            s1[q] += __shfl_xor(s1[q], off);
            s2[q] += __shfl_xor(s2[q], off);
          }
        }
        if (lane == 0) {
#pragma unroll
          for (int q = 0; q < SPB; ++q) {
            st1[wave][q] = s1[q];
            st2[wave][q] = s2[q];
          }
        }
        bar_nodrain();
        float mu[SPB], rs[SPB];
#pragma unroll
        for (int q = 0; q < SPB; ++q) {
          float a1 = 0.f, a2 = 0.f;
#pragma unroll
          for (int w = 0; w < 8; ++w) {
            a1 += st1[w][q];
            a2 += st2[w][q];
          }
          mu[q] = a1 * (1.f / NC);
          rs[q] = rsqrtf(a2 * (1.f / NC) - mu[q] * mu[q] + 1e-5f);
        }
        if (crow) {
          char* ab = (char*)A_lds;
#pragma unroll
          for (int q = 0; q < SPB; ++q) {
#pragma unroll
            for (int p = 0; p < 4; ++p) {
              float y = (acc[p][q] - mu[q]) * rs[q] * gv[layer][p] +
                        btv[layer][p];
              y = y > 0.f ? y : 0.2f * y;
              const int cp = wave * 64 + p * 16 + (lane & 15);
              *(unsigned short*)(ab + q * 1024 +
                                 ((cp * 2) ^ ((q & 7) << 4))) = f2bf(y);
            }
          }
        }
        bar_nodrain();
      } else {
        // ---- final linear -> ol; epilogue ----
        float s2[SPB];
#pragma unroll
        for (int q = 0; q < SPB; ++q) s2[q] = 0.f;
#pragma unroll
        for (int p = 0; p < 4; ++p) {
#pragma unroll
          for (int q = 0; q < SPB; ++q) {
            const float y = acc[p][q] + bsv[3][p];
            acc[p][q] = y;
            s2[q] = fmaf(y, y, s2[q]);
          }
        }
#pragma unroll
        for (int off = 1; off < 16; off <<= 1) {
#pragma unroll
          for (int q = 0; q < SPB; ++q) s2[q] += __shfl_xor(s2[q], off);
        }
        if (lane == 0) {
#pragma unroll
          for (int q = 0; q < SPB; ++q) st2[wave][q] = s2[q];
        }
        if (crow) {
#pragma unroll
          for (int q = 0; q < SPB; ++q) {
#pragma unroll
            for (int p = 0; p < 4; ++p)
              ol_lds[q][wave * 64 + p * 16 + (lane & 15)] = acc[p][q];
          }
        }
        bar_nodrain();
        float sc[SPB], on[SPB];
#pragma unroll
        for (int r = 0; r < SPB; ++r) {
          float a2 = 0.f;
#pragma unroll
          for (int w = 0; w < 8; ++w) a2 += st2[w][r];
          const float no = sqrtf(a2);
          sc[r] = cn[r] * lk_lds[r][t] / (no + EPSN);
          on[r] = no * sc[r];
        }
        if (tid < SPB) onb[(size_t)(seq0 + tid) * NT + t] = on[tid];
        float v4[SPB], s4[SPB];
#pragma unroll
        for (int r = 0; r < SPB; ++r) {
          const float olv = ol_lds[r][tid] * sc[r];
          olb[((size_t)(seq0 + r) * NT + t) * NC + tid] = olv;
          h[r] -= olv;
          v4[r] = h[r] * h[r];
        }
        blk_reduce1<SPB>(v4, s4, redB);
#pragma unroll
        for (int r = 0; r < SPB; ++r) {
          h[r] *= (cn[r] - on[r]) / (sqrtf(s4[r]) + EPSN);
          cn[r] = fabsf(cn[r] - on[r]);  // ||h|| carried exactly
        }
      }
    }
  }
}

// ---------------------------------------------------------------------------
// K5: batched out-MLP on all 32768 ol rows (f32, R8's known-good version):
// of = unit_norm(mlp_out(ol)*ham)*on. grid 2048, block 512.
// ---------------------------------------------------------------------------
__global__ __launch_bounds__(512) void k_out(
    const float* __restrict__ olb, const float* __restrict__ onb,
    const float* __restrict__ Ws, const float* __restrict__ bs,
    const float* __restrict__ g, const float* __restrict__ bt,
    float* __restrict__ ofb) {
  __shared__ float xs[16][NC];
  __shared__ float mu_s[16], rs_s[16], ono[16];
  const int tid = threadIdx.x;
  const int wave = tid >> 6, lane = tid & 63;
  const int m0 = blockIdx.x * 16;
  for (int i = 0; i < 16; ++i)
    xs[i][tid] = olb[(size_t)(m0 + i) * NC + tid];
  __syncthreads();
  float acc[16];
  for (int layer = 0; layer < 4; ++layer) {
    tile_gemm16(xs, Ws + (size_t)layer * NC * NC, tid, acc);
    __syncthreads();
    const float bv = bs[layer * NC + tid];
#pragma unroll
    for (int i = 0; i < 16; ++i) xs[i][tid] = acc[i] + bv;
    __syncthreads();
    if (layer < 3) ln_leaky16(xs, g, bt, layer, tid, mu_s, rs_s);
  }
  const float ham =
      0.54f - 0.46f * cosf(6.283185307179586f * (float)tid / (float)NC);
#pragma unroll
  for (int i = 0; i < 16; ++i) xs[i][tid] *= ham;
  __syncthreads();
  for (int f = wave; f < 16; f += 8) {
    float s = 0.f;
#pragma unroll
    for (int j = 0; j < 8; ++j) {
      const float vv = xs[f][lane + 64 * j];
      s = fmaf(vv, vv, s);
    }
#pragma unroll
    for (int off = 32; off; off >>= 1) s += __shfl_down(s, off);
    if (lane == 0) ono[f] = sqrtf(s);
  }
  __syncthreads();
  for (int i = 0; i < 16; ++i) {
    const float onv = onb[m0 + i];
    ofb[(size_t)(m0 + i) * NC + tid] = xs[i][tid] / (ono[i] + EPSN) * onv;
  }
}

// ---------------------------------------------------------------------------
// K6: overlap-add at hop 256, trim to 32768.
// ---------------------------------------------------------------------------
__global__ __launch_bounds__(256) void k_oa(const float* __restrict__ ofb,
                                            float* __restrict__ out) {
  const int idx = blockIdx.x * 256 + threadIdx.x;
  if (idx >= BE * 32768) return;
  const int be = idx >> 15;
  const int s = idx & 32767;
  const int t1 = s >> 8;
  float v = ofb[((size_t)be * NT + t1) * NC + (s - (t1 << 8))];
  if (t1 >= 1)
    v += ofb[((size_t)be * NT + (t1 - 1)) * NC + (s - ((t1 - 1) << 8))];
  out[idx] = v;
}

// ---------------------------------------------------------------------------
// Workspace (< 256 MiB): region A (deform->olb) 64 MiB, region B
// (weights->ofb) 64 MiB, region C (biases) 64 MiB, small buffers ~12 MiB.
// ---------------------------------------------------------------------------
extern "C" void kernel_launch(void* const* d_in, const int* in_sizes, int n_in,
                              void* d_out, int out_size, void* d_ws,
                              size_t ws_size, hipStream_t stream) {
  const float* embedding = (const float*)d_in[0];
  const float* impulse = (const float*)d_in[1];
  const float* W_def = (const float*)d_in[2];
  const float* b_def = (const float*)d_in[3];
  const float* W_w = (const float*)d_in[4];
  const float* b_w = (const float*)d_in[5];
  const float* W_b = (const float*)d_in[6];
  const float* b_b = (const float*)d_in[7];
  const float* W_l = (const float*)d_in[8];
  const float* b_l = (const float*)d_in[9];
  const float* Ws_imp = (const float*)d_in[10];
  const float* bs_imp = (const float*)d_in[11];
  const float* g_imp = (const float*)d_in[12];
  const float* bt_imp = (const float*)d_in[13];
  const float* Ws_lat = (const float*)d_in[14];
  const float* bs_lat = (const float*)d_in[15];
  const float* g_lat = (const float*)d_in[16];
  const float* bt_lat = (const float*)d_in[17];
  const float* Ws_out = (const float*)d_in[18];
  const float* bs_out = (const float*)d_in[19];
  const float* g_out = (const float*)d_in[20];
  const float* bt_out = (const float*)d_in[21];
  float* out = (float*)d_out;

  float* ws = (float*)d_ws;
  float* deform = ws;                  // region A (reused as olb)
  float* weights = deform + 16777216;  // region B (reused as ofb)
  float* biases = weights + 16777216;  // region C
  float* leakb = biases + 16777216;    // 32,768 f
  float* embw = leakb + 32768;         // 2,097,152 f
  float* onb = embw + 2097152;         // 32,768 f
  unsigned short* wmf = (unsigned short*)(onb + 32768);  // 1,048,576 us
  float* olb = deform;                 // alias: deform dead after k_wb
  float* ofb = weights;                // alias: weights dead after k_scan

  k_cvt<<<2048, 64, 0, stream>>>(Ws_lat, wmf);
  k_deform<<<dim3(256, 8), 256, 0, stream>>>(embedding, W_def, b_def, deform);
  k_wb<<<2048, 512, 0, stream>>>(deform, W_w, b_w, W_b, b_b, W_l, b_l,
                                 weights, biases, leakb);
  k_imp<<<256, 512, 0, stream>>>(impulse, Ws_imp, bs_imp, g_imp, bt_imp, embw);
  k_scan<<<NSCAN, 512, 0, stream>>>(weights, biases, leakb, embw, wmf, bs_lat,
                                    g_lat, bt_lat, olb, onb);
  k_out<<<2048, 512, 0, stream>>>(olb, onb, Ws_out, bs_out, g_out, bt_out,
                                  ofb);
  k_oa<<<32768, 256, 0, stream>>>(ofb, out);
}

// Round 11
// 5001.674 us; speedup vs baseline: 2.6578x; 1.1995x over previous
//
#include <hip/hip_runtime.h>
#include <math.h>

#define NB 4
#define NE 64
#define BE 256          // NB*NE
#define LAT 256
#define NC 512          // channels == window
#define NT 128          // n_frames
#define NDEF 65536      // NC*NT
#define NIMP 4096
#define NF 16           // impulse frames
#define EPSN 1e-8f
#define SPB 4           // sequences per scan block
#define NSCAN 64        // scan blocks (BE/SPB)

typedef unsigned short ushort8 __attribute__((ext_vector_type(8)));
typedef short short8v __attribute__((ext_vector_type(8)));
typedef float f32x4 __attribute__((ext_vector_type(4)));

__device__ __forceinline__ unsigned short f2bf(float f) {
  const unsigned u = __float_as_uint(f);
  return (unsigned short)((u + 0x7FFFu + ((u >> 16) & 1u)) >> 16);  // RNE
}

// raw barrier WITHOUT the vmcnt(0) drain __syncthreads emits: ds-writes are
// made visible via lgkmcnt(0); in-flight global_load_lds DMA (wave-private
// destinations) stays in flight. sched_barrier(0) pins ordering (rule #18).
__device__ __forceinline__ void bar_nodrain() {
  asm volatile("s_waitcnt lgkmcnt(0)" ::: "memory");
  __builtin_amdgcn_s_barrier();
  __builtin_amdgcn_sched_barrier(0);
}

// ---------------------------------------------------------------------------
// single-raw-barrier block reduction (used only inside k_scan's t-loop).
// ---------------------------------------------------------------------------
template <int NR>
__device__ __forceinline__ void blk_reduce1(const float* v, float* out,
                                            float* red) {
  const int tid = threadIdx.x, wave = tid >> 6, lane = tid & 63;
  float s[NR];
#pragma unroll
  for (int i = 0; i < NR; ++i) s[i] = v[i];
#pragma unroll
  for (int off = 32; off; off >>= 1) {
#pragma unroll
    for (int i = 0; i < NR; ++i) s[i] += __shfl_down(s[i], off);
  }
  if (lane == 0) {
#pragma unroll
    for (int i = 0; i < NR; ++i) red[wave * NR + i] = s[i];
  }
  bar_nodrain();
#pragma unroll
  for (int i = 0; i < NR; ++i) {
    float a = 0.f;
#pragma unroll
    for (int w = 0; w < 8; ++w) a += red[w * NR + i];
    out[i] = a;
  }
}

// ---------------------------------------------------------------------------
// K0: swizzle a 4x[512k][512n] f32 weight stack into fragment-major MFMA
// B-frag order, bf16. Fragment (layer, wv, kt, p) lives at
//   Wmf[ ((layer*8+wv)*64 + kt*4 + p)*512 + lane*8 + j ]
//     = bf16( W[layer][kt*32 + (lane>>4)*8 + j][wv*64 + p*16 + (lane&15)] )
// Each fragment = contiguous 1KB. grid 2048, block 64. Used for Ws_lat AND
// Ws_out.
// ---------------------------------------------------------------------------
__global__ __launch_bounds__(64) void k_cvt(const float* __restrict__ W,
                                            unsigned short* __restrict__ Wmf) {
  const int lane = threadIdx.x;
  const int gg = blockIdx.x;
  const int p = gg & 3;
  const int kt = (gg >> 2) & 15;
  const int wv = (gg >> 6) & 7;
  const int layer = gg >> 9;
  const int col = wv * 64 + p * 16 + (lane & 15);
  const int k0 = kt * 32 + (lane >> 4) * 8;
  ushort8 o;
#pragma unroll
  for (int j = 0; j < 8; ++j)
    o[j] = f2bf(W[((size_t)layer * NC + k0 + j) * NC + col]);
  *reinterpret_cast<ushort8*>(Wmf + ((size_t)gg * 64 + lane) * 8) = o;
}

// ---------------------------------------------------------------------------
// K1: deform = embedding @ W_def + b_def      (256 x 256) @ (256 x 65536)
// ---------------------------------------------------------------------------
__global__ __launch_bounds__(256) void k_deform(
    const float* __restrict__ emb, const float* __restrict__ Wd,
    const float* __restrict__ bd, float* __restrict__ deform) {
  __shared__ float As[32][LAT];
  const int tid = threadIdx.x;
  const int c = blockIdx.x * 256 + tid;
  const int m0 = blockIdx.y * 32;
  for (int i = 0; i < 32; ++i) As[i][tid] = emb[(m0 + i) * LAT + tid];
  __syncthreads();
  float acc[32];
#pragma unroll
  for (int i = 0; i < 32; ++i) acc[i] = 0.f;
  for (int k = 0; k < LAT; k += 4) {
    const float w0 = Wd[(size_t)(k + 0) * NDEF + c];
    const float w1 = Wd[(size_t)(k + 1) * NDEF + c];
    const float w2 = Wd[(size_t)(k + 2) * NDEF + c];
    const float w3 = Wd[(size_t)(k + 3) * NDEF + c];
#pragma unroll
    for (int i = 0; i < 32; ++i) {
      const float4 a = *reinterpret_cast<const float4*>(&As[i][k]);
      acc[i] = fmaf(a.x, w0, acc[i]);
      acc[i] = fmaf(a.y, w1, acc[i]);
      acc[i] = fmaf(a.z, w2, acc[i]);
      acc[i] = fmaf(a.w, w3, acc[i]);
    }
  }
  const float bv = bd[c];
  for (int i = 0; i < 32; ++i)
    deform[(size_t)(m0 + i) * NDEF + c] = acc[i] + bv;
}

// ---------------------------------------------------------------------------
// K2: per-(be,t) rows of deform: unit_norm over channel dim, then
//   weights = x @ W_w + b_w ; biases = x @ W_b + b_b ; leak = sigmoid path.
// ---------------------------------------------------------------------------
__global__ __launch_bounds__(512) void k_wb(
    const float* __restrict__ deform, const float* __restrict__ Ww,
    const float* __restrict__ bw, const float* __restrict__ Wb,
    const float* __restrict__ bb, const float* __restrict__ Wl,
    const float* __restrict__ bl, float* __restrict__ weights,
    float* __restrict__ biases, float* __restrict__ leak) {
  __shared__ float xs[16][NC];
  __shared__ float rno[16], lks[16];
  const int tid = threadIdx.x;
  const int wave = tid >> 6, lane = tid & 63;
  const int be = blockIdx.x >> 3;
  const int t0 = (blockIdx.x & 7) * 16;
  const float* dbase = deform + (size_t)be * NDEF;
  for (int i = 0; i < 16; ++i)
    xs[i][tid] = dbase[(size_t)tid * NT + t0 + i];
  __syncthreads();
  for (int f = wave; f < 16; f += 8) {
    float s = 0.f;
#pragma unroll
    for (int j = 0; j < 8; ++j) {
      const float v = xs[f][lane + 64 * j];
      s = fmaf(v, v, s);
    }
#pragma unroll
    for (int off = 32; off; off >>= 1) s += __shfl_down(s, off);
    if (lane == 0) rno[f] = sqrtf(s);
  }
  __syncthreads();
#pragma unroll
  for (int i = 0; i < 16; ++i) xs[i][tid] = xs[i][tid] / (rno[i] + EPSN);
  __syncthreads();
  for (int f = wave; f < 16; f += 8) {
    float s = 0.f;
#pragma unroll
    for (int j = 0; j < 8; ++j)
      s = fmaf(xs[f][lane + 64 * j], Wl[lane + 64 * j], s);
#pragma unroll
    for (int off = 32; off; off >>= 1) s += __shfl_down(s, off);
    if (lane == 0) lks[f] = s;
  }
  __syncthreads();
  if (tid < 16) {
    const float v = lks[tid] + bl[0];
    leak[(size_t)be * NT + t0 + tid] = 0.1f + 0.98f / (1.f + expf(-v));
  }
  float accw[16], accb[16];
#pragma unroll
  for (int i = 0; i < 16; ++i) { accw[i] = 0.f; accb[i] = 0.f; }
  for (int k = 0; k < NC; k += 2) {
    const float w0 = Ww[(size_t)k * NC + tid];
    const float w1 = Ww[(size_t)(k + 1) * NC + tid];
    const float v0 = Wb[(size_t)k * NC + tid];
    const float v1 = Wb[(size_t)(k + 1) * NC + tid];
#pragma unroll
    for (int i = 0; i < 16; ++i) {
      const float2 a = *reinterpret_cast<const float2*>(&xs[i][k]);
      accw[i] = fmaf(a.x, w0, accw[i]);
      accw[i] = fmaf(a.y, w1, accw[i]);
      accb[i] = fmaf(a.x, v0, accb[i]);
      accb[i] = fmaf(a.y, v1, accb[i]);
    }
  }
  const float bwv = bw[tid], bbv = bb[tid];
  for (int i = 0; i < 16; ++i) {
    const size_t o = ((size_t)be * NT + t0 + i) * NC + tid;
    weights[o] = accw[i] + bwv;
    biases[o] = accb[i] + bbv;
  }
}

// ---------------------------------------------------------------------------
// 16-row tile x (512x512) GEMM helper (f32, used by k_imp).
// ---------------------------------------------------------------------------
__device__ __forceinline__ void tile_gemm16(const float (*xs)[NC],
                                            const float* __restrict__ W,
                                            int tid, float acc[16]) {
#pragma unroll
  for (int i = 0; i < 16; ++i) acc[i] = 0.f;
  for (int k = 0; k < NC; k += 4) {
    const float w0 = W[(size_t)(k + 0) * NC + tid];
    const float w1 = W[(size_t)(k + 1) * NC + tid];
    const float w2 = W[(size_t)(k + 2) * NC + tid];
    const float w3 = W[(size_t)(k + 3) * NC + tid];
#pragma unroll
    for (int i = 0; i < 16; ++i) {
      const float4 a = *reinterpret_cast<const float4*>(&xs[i][k]);
      acc[i] = fmaf(a.x, w0, acc[i]);
      acc[i] = fmaf(a.y, w1, acc[i]);
      acc[i] = fmaf(a.z, w2, acc[i]);
      acc[i] = fmaf(a.w, w3, acc[i]);
    }
  }
}

// LN (+leaky) stats applied in-place on xs[16][NC] (k_imp only)
__device__ __forceinline__ void ln_leaky16(float (*xs)[NC],
                                           const float* __restrict__ g,
                                           const float* __restrict__ bt,
                                           int layer, int tid, float* mu_s,
                                           float* rs_s) {
  const int wave = tid >> 6, lane = tid & 63;
  for (int f = wave; f < 16; f += 8) {
    float s = 0.f, s2 = 0.f;
#pragma unroll
    for (int j = 0; j < 8; ++j) {
      const float v = xs[f][lane + 64 * j];
      s += v;
      s2 = fmaf(v, v, s2);
    }
#pragma unroll
    for (int off = 32; off; off >>= 1) {
      s += __shfl_down(s, off);
      s2 += __shfl_down(s2, off);
    }
    if (lane == 0) {
      const float mu = s * (1.f / NC);
      mu_s[f] = mu;
      rs_s[f] = rsqrtf(s2 * (1.f / NC) - mu * mu + 1e-5f);
    }
  }
  __syncthreads();
  const float gv = g[layer * NC + tid], btv = bt[layer * NC + tid];
#pragma unroll
  for (int i = 0; i < 16; ++i) {
    const float y = (xs[i][tid] - mu_s[i]) * rs_s[i] * gv + btv;
    xs[i][tid] = y > 0.f ? y : 0.2f * y;
  }
  __syncthreads();
}

// ---------------------------------------------------------------------------
// K3: windowed impulse -> mlp_imp -> unit_norm * window-norm -> emb stream.
// ---------------------------------------------------------------------------
__global__ __launch_bounds__(512) void k_imp(
    const float* __restrict__ impulse, const float* __restrict__ Ws,
    const float* __restrict__ bs, const float* __restrict__ g,
    const float* __restrict__ bt, float* __restrict__ embo) {
  __shared__ float xs[16][NC];
  __shared__ float wno[16], mu_s[16], rs_s[16], ono[16];
  const int tid = threadIdx.x;
  const int wave = tid >> 6, lane = tid & 63;
  const int be = blockIdx.x;
  const float* ib = impulse + (size_t)be * NIMP;
  for (int f = 0; f < 16; ++f) {
    const int s = f * 256 + tid;
    xs[f][tid] = (s < NIMP) ? ib[s] : 0.f;
  }
  __syncthreads();
  for (int f = wave; f < 16; f += 8) {
    float s = 0.f;
#pragma unroll
    for (int j = 0; j < 8; ++j) {
      const float v = xs[f][lane + 64 * j];
      s = fmaf(v, v, s);
    }
#pragma unroll
    for (int off = 32; off; off >>= 1) s += __shfl_down(s, off);
    if (lane == 0) wno[f] = sqrtf(s);
  }
  __syncthreads();
  float acc[16];
  for (int layer = 0; layer < 4; ++layer) {
    tile_gemm16(xs, Ws + (size_t)layer * NC * NC, tid, acc);
    __syncthreads();
    const float bv = bs[layer * NC + tid];
#pragma unroll
    for (int i = 0; i < 16; ++i) xs[i][tid] = acc[i] + bv;
    __syncthreads();
    if (layer < 3) ln_leaky16(xs, g, bt, layer, tid, mu_s, rs_s);
  }
  for (int f = wave; f < 16; f += 8) {
    float s = 0.f;
#pragma unroll
    for (int j = 0; j < 8; ++j) {
      const float v = xs[f][lane + 64 * j];
      s = fmaf(v, v, s);
    }
#pragma unroll
    for (int off = 32; off; off >>= 1) s += __shfl_down(s, off);
    if (lane == 0) ono[f] = sqrtf(s);
  }
  __syncthreads();
  for (int f = 0; f < 16; ++f)
    embo[((size_t)be * NF + f) * NC + tid] =
        xs[f][tid] / (ono[f] + EPSN) * wno[f];
}

// ---------------------------------------------------------------------------
// K4: the sequential scan, MFMA v8 (UNCHANGED from R10 — known good).
// Hardened continuous DMA ring: 4 LDS slots/wave, 3 chunks in flight, issue
// chunk cc+3 after consuming cc (reuse distance 1 full iteration), steady
// vmcnt(8). Raw no-drain barriers keep DMA flowing through LN/reduce phases.
// ---------------------------------------------------------------------------
__global__ __launch_bounds__(512) void k_scan(
    const float* __restrict__ weights, const float* __restrict__ biases,
    const float* __restrict__ leak, const float* __restrict__ embw,
    const unsigned short* __restrict__ Wmf, const float* __restrict__ bs,
    const float* __restrict__ g, const float* __restrict__ bt,
    float* __restrict__ olb, float* __restrict__ onb) {
  __shared__ __align__(16) unsigned short A_lds[16 * NC];     // 16KB
  __shared__ __align__(16) unsigned short B_lds[8][4][2048];  // 128KB
  __shared__ float ol_lds[SPB][NC];                           // 8KB
  __shared__ float redA[64];
  __shared__ float redB[32];
  __shared__ float st1[8][SPB], st2[8][SPB];
  __shared__ float lk_lds[SPB][NT];

  const int tid = threadIdx.x;
  const int wave = tid >> 6, lane = tid & 63;
  const int seq0 = blockIdx.x * SPB;

  // stage leak slice (one element per thread)
  {
    const int r = tid >> 7, tt = tid & 127;
    lk_lds[r][tt] = leak[(size_t)(seq0 + r) * NT + tt];
  }
  // zero the pad rows 4..15 of A (never written again)
  {
    unsigned* z = (unsigned*)(A_lds + SPB * NC);
    for (int i = tid; i < (16 - SPB) * NC / 2; i += 512) z[i] = 0u;
  }

  // per-lane MFMA geometry
  const int arow = lane & 15;
  const int kgrp = lane >> 4;
  const int abase = arow * (NC * 2);
  const int axor = (arow & 7) << 4;
  const int akoff = kgrp * 16;
  const bool crow = (kgrp == 0);  // lanes holding C rows 0..3

  // hoist per-lane (t-invariant) bias / LN params for this wave's 4 n-tiles
  float bsv[4][4], gv[3][4], btv[3][4];
#pragma unroll
  for (int p = 0; p < 4; ++p) {
    const int cp = wave * 64 + p * 16 + (lane & 15);
#pragma unroll
    for (int l = 0; l < 4; ++l) bsv[l][p] = bs[l * NC + cp];
#pragma unroll
    for (int l = 0; l < 3; ++l) {
      gv[l][p] = g[l * NC + cp];
      btv[l][p] = bt[l * NC + cp];
    }
  }
  // this wave's fragment stream: fragment (layer,kt,p) at
  //   wfrag + layer*262144 + (kt*4+p)*512   (per-lane 16B at +lane*8)
  const unsigned short* wfrag = Wmf + (size_t)wave * 32768 + lane * 8;

  // DMA one 4KB chunk of the unified 64-chunk ring into slot cc&3
  auto issue_chunk = [&](int cc) {
    const int layer = cc >> 4, kt = cc & 15, slot = cc & 3;
#pragma unroll
    for (int p = 0; p < 4; ++p) {
      __builtin_amdgcn_global_load_lds(
          (const unsigned int*)(wfrag + (size_t)layer * 262144 +
                                (kt * 4 + p) * 512),
          (unsigned int*)&B_lds[wave][slot][p * 512], 16, 0, 0);
    }
  };

  // initial prefetch for t=0
  float wpre[SPB], bpre[SPB], epre[SPB];
#pragma unroll
  for (int r = 0; r < SPB; ++r) {
    const size_t o = ((size_t)(seq0 + r) * NT) * NC + tid;
    wpre[r] = weights[o];
    bpre[r] = biases[o];
    epre[r] = embw[((size_t)(seq0 + r) * NF) * NC + tid];
  }

  __syncthreads();

  // prime the ring (3 chunks in flight)
  issue_chunk(0);
  issue_chunk(1);
  issue_chunk(2);

  float h[SPB], cn[SPB];
#pragma unroll
  for (int r = 0; r < SPB; ++r) { h[r] = 0.f; cn[r] = 0.f; }

#pragma unroll 1
  for (int t = 0; t < NT; ++t) {
    float hw[SPB];
    if (t < NF) {
#pragma unroll
      for (int r = 0; r < SPB; ++r) h[r] += epre[r];
      if (t + 1 < NF) {
#pragma unroll
        for (int r = 0; r < SPB; ++r)
          epre[r] = embw[((size_t)(seq0 + r) * NF + t + 1) * NC + tid];
      }
      float v8[8], s8[8];
#pragma unroll
      for (int r = 0; r < SPB; ++r) {
        hw[r] = fmaf(h[r], wpre[r], bpre[r]);
        v8[r] = h[r] * h[r];
        v8[SPB + r] = hw[r] * hw[r];
      }
      blk_reduce1<8>(v8, s8, redA);
#pragma unroll
      for (int r = 0; r < SPB; ++r) {
        cn[r] = sqrtf(s8[r]);
        h[r] = hw[r] * (cn[r] / (sqrtf(s8[SPB + r]) + EPSN));
      }
    } else {
      float v4[SPB], s4[SPB];
#pragma unroll
      for (int r = 0; r < SPB; ++r) {
        hw[r] = fmaf(h[r], wpre[r], bpre[r]);
        v4[r] = hw[r] * hw[r];
      }
      blk_reduce1<SPB>(v4, s4, redA);
#pragma unroll
      for (int r = 0; r < SPB; ++r)
        h[r] = hw[r] * (cn[r] / (sqrtf(s4[r]) + EPSN));
    }
    // prefetch weights/biases for t+1 (flies under the MFMA phase)
    if (t + 1 < NT) {
#pragma unroll
      for (int r = 0; r < SPB; ++r) {
        const size_t o = ((size_t)(seq0 + r) * NT + t + 1) * NC + tid;
        wpre[r] = weights[o];
        bpre[r] = biases[o];
      }
    }
    // pack x -> A rows 0..3 (bf16, swizzled)
    {
      char* ab = (char*)A_lds;
#pragma unroll
      for (int r = 0; r < SPB; ++r)
        *(unsigned short*)(ab + r * 1024 + ((tid * 2) ^ ((r & 7) << 4))) =
            f2bf(h[r]);
    }
    bar_nodrain();

    // ---- 4 layers, unified DMA ring ----
#pragma unroll 1
    for (int layer = 0; layer < 4; ++layer) {
      f32x4 acc[4];
#pragma unroll
      for (int p = 0; p < 4; ++p) acc[p] = (f32x4){0.f, 0.f, 0.f, 0.f};
#pragma unroll
      for (int kt = 0; kt < 16; ++kt) {
        asm volatile("s_waitcnt vmcnt(8)" ::: "memory");
        const short8v a = *(const short8v*)((const char*)A_lds + abase +
                                            (((kt * 64) + akoff) ^ axor));
        const int slot = kt & 3;
#pragma unroll
        for (int p = 0; p < 4; ++p) {
          const short8v b =
              *(const short8v*)((const char*)&B_lds[wave][slot][0] + p * 1024 +
                                lane * 16);
          acc[p] =
              __builtin_amdgcn_mfma_f32_16x16x32_bf16(a, b, acc[p], 0, 0, 0);
        }
        issue_chunk((layer * 16 + kt + 3) & 63);
      }

      if (layer < 3) {
        float s1[SPB], s2[SPB];
#pragma unroll
        for (int q = 0; q < SPB; ++q) { s1[q] = 0.f; s2[q] = 0.f; }
#pragma unroll
        for (int p = 0; p < 4; ++p) {
#pragma unroll
          for (int q = 0; q < SPB; ++q) {
            const float y = acc[p][q] + bsv[layer][p];
            acc[p][q] = y;
            s1[q] += y;
            s2[q] = fmaf(y, y, s2[q]);
          }
        }
#pragma unroll
        for (int off = 1; off < 16; off <<= 1) {
#pragma unroll
          for (int q = 0; q < SPB; ++q) {
            s1[q] += __shfl_xor(s1[q], off);
            s2[q] += __shfl_xor(s2[q], off);
          }
        }
        if (lane == 0) {
#pragma unroll
          for (int q = 0; q < SPB; ++q) {
            st1[wave][q] = s1[q];
            st2[wave][q] = s2[q];
          }
        }
        bar_nodrain();
        float mu[SPB], rs[SPB];
#pragma unroll
        for (int q = 0; q < SPB; ++q) {
          float a1 = 0.f, a2 = 0.f;
#pragma unroll
          for (int w = 0; w < 8; ++w) {
            a1 += st1[w][q];
            a2 += st2[w][q];
          }
          mu[q] = a1 * (1.f / NC);
          rs[q] = rsqrtf(a2 * (1.f / NC) - mu[q] * mu[q] + 1e-5f);
        }
        if (crow) {
          char* ab = (char*)A_lds;
#pragma unroll
          for (int q = 0; q < SPB; ++q) {
#pragma unroll
            for (int p = 0; p < 4; ++p) {
              float y = (acc[p][q] - mu[q]) * rs[q] * gv[layer][p] +
                        btv[layer][p];
              y = y > 0.f ? y : 0.2f * y;
              const int cp = wave * 64 + p * 16 + (lane & 15);
              *(unsigned short*)(ab + q * 1024 +
                                 ((cp * 2) ^ ((q & 7) << 4))) = f2bf(y);
            }
          }
        }
        bar_nodrain();
      } else {
        // ---- final linear -> ol; epilogue ----
        float s2[SPB];
#pragma unroll
        for (int q = 0; q < SPB; ++q) s2[q] = 0.f;
#pragma unroll
        for (int p = 0; p < 4; ++p) {
#pragma unroll
          for (int q = 0; q < SPB; ++q) {
            const float y = acc[p][q] + bsv[3][p];
            acc[p][q] = y;
            s2[q] = fmaf(y, y, s2[q]);
          }
        }
#pragma unroll
        for (int off = 1; off < 16; off <<= 1) {
#pragma unroll
          for (int q = 0; q < SPB; ++q) s2[q] += __shfl_xor(s2[q], off);
        }
        if (lane == 0) {
#pragma unroll
          for (int q = 0; q < SPB; ++q) st2[wave][q] = s2[q];
        }
        if (crow) {
#pragma unroll
          for (int q = 0; q < SPB; ++q) {
#pragma unroll
            for (int p = 0; p < 4; ++p)
              ol_lds[q][wave * 64 + p * 16 + (lane & 15)] = acc[p][q];
          }
        }
        bar_nodrain();
        float sc[SPB], on[SPB];
#pragma unroll
        for (int r = 0; r < SPB; ++r) {
          float a2 = 0.f;
#pragma unroll
          for (int w = 0; w < 8; ++w) a2 += st2[w][r];
          const float no = sqrtf(a2);
          sc[r] = cn[r] * lk_lds[r][t] / (no + EPSN);
          on[r] = no * sc[r];
        }
        if (tid < SPB) onb[(size_t)(seq0 + tid) * NT + t] = on[tid];
        float v4[SPB], s4[SPB];
#pragma unroll
        for (int r = 0; r < SPB; ++r) {
          const float olv = ol_lds[r][tid] * sc[r];
          olb[((size_t)(seq0 + r) * NT + t) * NC + tid] = olv;
          h[r] -= olv;
          v4[r] = h[r] * h[r];
        }
        blk_reduce1<SPB>(v4, s4, redB);
#pragma unroll
        for (int r = 0; r < SPB; ++r) {
          h[r] *= (cn[r] - on[r]) / (sqrtf(s4[r]) + EPSN);
          cn[r] = fabsf(cn[r] - on[r]);  // ||h|| carried exactly
        }
      }
    }
  }
}

// ---------------------------------------------------------------------------
// K5: batched out-MLP, MFMA edition (isolated re-introduction; template
// audited — R9's failure is fully explained by the k_scan ring race fixed in
// R10). 2048 blocks x 512 threads; full M=16 tile per block; C/D rows
// r = (lane>>4)*4 + reg, col = lane&15 (m89-verified layout). Weights from
// k_cvt'd Ws_out; plain register B-loads — 32 waves/CU of TLP hide latency.
// of = unit_norm(mlp_out(ol) * ham) * on.
// ---------------------------------------------------------------------------
__global__ __launch_bounds__(512) void k_out(
    const float* __restrict__ olb, const float* __restrict__ onb,
    const unsigned short* __restrict__ Wmf, const float* __restrict__ bs,
    const float* __restrict__ g, const float* __restrict__ bt,
    float* __restrict__ ofb) {
  __shared__ __align__(16) unsigned short A_lds[16 * NC];  // 16KB
  __shared__ float st1[8][16], st2[8][16];
  __shared__ float on_l[16];
  const int tid = threadIdx.x;
  const int wave = tid >> 6, lane = tid & 63;
  const int m0 = blockIdx.x * 16;
  const int arow = lane & 15;
  const int kgrp = lane >> 4;
  const int r0 = kgrp * 4;
  const int abase = arow * (NC * 2);
  const int axor = (arow & 7) << 4;
  const int akoff = kgrp * 16;

  float bsv[4][4], gv[3][4], btv[3][4], hamv[4];
#pragma unroll
  for (int p = 0; p < 4; ++p) {
    const int cp = wave * 64 + p * 16 + (lane & 15);
#pragma unroll
    for (int l = 0; l < 4; ++l) bsv[l][p] = bs[l * NC + cp];
#pragma unroll
    for (int l = 0; l < 3; ++l) {
      gv[l][p] = g[l * NC + cp];
      btv[l][p] = bt[l * NC + cp];
    }
    hamv[p] =
        0.54f - 0.46f * cosf(6.283185307179586f * (float)cp / (float)NC);
  }
  if (tid < 16) on_l[tid] = onb[m0 + tid];
  // pack A from olb (bf16, swizzled)
  {
    char* ab = (char*)A_lds;
    for (int i = 0; i < 16; ++i) {
      const float v = olb[(size_t)(m0 + i) * NC + tid];
      *(unsigned short*)(ab + i * 1024 + ((tid * 2) ^ ((i & 7) << 4))) =
          f2bf(v);
    }
  }
  __syncthreads();

  const unsigned short* wfrag = Wmf + (size_t)wave * 32768 + lane * 8;

#pragma unroll 1
  for (int layer = 0; layer < 4; ++layer) {
    f32x4 acc[4];
#pragma unroll
    for (int p = 0; p < 4; ++p) acc[p] = (f32x4){0.f, 0.f, 0.f, 0.f};
#pragma unroll
    for (int kt = 0; kt < 16; ++kt) {
      const short8v a = *(const short8v*)((const char*)A_lds + abase +
                                          (((kt * 64) + akoff) ^ axor));
#pragma unroll
      for (int p = 0; p < 4; ++p) {
        const short8v b = *(const short8v*)(wfrag + (size_t)layer * 262144 +
                                            (kt * 4 + p) * 512);
        acc[p] = __builtin_amdgcn_mfma_f32_16x16x32_bf16(a, b, acc[p], 0, 0, 0);
      }
    }
    if (layer < 3) {
      float s1[4], s2[4];
#pragma unroll
      for (int q = 0; q < 4; ++q) { s1[q] = 0.f; s2[q] = 0.f; }
#pragma unroll
      for (int p = 0; p < 4; ++p) {
#pragma unroll
        for (int q = 0; q < 4; ++q) {
          const float y = acc[p][q] + bsv[layer][p];
          acc[p][q] = y;
          s1[q] += y;
          s2[q] = fmaf(y, y, s2[q]);
        }
      }
#pragma unroll
      for (int off = 1; off < 16; off <<= 1) {
#pragma unroll
        for (int q = 0; q < 4; ++q) {
          s1[q] += __shfl_xor(s1[q], off);
          s2[q] += __shfl_xor(s2[q], off);
        }
      }
      if ((lane & 15) == 0) {
#pragma unroll
        for (int q = 0; q < 4; ++q) {
          st1[wave][r0 + q] = s1[q];
          st2[wave][r0 + q] = s2[q];
        }
      }
      __syncthreads();
      char* ab = (char*)A_lds;
#pragma unroll
      for (int q = 0; q < 4; ++q) {
        const int row = r0 + q;
        float a1 = 0.f, a2 = 0.f;
#pragma unroll
        for (int w = 0; w < 8; ++w) {
          a1 += st1[w][row];
          a2 += st2[w][row];
        }
        const float mu = a1 * (1.f / NC);
        const float rs = rsqrtf(a2 * (1.f / NC) - mu * mu + 1e-5f);
#pragma unroll
        for (int p = 0; p < 4; ++p) {
          float y = (acc[p][q] - mu) * rs * gv[layer][p] + btv[layer][p];
          y = y > 0.f ? y : 0.2f * y;
          const int cp = wave * 64 + p * 16 + (lane & 15);
          *(unsigned short*)(ab + row * 1024 +
                             ((cp * 2) ^ ((row & 7) << 4))) = f2bf(y);
        }
      }
      __syncthreads();
    } else {
      // bias, hamming, row-norm, scale by on
      float s2[4];
#pragma unroll
      for (int q = 0; q < 4; ++q) s2[q] = 0.f;
#pragma unroll
      for (int p = 0; p < 4; ++p) {
#pragma unroll
        for (int q = 0; q < 4; ++q) {
          float y = (acc[p][q] + bsv[3][p]) * hamv[p];
          acc[p][q] = y;
          s2[q] = fmaf(y, y, s2[q]);
        }
      }
#pragma unroll
      for (int off = 1; off < 16; off <<= 1) {
#pragma unroll
        for (int q = 0; q < 4; ++q) s2[q] += __shfl_xor(s2[q], off);
      }
      if ((lane & 15) == 0) {
#pragma unroll
        for (int q = 0; q < 4; ++q) st2[wave][r0 + q] = s2[q];
      }
      __syncthreads();
#pragma unroll
      for (int q = 0; q < 4; ++q) {
        const int row = r0 + q;
        float a2 = 0.f;
#pragma unroll
        for (int w = 0; w < 8; ++w) a2 += st2[w][row];
        const float inv = on_l[row] / (sqrtf(a2) + EPSN);
#pragma unroll
        for (int p = 0; p < 4; ++p) {
          const int cp = wave * 64 + p * 16 + (lane & 15);
          ofb[(size_t)(m0 + row) * NC + cp] = acc[p][q] * inv;
        }
      }
    }
  }
}

// ---------------------------------------------------------------------------
// K6: overlap-add at hop 256, trim to 32768.
// ---------------------------------------------------------------------------
__global__ __launch_bounds__(256) void k_oa(const float* __restrict__ ofb,
                                            float* __restrict__ out) {
  const int idx = blockIdx.x * 256 + threadIdx.x;
  if (idx >= BE * 32768) return;
  const int be = idx >> 15;
  const int s = idx & 32767;
  const int t1 = s >> 8;
  float v = ofb[((size_t)be * NT + t1) * NC + (s - (t1 << 8))];
  if (t1 >= 1)
    v += ofb[((size_t)be * NT + (t1 - 1)) * NC + (s - ((t1 - 1) << 8))];
  out[idx] = v;
}

// ---------------------------------------------------------------------------
// Workspace (< 256 MiB): region A (deform->olb) 64 MiB, region B
// (weights->ofb) 64 MiB, region C (biases) 64 MiB, small buffers ~14 MiB.
// ---------------------------------------------------------------------------
extern "C" void kernel_launch(void* const* d_in, const int* in_sizes, int n_in,
                              void* d_out, int out_size, void* d_ws,
                              size_t ws_size, hipStream_t stream) {
  const float* embedding = (const float*)d_in[0];
  const float* impulse = (const float*)d_in[1];
  const float* W_def = (const float*)d_in[2];
  const float* b_def = (const float*)d_in[3];
  const float* W_w = (const float*)d_in[4];
  const float* b_w = (const float*)d_in[5];
  const float* W_b = (const float*)d_in[6];
  const float* b_b = (const float*)d_in[7];
  const float* W_l = (const float*)d_in[8];
  const float* b_l = (const float*)d_in[9];
  const float* Ws_imp = (const float*)d_in[10];
  const float* bs_imp = (const float*)d_in[11];
  const float* g_imp = (const float*)d_in[12];
  const float* bt_imp = (const float*)d_in[13];
  const float* Ws_lat = (const float*)d_in[14];
  const float* bs_lat = (const float*)d_in[15];
  const float* g_lat = (const float*)d_in[16];
  const float* bt_lat = (const float*)d_in[17];
  const float* Ws_out = (const float*)d_in[18];
  const float* bs_out = (const float*)d_in[19];
  const float* g_out = (const float*)d_in[20];
  const float* bt_out = (const float*)d_in[21];
  float* out = (float*)d_out;

  float* ws = (float*)d_ws;
  float* deform = ws;                  // region A (reused as olb)
  float* weights = deform + 16777216;  // region B (reused as ofb)
  float* biases = weights + 16777216;  // region C
  float* leakb = biases + 16777216;    // 32,768 f
  float* embw = leakb + 32768;         // 2,097,152 f
  float* onb = embw + 2097152;         // 32,768 f
  unsigned short* wmf = (unsigned short*)(onb + 32768);    // 1,048,576 us
  unsigned short* wmf_out = wmf + 1048576;                 // 1,048,576 us
  float* olb = deform;                 // alias: deform dead after k_wb
  float* ofb = weights;                // alias: weights dead after k_scan

  k_cvt<<<2048, 64, 0, stream>>>(Ws_lat, wmf);
  k_cvt<<<2048, 64, 0, stream>>>(Ws_out, wmf_out);
  k_deform<<<dim3(256, 8), 256, 0, stream>>>(embedding, W_def, b_def, deform);
  k_wb<<<2048, 512, 0, stream>>>(deform, W_w, b_w, W_b, b_b, W_l, b_l,
                                 weights, biases, leakb);
  k_imp<<<256, 512, 0, stream>>>(impulse, Ws_imp, bs_imp, g_imp, bt_imp, embw);
  k_scan<<<NSCAN, 512, 0, stream>>>(weights, biases, leakb, embw, wmf, bs_lat,
                                    g_lat, bt_lat, olb, onb);
  k_out<<<2048, 512, 0, stream>>>(olb, onb, wmf_out, bs_out, g_out, bt_out,
                                  ofb);
  k_oa<<<32768, 256, 0, stream>>>(ofb, out);
}

// Round 12
// 4474.457 us; speedup vs baseline: 2.9709x; 1.1178x over previous
//
#include <hip/hip_runtime.h>
#include <math.h>

#define NB 4
#define NE 64
#define BE 256          // NB*NE
#define LAT 256
#define NC 512          // channels == window
#define NT 128          // n_frames
#define NDEF 65536      // NC*NT
#define NIMP 4096
#define NF 16           // impulse frames
#define EPSN 1e-8f
#define SPB 4           // sequences per scan block
#define NSCAN 64        // scan blocks (BE/SPB)

typedef unsigned short ushort8 __attribute__((ext_vector_type(8)));
typedef short short8v __attribute__((ext_vector_type(8)));
typedef float f32x4 __attribute__((ext_vector_type(4)));

__device__ __forceinline__ unsigned short f2bf(float f) {
  const unsigned u = __float_as_uint(f);
  return (unsigned short)((u + 0x7FFFu + ((u >> 16) & 1u)) >> 16);  // RNE
}

// raw barrier WITHOUT the vmcnt(0) drain __syncthreads emits: ds-writes are
// made visible via lgkmcnt(0); in-flight global_load_lds DMA (wave-private
// destinations) stays in flight. sched_barrier(0) pins ordering (rule #18).
__device__ __forceinline__ void bar_nodrain() {
  asm volatile("s_waitcnt lgkmcnt(0)" ::: "memory");
  __builtin_amdgcn_s_barrier();
  __builtin_amdgcn_sched_barrier(0);
}

// ---------------------------------------------------------------------------
// single-raw-barrier block reduction (used only inside k_scan's t-loop).
// ---------------------------------------------------------------------------
template <int NR>
__device__ __forceinline__ void blk_reduce1(const float* v, float* out,
                                            float* red) {
  const int tid = threadIdx.x, wave = tid >> 6, lane = tid & 63;
  float s[NR];
#pragma unroll
  for (int i = 0; i < NR; ++i) s[i] = v[i];
#pragma unroll
  for (int off = 32; off; off >>= 1) {
#pragma unroll
    for (int i = 0; i < NR; ++i) s[i] += __shfl_down(s[i], off);
  }
  if (lane == 0) {
#pragma unroll
    for (int i = 0; i < NR; ++i) red[wave * NR + i] = s[i];
  }
  bar_nodrain();
#pragma unroll
  for (int i = 0; i < NR; ++i) {
    float a = 0.f;
#pragma unroll
    for (int w = 0; w < 8; ++w) a += red[w * NR + i];
    out[i] = a;
  }
}

// ---------------------------------------------------------------------------
// K0: swizzle an L-layer [512k][512n] f32 weight stack into fragment-major
// MFMA B-frag order, bf16. Fragment (layer, wv, kt, p) lives at
//   Wmf[ ((layer*8+wv)*64 + kt*4 + p)*512 + lane*8 + j ]
//     = bf16( W[layer][kt*32 + (lane>>4)*8 + j][wv*64 + p*16 + (lane&15)] )
// Each fragment = contiguous 1KB. grid = L*512, block 64. Used for Ws_lat
// (L=4), Ws_out (L=4), and W_w / W_b (L=1 each).
// ---------------------------------------------------------------------------
__global__ __launch_bounds__(64) void k_cvt(const float* __restrict__ W,
                                            unsigned short* __restrict__ Wmf) {
  const int lane = threadIdx.x;
  const int gg = blockIdx.x;
  const int p = gg & 3;
  const int kt = (gg >> 2) & 15;
  const int wv = (gg >> 6) & 7;
  const int layer = gg >> 9;
  const int col = wv * 64 + p * 16 + (lane & 15);
  const int k0 = kt * 32 + (lane >> 4) * 8;
  ushort8 o;
#pragma unroll
  for (int j = 0; j < 8; ++j)
    o[j] = f2bf(W[((size_t)layer * NC + k0 + j) * NC + col]);
  *reinterpret_cast<ushort8*>(Wmf + ((size_t)gg * 64 + lane) * 8) = o;
}

// ---------------------------------------------------------------------------
// K1: deform = embedding @ W_def + b_def      (256 x 256) @ (256 x 65536)
// ---------------------------------------------------------------------------
__global__ __launch_bounds__(256) void k_deform(
    const float* __restrict__ emb, const float* __restrict__ Wd,
    const float* __restrict__ bd, float* __restrict__ deform) {
  __shared__ float As[32][LAT];
  const int tid = threadIdx.x;
  const int c = blockIdx.x * 256 + tid;
  const int m0 = blockIdx.y * 32;
  for (int i = 0; i < 32; ++i) As[i][tid] = emb[(m0 + i) * LAT + tid];
  __syncthreads();
  float acc[32];
#pragma unroll
  for (int i = 0; i < 32; ++i) acc[i] = 0.f;
  for (int k = 0; k < LAT; k += 4) {
    const float w0 = Wd[(size_t)(k + 0) * NDEF + c];
    const float w1 = Wd[(size_t)(k + 1) * NDEF + c];
    const float w2 = Wd[(size_t)(k + 2) * NDEF + c];
    const float w3 = Wd[(size_t)(k + 3) * NDEF + c];
#pragma unroll
    for (int i = 0; i < 32; ++i) {
      const float4 a = *reinterpret_cast<const float4*>(&As[i][k]);
      acc[i] = fmaf(a.x, w0, acc[i]);
      acc[i] = fmaf(a.y, w1, acc[i]);
      acc[i] = fmaf(a.z, w2, acc[i]);
      acc[i] = fmaf(a.w, w3, acc[i]);
    }
  }
  const float bv = bd[c];
  for (int i = 0; i < 32; ++i)
    deform[(size_t)(m0 + i) * NDEF + c] = acc[i] + bv;
}

// ---------------------------------------------------------------------------
// K2: per-(be,t) rows of deform: unit_norm over channel dim, then MFMA dual
// GEMM: weights = x @ W_w + b_w ; biases = x @ W_b + b_b ; leak = sigmoid.
// Staging/norm/leak stay f32 (unchanged numerics); the two 512x512 GEMMs use
// the validated MFMA template (Wmf2 = 2-layer fragment stack: l0=Ww, l1=Wb),
// sharing each A-fragment across both B-matrices (8 MFMAs per kt).
// grid 2048 (= 256 be * 8 t-tiles), block 512.
// ---------------------------------------------------------------------------
__global__ __launch_bounds__(512) void k_wb(
    const float* __restrict__ deform, const unsigned short* __restrict__ Wmf2,
    const float* __restrict__ bw, const float* __restrict__ bb,
    const float* __restrict__ Wl, const float* __restrict__ bl,
    float* __restrict__ weights, float* __restrict__ biases,
    float* __restrict__ leak) {
  __shared__ float xs[16][NC];                             // 32KB
  __shared__ __align__(16) unsigned short A_lds[16 * NC];  // 16KB
  __shared__ float rno[16], lks[16];
  const int tid = threadIdx.x;
  const int wave = tid >> 6, lane = tid & 63;
  const int be = blockIdx.x >> 3;
  const int t0 = (blockIdx.x & 7) * 16;
  const float* dbase = deform + (size_t)be * NDEF;
  for (int i = 0; i < 16; ++i)
    xs[i][tid] = dbase[(size_t)tid * NT + t0 + i];
  __syncthreads();
  // row norms over c (norm over axis=2 of (B,E,C,T))
  for (int f = wave; f < 16; f += 8) {
    float s = 0.f;
#pragma unroll
    for (int j = 0; j < 8; ++j) {
      const float v = xs[f][lane + 64 * j];
      s = fmaf(v, v, s);
    }
#pragma unroll
    for (int off = 32; off; off >>= 1) s += __shfl_down(s, off);
    if (lane == 0) rno[f] = sqrtf(s);
  }
  __syncthreads();
  // normalize in place + pack A (bf16, swizzled)
  {
    char* ab = (char*)A_lds;
#pragma unroll
    for (int i = 0; i < 16; ++i) {
      const float xv = xs[i][tid] / (rno[i] + EPSN);
      xs[i][tid] = xv;
      *(unsigned short*)(ab + i * 1024 + ((tid * 2) ^ ((i & 7) << 4))) =
          f2bf(xv);
    }
  }
  __syncthreads();
  // leak = 0.1 + 0.98*sigmoid(x @ W_l + b_l)
  for (int f = wave; f < 16; f += 8) {
    float s = 0.f;
#pragma unroll
    for (int j = 0; j < 8; ++j)
      s = fmaf(xs[f][lane + 64 * j], Wl[lane + 64 * j], s);
#pragma unroll
    for (int off = 32; off; off >>= 1) s += __shfl_down(s, off);
    if (lane == 0) lks[f] = s;
  }
  __syncthreads();
  if (tid < 16) {
    const float v = lks[tid] + bl[0];
    leak[(size_t)be * NT + t0 + tid] = 0.1f + 0.98f / (1.f + expf(-v));
  }
  // dual MFMA GEMM
  const int arow = lane & 15;
  const int kgrp = lane >> 4;
  const int r0 = kgrp * 4;
  const int abase = arow * (NC * 2);
  const int axor = (arow & 7) << 4;
  const int akoff = kgrp * 16;
  float bwv[4], bbv[4];
#pragma unroll
  for (int p = 0; p < 4; ++p) {
    const int cp = wave * 64 + p * 16 + (lane & 15);
    bwv[p] = bw[cp];
    bbv[p] = bb[cp];
  }
  const unsigned short* wfrag = Wmf2 + (size_t)wave * 32768 + lane * 8;
  f32x4 accw[4], accb[4];
#pragma unroll
  for (int p = 0; p < 4; ++p) {
    accw[p] = (f32x4){0.f, 0.f, 0.f, 0.f};
    accb[p] = (f32x4){0.f, 0.f, 0.f, 0.f};
  }
#pragma unroll
  for (int kt = 0; kt < 16; ++kt) {
    const short8v a = *(const short8v*)((const char*)A_lds + abase +
                                        (((kt * 64) + akoff) ^ axor));
#pragma unroll
    for (int p = 0; p < 4; ++p) {
      const short8v b0 = *(const short8v*)(wfrag + (kt * 4 + p) * 512);
      accw[p] = __builtin_amdgcn_mfma_f32_16x16x32_bf16(a, b0, accw[p], 0, 0, 0);
      const short8v b1 =
          *(const short8v*)(wfrag + (size_t)262144 + (kt * 4 + p) * 512);
      accb[p] = __builtin_amdgcn_mfma_f32_16x16x32_bf16(a, b1, accb[p], 0, 0, 0);
    }
  }
  // epilogue: add bias, store both outputs (C-layout: row=r0+q, col=cp)
#pragma unroll
  for (int q = 0; q < 4; ++q) {
    const int row = r0 + q;
#pragma unroll
    for (int p = 0; p < 4; ++p) {
      const int cp = wave * 64 + p * 16 + (lane & 15);
      const size_t o = ((size_t)be * NT + t0 + row) * NC + cp;
      weights[o] = accw[p][q] + bwv[p];
      biases[o] = accb[p][q] + bbv[p];
    }
  }
}

// ---------------------------------------------------------------------------
// 16-row tile x (512x512) GEMM helper (f32, used by k_imp).
// ---------------------------------------------------------------------------
__device__ __forceinline__ void tile_gemm16(const float (*xs)[NC],
                                            const float* __restrict__ W,
                                            int tid, float acc[16]) {
#pragma unroll
  for (int i = 0; i < 16; ++i) acc[i] = 0.f;
  for (int k = 0; k < NC; k += 4) {
    const float w0 = W[(size_t)(k + 0) * NC + tid];
    const float w1 = W[(size_t)(k + 1) * NC + tid];
    const float w2 = W[(size_t)(k + 2) * NC + tid];
    const float w3 = W[(size_t)(k + 3) * NC + tid];
#pragma unroll
    for (int i = 0; i < 16; ++i) {
      const float4 a = *reinterpret_cast<const float4*>(&xs[i][k]);
      acc[i] = fmaf(a.x, w0, acc[i]);
      acc[i] = fmaf(a.y, w1, acc[i]);
      acc[i] = fmaf(a.z, w2, acc[i]);
      acc[i] = fmaf(a.w, w3, acc[i]);
    }
  }
}

// LN (+leaky) stats applied in-place on xs[16][NC] (k_imp only)
__device__ __forceinline__ void ln_leaky16(float (*xs)[NC],
                                           const float* __restrict__ g,
                                           const float* __restrict__ bt,
                                           int layer, int tid, float* mu_s,
                                           float* rs_s) {
  const int wave = tid >> 6, lane = tid & 63;
  for (int f = wave; f < 16; f += 8) {
    float s = 0.f, s2 = 0.f;
#pragma unroll
    for (int j = 0; j < 8; ++j) {
      const float v = xs[f][lane + 64 * j];
      s += v;
      s2 = fmaf(v, v, s2);
    }
#pragma unroll
    for (int off = 32; off; off >>= 1) {
      s += __shfl_down(s, off);
      s2 += __shfl_down(s2, off);
    }
    if (lane == 0) {
      const float mu = s * (1.f / NC);
      mu_s[f] = mu;
      rs_s[f] = rsqrtf(s2 * (1.f / NC) - mu * mu + 1e-5f);
    }
  }
  __syncthreads();
  const float gv = g[layer * NC + tid], btv = bt[layer * NC + tid];
#pragma unroll
  for (int i = 0; i < 16; ++i) {
    const float y = (xs[i][tid] - mu_s[i]) * rs_s[i] * gv + btv;
    xs[i][tid] = y > 0.f ? y : 0.2f * y;
  }
  __syncthreads();
}

// ---------------------------------------------------------------------------
// K3: windowed impulse -> mlp_imp -> unit_norm * window-norm -> emb stream.
// ---------------------------------------------------------------------------
__global__ __launch_bounds__(512) void k_imp(
    const float* __restrict__ impulse, const float* __restrict__ Ws,
    const float* __restrict__ bs, const float* __restrict__ g,
    const float* __restrict__ bt, float* __restrict__ embo) {
  __shared__ float xs[16][NC];
  __shared__ float wno[16], mu_s[16], rs_s[16], ono[16];
  const int tid = threadIdx.x;
  const int wave = tid >> 6, lane = tid & 63;
  const int be = blockIdx.x;
  const float* ib = impulse + (size_t)be * NIMP;
  for (int f = 0; f < 16; ++f) {
    const int s = f * 256 + tid;
    xs[f][tid] = (s < NIMP) ? ib[s] : 0.f;
  }
  __syncthreads();
  for (int f = wave; f < 16; f += 8) {
    float s = 0.f;
#pragma unroll
    for (int j = 0; j < 8; ++j) {
      const float v = xs[f][lane + 64 * j];
      s = fmaf(v, v, s);
    }
#pragma unroll
    for (int off = 32; off; off >>= 1) s += __shfl_down(s, off);
    if (lane == 0) wno[f] = sqrtf(s);
  }
  __syncthreads();
  float acc[16];
  for (int layer = 0; layer < 4; ++layer) {
    tile_gemm16(xs, Ws + (size_t)layer * NC * NC, tid, acc);
    __syncthreads();
    const float bv = bs[layer * NC + tid];
#pragma unroll
    for (int i = 0; i < 16; ++i) xs[i][tid] = acc[i] + bv;
    __syncthreads();
    if (layer < 3) ln_leaky16(xs, g, bt, layer, tid, mu_s, rs_s);
  }
  for (int f = wave; f < 16; f += 8) {
    float s = 0.f;
#pragma unroll
    for (int j = 0; j < 8; ++j) {
      const float v = xs[f][lane + 64 * j];
      s = fmaf(v, v, s);
    }
#pragma unroll
    for (int off = 32; off; off >>= 1) s += __shfl_down(s, off);
    if (lane == 0) ono[f] = sqrtf(s);
  }
  __syncthreads();
  for (int f = 0; f < 16; ++f)
    embo[((size_t)be * NF + f) * NC + tid] =
        xs[f][tid] / (ono[f] + EPSN) * wno[f];
}

// ---------------------------------------------------------------------------
// K4: the sequential scan, MFMA v8 (UNCHANGED from R10/R11 — known good).
// Hardened continuous DMA ring: 4 LDS slots/wave, 3 chunks in flight, issue
// chunk cc+3 after consuming cc (reuse distance 1 full iteration), steady
// vmcnt(8). Raw no-drain barriers keep DMA flowing through LN/reduce phases.
// ---------------------------------------------------------------------------
__global__ __launch_bounds__(512) void k_scan(
    const float* __restrict__ weights, const float* __restrict__ biases,
    const float* __restrict__ leak, const float* __restrict__ embw,
    const unsigned short* __restrict__ Wmf, const float* __restrict__ bs,
    const float* __restrict__ g, const float* __restrict__ bt,
    float* __restrict__ olb, float* __restrict__ onb) {
  __shared__ __align__(16) unsigned short A_lds[16 * NC];     // 16KB
  __shared__ __align__(16) unsigned short B_lds[8][4][2048];  // 128KB
  __shared__ float ol_lds[SPB][NC];                           // 8KB
  __shared__ float redA[64];
  __shared__ float redB[32];
  __shared__ float st1[8][SPB], st2[8][SPB];
  __shared__ float lk_lds[SPB][NT];

  const int tid = threadIdx.x;
  const int wave = tid >> 6, lane = tid & 63;
  const int seq0 = blockIdx.x * SPB;

  // stage leak slice (one element per thread)
  {
    const int r = tid >> 7, tt = tid & 127;
    lk_lds[r][tt] = leak[(size_t)(seq0 + r) * NT + tt];
  }
  // zero the pad rows 4..15 of A (never written again)
  {
    unsigned* z = (unsigned*)(A_lds + SPB * NC);
    for (int i = tid; i < (16 - SPB) * NC / 2; i += 512) z[i] = 0u;
  }

  // per-lane MFMA geometry
  const int arow = lane & 15;
  const int kgrp = lane >> 4;
  const int abase = arow * (NC * 2);
  const int axor = (arow & 7) << 4;
  const int akoff = kgrp * 16;
  const bool crow = (kgrp == 0);  // lanes holding C rows 0..3

  // hoist per-lane (t-invariant) bias / LN params for this wave's 4 n-tiles
  float bsv[4][4], gv[3][4], btv[3][4];
#pragma unroll
  for (int p = 0; p < 4; ++p) {
    const int cp = wave * 64 + p * 16 + (lane & 15);
#pragma unroll
    for (int l = 0; l < 4; ++l) bsv[l][p] = bs[l * NC + cp];
#pragma unroll
    for (int l = 0; l < 3; ++l) {
      gv[l][p] = g[l * NC + cp];
      btv[l][p] = bt[l * NC + cp];
    }
  }
  // this wave's fragment stream: fragment (layer,kt,p) at
  //   wfrag + layer*262144 + (kt*4+p)*512   (per-lane 16B at +lane*8)
  const unsigned short* wfrag = Wmf + (size_t)wave * 32768 + lane * 8;

  // DMA one 4KB chunk of the unified 64-chunk ring into slot cc&3
  auto issue_chunk = [&](int cc) {
    const int layer = cc >> 4, kt = cc & 15, slot = cc & 3;
#pragma unroll
    for (int p = 0; p < 4; ++p) {
      __builtin_amdgcn_global_load_lds(
          (const unsigned int*)(wfrag + (size_t)layer * 262144 +
                                (kt * 4 + p) * 512),
          (unsigned int*)&B_lds[wave][slot][p * 512], 16, 0, 0);
    }
  };

  // initial prefetch for t=0
  float wpre[SPB], bpre[SPB], epre[SPB];
#pragma unroll
  for (int r = 0; r < SPB; ++r) {
    const size_t o = ((size_t)(seq0 + r) * NT) * NC + tid;
    wpre[r] = weights[o];
    bpre[r] = biases[o];
    epre[r] = embw[((size_t)(seq0 + r) * NF) * NC + tid];
  }

  __syncthreads();

  // prime the ring (3 chunks in flight)
  issue_chunk(0);
  issue_chunk(1);
  issue_chunk(2);

  float h[SPB], cn[SPB];
#pragma unroll
  for (int r = 0; r < SPB; ++r) { h[r] = 0.f; cn[r] = 0.f; }

#pragma unroll 1
  for (int t = 0; t < NT; ++t) {
    float hw[SPB];
    if (t < NF) {
#pragma unroll
      for (int r = 0; r < SPB; ++r) h[r] += epre[r];
      if (t + 1 < NF) {
#pragma unroll
        for (int r = 0; r < SPB; ++r)
          epre[r] = embw[((size_t)(seq0 + r) * NF + t + 1) * NC + tid];
      }
      float v8[8], s8[8];
#pragma unroll
      for (int r = 0; r < SPB; ++r) {
        hw[r] = fmaf(h[r], wpre[r], bpre[r]);
        v8[r] = h[r] * h[r];
        v8[SPB + r] = hw[r] * hw[r];
      }
      blk_reduce1<8>(v8, s8, redA);
#pragma unroll
      for (int r = 0; r < SPB; ++r) {
        cn[r] = sqrtf(s8[r]);
        h[r] = hw[r] * (cn[r] / (sqrtf(s8[SPB + r]) + EPSN));
      }
    } else {
      float v4[SPB], s4[SPB];
#pragma unroll
      for (int r = 0; r < SPB; ++r) {
        hw[r] = fmaf(h[r], wpre[r], bpre[r]);
        v4[r] = hw[r] * hw[r];
      }
      blk_reduce1<SPB>(v4, s4, redA);
#pragma unroll
      for (int r = 0; r < SPB; ++r)
        h[r] = hw[r] * (cn[r] / (sqrtf(s4[r]) + EPSN));
    }
    // prefetch weights/biases for t+1 (flies under the MFMA phase)
    if (t + 1 < NT) {
#pragma unroll
      for (int r = 0; r < SPB; ++r) {
        const size_t o = ((size_t)(seq0 + r) * NT + t + 1) * NC + tid;
        wpre[r] = weights[o];
        bpre[r] = biases[o];
      }
    }
    // pack x -> A rows 0..3 (bf16, swizzled)
    {
      char* ab = (char*)A_lds;
#pragma unroll
      for (int r = 0; r < SPB; ++r)
        *(unsigned short*)(ab + r * 1024 + ((tid * 2) ^ ((r & 7) << 4))) =
            f2bf(h[r]);
    }
    bar_nodrain();

    // ---- 4 layers, unified DMA ring ----
#pragma unroll 1
    for (int layer = 0; layer < 4; ++layer) {
      f32x4 acc[4];
#pragma unroll
      for (int p = 0; p < 4; ++p) acc[p] = (f32x4){0.f, 0.f, 0.f, 0.f};
#pragma unroll
      for (int kt = 0; kt < 16; ++kt) {
        asm volatile("s_waitcnt vmcnt(8)" ::: "memory");
        const short8v a = *(const short8v*)((const char*)A_lds + abase +
                                            (((kt * 64) + akoff) ^ axor));
        const int slot = kt & 3;
#pragma unroll
        for (int p = 0; p < 4; ++p) {
          const short8v b =
              *(const short8v*)((const char*)&B_lds[wave][slot][0] + p * 1024 +
                                lane * 16);
          acc[p] =
              __builtin_amdgcn_mfma_f32_16x16x32_bf16(a, b, acc[p], 0, 0, 0);
        }
        issue_chunk((layer * 16 + kt + 3) & 63);
      }

      if (layer < 3) {
        float s1[SPB], s2[SPB];
#pragma unroll
        for (int q = 0; q < SPB; ++q) { s1[q] = 0.f; s2[q] = 0.f; }
#pragma unroll
        for (int p = 0; p < 4; ++p) {
#pragma unroll
          for (int q = 0; q < SPB; ++q) {
            const float y = acc[p][q] + bsv[layer][p];
            acc[p][q] = y;
            s1[q] += y;
            s2[q] = fmaf(y, y, s2[q]);
          }
        }
#pragma unroll
        for (int off = 1; off < 16; off <<= 1) {
#pragma unroll
          for (int q = 0; q < SPB; ++q) {
            s1[q] += __shfl_xor(s1[q], off);
            s2[q] += __shfl_xor(s2[q], off);
          }
        }
        if (lane == 0) {
#pragma unroll
          for (int q = 0; q < SPB; ++q) {
            st1[wave][q] = s1[q];
            st2[wave][q] = s2[q];
          }
        }
        bar_nodrain();
        float mu[SPB], rs[SPB];
#pragma unroll
        for (int q = 0; q < SPB; ++q) {
          float a1 = 0.f, a2 = 0.f;
#pragma unroll
          for (int w = 0; w < 8; ++w) {
            a1 += st1[w][q];
            a2 += st2[w][q];
          }
          mu[q] = a1 * (1.f / NC);
          rs[q] = rsqrtf(a2 * (1.f / NC) - mu[q] * mu[q] + 1e-5f);
        }
        if (crow) {
          char* ab = (char*)A_lds;
#pragma unroll
          for (int q = 0; q < SPB; ++q) {
#pragma unroll
            for (int p = 0; p < 4; ++p) {
              float y = (acc[p][q] - mu[q]) * rs[q] * gv[layer][p] +
                        btv[layer][p];
              y = y > 0.f ? y : 0.2f * y;
              const int cp = wave * 64 + p * 16 + (lane & 15);
              *(unsigned short*)(ab + q * 1024 +
                                 ((cp * 2) ^ ((q & 7) << 4))) = f2bf(y);
            }
          }
        }
        bar_nodrain();
      } else {
        // ---- final linear -> ol; epilogue ----
        float s2[SPB];
#pragma unroll
        for (int q = 0; q < SPB; ++q) s2[q] = 0.f;
#pragma unroll
        for (int p = 0; p < 4; ++p) {
#pragma unroll
          for (int q = 0; q < SPB; ++q) {
            const float y = acc[p][q] + bsv[3][p];
            acc[p][q] = y;
            s2[q] = fmaf(y, y, s2[q]);
          }
        }
#pragma unroll
        for (int off = 1; off < 16; off <<= 1) {
#pragma unroll
          for (int q = 0; q < SPB; ++q) s2[q] += __shfl_xor(s2[q], off);
        }
        if (lane == 0) {
#pragma unroll
          for (int q = 0; q < SPB; ++q) st2[wave][q] = s2[q];
        }
        if (crow) {
#pragma unroll
          for (int q = 0; q < SPB; ++q) {
#pragma unroll
            for (int p = 0; p < 4; ++p)
              ol_lds[q][wave * 64 + p * 16 + (lane & 15)] = acc[p][q];
          }
        }
        bar_nodrain();
        float sc[SPB], on[SPB];
#pragma unroll
        for (int r = 0; r < SPB; ++r) {
          float a2 = 0.f;
#pragma unroll
          for (int w = 0; w < 8; ++w) a2 += st2[w][r];
          const float no = sqrtf(a2);
          sc[r] = cn[r] * lk_lds[r][t] / (no + EPSN);
          on[r] = no * sc[r];
        }
        if (tid < SPB) onb[(size_t)(seq0 + tid) * NT + t] = on[tid];
        float v4[SPB], s4[SPB];
#pragma unroll
        for (int r = 0; r < SPB; ++r) {
          const float olv = ol_lds[r][tid] * sc[r];
          olb[((size_t)(seq0 + r) * NT + t) * NC + tid] = olv;
          h[r] -= olv;
          v4[r] = h[r] * h[r];
        }
        blk_reduce1<SPB>(v4, s4, redB);
#pragma unroll
        for (int r = 0; r < SPB; ++r) {
          h[r] *= (cn[r] - on[r]) / (sqrtf(s4[r]) + EPSN);
          cn[r] = fabsf(cn[r] - on[r]);  // ||h|| carried exactly
        }
      }
    }
  }
}

// ---------------------------------------------------------------------------
// K5: batched out-MLP, MFMA edition (UNCHANGED from R11 — known good).
// ---------------------------------------------------------------------------
__global__ __launch_bounds__(512) void k_out(
    const float* __restrict__ olb, const float* __restrict__ onb,
    const unsigned short* __restrict__ Wmf, const float* __restrict__ bs,
    const float* __restrict__ g, const float* __restrict__ bt,
    float* __restrict__ ofb) {
  __shared__ __align__(16) unsigned short A_lds[16 * NC];  // 16KB
  __shared__ float st1[8][16], st2[8][16];
  __shared__ float on_l[16];
  const int tid = threadIdx.x;
  const int wave = tid >> 6, lane = tid & 63;
  const int m0 = blockIdx.x * 16;
  const int arow = lane & 15;
  const int kgrp = lane >> 4;
  const int r0 = kgrp * 4;
  const int abase = arow * (NC * 2);
  const int axor = (arow & 7) << 4;
  const int akoff = kgrp * 16;

  float bsv[4][4], gv[3][4], btv[3][4], hamv[4];
#pragma unroll
  for (int p = 0; p < 4; ++p) {
    const int cp = wave * 64 + p * 16 + (lane & 15);
#pragma unroll
    for (int l = 0; l < 4; ++l) bsv[l][p] = bs[l * NC + cp];
#pragma unroll
    for (int l = 0; l < 3; ++l) {
      gv[l][p] = g[l * NC + cp];
      btv[l][p] = bt[l * NC + cp];
    }
    hamv[p] =
        0.54f - 0.46f * cosf(6.283185307179586f * (float)cp / (float)NC);
  }
  if (tid < 16) on_l[tid] = onb[m0 + tid];
  // pack A from olb (bf16, swizzled)
  {
    char* ab = (char*)A_lds;
    for (int i = 0; i < 16; ++i) {
      const float v = olb[(size_t)(m0 + i) * NC + tid];
      *(unsigned short*)(ab + i * 1024 + ((tid * 2) ^ ((i & 7) << 4))) =
          f2bf(v);
    }
  }
  __syncthreads();

  const unsigned short* wfrag = Wmf + (size_t)wave * 32768 + lane * 8;

#pragma unroll 1
  for (int layer = 0; layer < 4; ++layer) {
    f32x4 acc[4];
#pragma unroll
    for (int p = 0; p < 4; ++p) acc[p] = (f32x4){0.f, 0.f, 0.f, 0.f};
#pragma unroll
    for (int kt = 0; kt < 16; ++kt) {
      const short8v a = *(const short8v*)((const char*)A_lds + abase +
                                          (((kt * 64) + akoff) ^ axor));
#pragma unroll
      for (int p = 0; p < 4; ++p) {
        const short8v b = *(const short8v*)(wfrag + (size_t)layer * 262144 +
                                            (kt * 4 + p) * 512);
        acc[p] = __builtin_amdgcn_mfma_f32_16x16x32_bf16(a, b, acc[p], 0, 0, 0);
      }
    }
    if (layer < 3) {
      float s1[4], s2[4];
#pragma unroll
      for (int q = 0; q < 4; ++q) { s1[q] = 0.f; s2[q] = 0.f; }
#pragma unroll
      for (int p = 0; p < 4; ++p) {
#pragma unroll
        for (int q = 0; q < 4; ++q) {
          const float y = acc[p][q] + bsv[layer][p];
          acc[p][q] = y;
          s1[q] += y;
          s2[q] = fmaf(y, y, s2[q]);
        }
      }
#pragma unroll
      for (int off = 1; off < 16; off <<= 1) {
#pragma unroll
        for (int q = 0; q < 4; ++q) {
          s1[q] += __shfl_xor(s1[q], off);
          s2[q] += __shfl_xor(s2[q], off);
        }
      }
      if ((lane & 15) == 0) {
#pragma unroll
        for (int q = 0; q < 4; ++q) {
          st1[wave][r0 + q] = s1[q];
          st2[wave][r0 + q] = s2[q];
        }
      }
      __syncthreads();
      char* ab = (char*)A_lds;
#pragma unroll
      for (int q = 0; q < 4; ++q) {
        const int row = r0 + q;
        float a1 = 0.f, a2 = 0.f;
#pragma unroll
        for (int w = 0; w < 8; ++w) {
          a1 += st1[w][row];
          a2 += st2[w][row];
        }
        const float mu = a1 * (1.f / NC);
        const float rs = rsqrtf(a2 * (1.f / NC) - mu * mu + 1e-5f);
#pragma unroll
        for (int p = 0; p < 4; ++p) {
          float y = (acc[p][q] - mu) * rs * gv[layer][p] + btv[layer][p];
          y = y > 0.f ? y : 0.2f * y;
          const int cp = wave * 64 + p * 16 + (lane & 15);
          *(unsigned short*)(ab + row * 1024 +
                             ((cp * 2) ^ ((row & 7) << 4))) = f2bf(y);
        }
      }
      __syncthreads();
    } else {
      // bias, hamming, row-norm, scale by on
      float s2[4];
#pragma unroll
      for (int q = 0; q < 4; ++q) s2[q] = 0.f;
#pragma unroll
      for (int p = 0; p < 4; ++p) {
#pragma unroll
        for (int q = 0; q < 4; ++q) {
          float y = (acc[p][q] + bsv[3][p]) * hamv[p];
          acc[p][q] = y;
          s2[q] = fmaf(y, y, s2[q]);
        }
      }
#pragma unroll
      for (int off = 1; off < 16; off <<= 1) {
#pragma unroll
        for (int q = 0; q < 4; ++q) s2[q] += __shfl_xor(s2[q], off);
      }
      if ((lane & 15) == 0) {
#pragma unroll
        for (int q = 0; q < 4; ++q) st2[wave][r0 + q] = s2[q];
      }
      __syncthreads();
#pragma unroll
      for (int q = 0; q < 4; ++q) {
        const int row = r0 + q;
        float a2 = 0.f;
#pragma unroll
        for (int w = 0; w < 8; ++w) a2 += st2[w][row];
        const float inv = on_l[row] / (sqrtf(a2) + EPSN);
#pragma unroll
        for (int p = 0; p < 4; ++p) {
          const int cp = wave * 64 + p * 16 + (lane & 15);
          ofb[(size_t)(m0 + row) * NC + cp] = acc[p][q] * inv;
        }
      }
    }
  }
}

// ---------------------------------------------------------------------------
// K6: overlap-add at hop 256, trim to 32768.
// ---------------------------------------------------------------------------
__global__ __launch_bounds__(256) void k_oa(const float* __restrict__ ofb,
                                            float* __restrict__ out) {
  const int idx = blockIdx.x * 256 + threadIdx.x;
  if (idx >= BE * 32768) return;
  const int be = idx >> 15;
  const int s = idx & 32767;
  const int t1 = s >> 8;
  float v = ofb[((size_t)be * NT + t1) * NC + (s - (t1 << 8))];
  if (t1 >= 1)
    v += ofb[((size_t)be * NT + (t1 - 1)) * NC + (s - ((t1 - 1) << 8))];
  out[idx] = v;
}

// ---------------------------------------------------------------------------
// Workspace (< 256 MiB): region A (deform->olb) 64 MiB, region B
// (weights->ofb) 64 MiB, region C (biases) 64 MiB, small buffers ~15 MiB.
// ---------------------------------------------------------------------------
extern "C" void kernel_launch(void* const* d_in, const int* in_sizes, int n_in,
                              void* d_out, int out_size, void* d_ws,
                              size_t ws_size, hipStream_t stream) {
  const float* embedding = (const float*)d_in[0];
  const float* impulse = (const float*)d_in[1];
  const float* W_def = (const float*)d_in[2];
  const float* b_def = (const float*)d_in[3];
  const float* W_w = (const float*)d_in[4];
  const float* b_w = (const float*)d_in[5];
  const float* W_b = (const float*)d_in[6];
  const float* b_b = (const float*)d_in[7];
  const float* W_l = (const float*)d_in[8];
  const float* b_l = (const float*)d_in[9];
  const float* Ws_imp = (const float*)d_in[10];
  const float* bs_imp = (const float*)d_in[11];
  const float* g_imp = (const float*)d_in[12];
  const float* bt_imp = (const float*)d_in[13];
  const float* Ws_lat = (const float*)d_in[14];
  const float* bs_lat = (const float*)d_in[15];
  const float* g_lat = (const float*)d_in[16];
  const float* bt_lat = (const float*)d_in[17];
  const float* Ws_out = (const float*)d_in[18];
  const float* bs_out = (const float*)d_in[19];
  const float* g_out = (const float*)d_in[20];
  const float* bt_out = (const float*)d_in[21];
  float* out = (float*)d_out;

  float* ws = (float*)d_ws;
  float* deform = ws;                  // region A (reused as olb)
  float* weights = deform + 16777216;  // region B (reused as ofb)
  float* biases = weights + 16777216;  // region C
  float* leakb = biases + 16777216;    // 32,768 f
  float* embw = leakb + 32768;         // 2,097,152 f
  float* onb = embw + 2097152;         // 32,768 f
  unsigned short* wmf = (unsigned short*)(onb + 32768);    // 1,048,576 us
  unsigned short* wmf_out = wmf + 1048576;                 // 1,048,576 us
  unsigned short* wmf_wb = wmf_out + 1048576;              // 524,288 us
  float* olb = deform;                 // alias: deform dead after k_wb
  float* ofb = weights;                // alias: weights dead after k_scan

  k_cvt<<<2048, 64, 0, stream>>>(Ws_lat, wmf);
  k_cvt<<<2048, 64, 0, stream>>>(Ws_out, wmf_out);
  k_cvt<<<512, 64, 0, stream>>>(W_w, wmf_wb);
  k_cvt<<<512, 64, 0, stream>>>(W_b, wmf_wb + 262144);
  k_deform<<<dim3(256, 8), 256, 0, stream>>>(embedding, W_def, b_def, deform);
  k_wb<<<2048, 512, 0, stream>>>(deform, wmf_wb, b_w, b_b, W_l, b_l,
                                 weights, biases, leakb);
  k_imp<<<256, 512, 0, stream>>>(impulse, Ws_imp, bs_imp, g_imp, bt_imp, embw);
  k_scan<<<NSCAN, 512, 0, stream>>>(weights, biases, leakb, embw, wmf, bs_lat,
                                    g_lat, bt_lat, olb, onb);
  k_out<<<2048, 512, 0, stream>>>(olb, onb, wmf_out, bs_out, g_out, bt_out,
                                  ofb);
  k_oa<<<32768, 256, 0, stream>>>(ofb, out);
}

// Round 13
// 4311.978 us; speedup vs baseline: 3.0829x; 1.0377x over previous
//
#include <hip/hip_runtime.h>
#include <math.h>

#define NB 4
#define NE 64
#define BE 256          // NB*NE
#define LAT 256
#define NC 512          // channels == window
#define NT 128          // n_frames
#define NDEF 65536      // NC*NT
#define NIMP 4096
#define NF 16           // impulse frames
#define EPSN 1e-8f
#define SPB 4           // sequences per scan block
#define NSCAN 64        // scan blocks (BE/SPB)
#define NSAMP 32768

typedef unsigned short ushort8 __attribute__((ext_vector_type(8)));
typedef short short8v __attribute__((ext_vector_type(8)));
typedef float f32x4 __attribute__((ext_vector_type(4)));

__device__ __forceinline__ unsigned short f2bf(float f) {
  const unsigned u = __float_as_uint(f);
  return (unsigned short)((u + 0x7FFFu + ((u >> 16) & 1u)) >> 16);  // RNE
}

// raw barrier WITHOUT the vmcnt(0) drain __syncthreads emits: ds-writes are
// made visible via lgkmcnt(0); in-flight global_load_lds DMA (wave-private
// destinations) stays in flight. sched_barrier(0) pins ordering (rule #18).
__device__ __forceinline__ void bar_nodrain() {
  asm volatile("s_waitcnt lgkmcnt(0)" ::: "memory");
  __builtin_amdgcn_s_barrier();
  __builtin_amdgcn_sched_barrier(0);
}

// ---------------------------------------------------------------------------
// single-raw-barrier block reduction (used only inside k_scan's t-loop).
// ---------------------------------------------------------------------------
template <int NR>
__device__ __forceinline__ void blk_reduce1(const float* v, float* out,
                                            float* red) {
  const int tid = threadIdx.x, wave = tid >> 6, lane = tid & 63;
  float s[NR];
#pragma unroll
  for (int i = 0; i < NR; ++i) s[i] = v[i];
#pragma unroll
  for (int off = 32; off; off >>= 1) {
#pragma unroll
    for (int i = 0; i < NR; ++i) s[i] += __shfl_down(s[i], off);
  }
  if (lane == 0) {
#pragma unroll
    for (int i = 0; i < NR; ++i) red[wave * NR + i] = s[i];
  }
  bar_nodrain();
#pragma unroll
  for (int i = 0; i < NR; ++i) {
    float a = 0.f;
#pragma unroll
    for (int w = 0; w < 8; ++w) a += red[w * NR + i];
    out[i] = a;
  }
}

// ---------------------------------------------------------------------------
// K0: swizzle an L-layer [512k][512n] f32 weight stack into fragment-major
// MFMA B-frag order, bf16. Fragment (layer, wv, kt, p) lives at
//   Wmf[ ((layer*8+wv)*64 + kt*4 + p)*512 + lane*8 + j ]
//     = bf16( W[layer][kt*32 + (lane>>4)*8 + j][wv*64 + p*16 + (lane&15)] )
// Each fragment = contiguous 1KB. grid = L*512, block 64. Used for Ws_lat
// (L=4), Ws_out (L=4), and W_w / W_b (L=1 each).
// ---------------------------------------------------------------------------
__global__ __launch_bounds__(64) void k_cvt(const float* __restrict__ W,
                                            unsigned short* __restrict__ Wmf) {
  const int lane = threadIdx.x;
  const int gg = blockIdx.x;
  const int p = gg & 3;
  const int kt = (gg >> 2) & 15;
  const int wv = (gg >> 6) & 7;
  const int layer = gg >> 9;
  const int col = wv * 64 + p * 16 + (lane & 15);
  const int k0 = kt * 32 + (lane >> 4) * 8;
  ushort8 o;
#pragma unroll
  for (int j = 0; j < 8; ++j)
    o[j] = f2bf(W[((size_t)layer * NC + k0 + j) * NC + col]);
  *reinterpret_cast<ushort8*>(Wmf + ((size_t)gg * 64 + lane) * 8) = o;
}

// ---------------------------------------------------------------------------
// K1: deform = embedding @ W_def + b_def      (256 x 256) @ (256 x 65536)
// ---------------------------------------------------------------------------
__global__ __launch_bounds__(256) void k_deform(
    const float* __restrict__ emb, const float* __restrict__ Wd,
    const float* __restrict__ bd, float* __restrict__ deform) {
  __shared__ float As[32][LAT];
  const int tid = threadIdx.x;
  const int c = blockIdx.x * 256 + tid;
  const int m0 = blockIdx.y * 32;
  for (int i = 0; i < 32; ++i) As[i][tid] = emb[(m0 + i) * LAT + tid];
  __syncthreads();
  float acc[32];
#pragma unroll
  for (int i = 0; i < 32; ++i) acc[i] = 0.f;
  for (int k = 0; k < LAT; k += 4) {
    const float w0 = Wd[(size_t)(k + 0) * NDEF + c];
    const float w1 = Wd[(size_t)(k + 1) * NDEF + c];
    const float w2 = Wd[(size_t)(k + 2) * NDEF + c];
    const float w3 = Wd[(size_t)(k + 3) * NDEF + c];
#pragma unroll
    for (int i = 0; i < 32; ++i) {
      const float4 a = *reinterpret_cast<const float4*>(&As[i][k]);
      acc[i] = fmaf(a.x, w0, acc[i]);
      acc[i] = fmaf(a.y, w1, acc[i]);
      acc[i] = fmaf(a.z, w2, acc[i]);
      acc[i] = fmaf(a.w, w3, acc[i]);
    }
  }
  const float bv = bd[c];
  for (int i = 0; i < 32; ++i)
    deform[(size_t)(m0 + i) * NDEF + c] = acc[i] + bv;
}

// ---------------------------------------------------------------------------
// K2: per-(be,t) rows of deform: unit_norm over channel dim, then MFMA dual
// GEMM (UNCHANGED from R12 — known good).
// ---------------------------------------------------------------------------
__global__ __launch_bounds__(512) void k_wb(
    const float* __restrict__ deform, const unsigned short* __restrict__ Wmf2,
    const float* __restrict__ bw, const float* __restrict__ bb,
    const float* __restrict__ Wl, const float* __restrict__ bl,
    float* __restrict__ weights, float* __restrict__ biases,
    float* __restrict__ leak) {
  __shared__ float xs[16][NC];                             // 32KB
  __shared__ __align__(16) unsigned short A_lds[16 * NC];  // 16KB
  __shared__ float rno[16], lks[16];
  const int tid = threadIdx.x;
  const int wave = tid >> 6, lane = tid & 63;
  const int be = blockIdx.x >> 3;
  const int t0 = (blockIdx.x & 7) * 16;
  const float* dbase = deform + (size_t)be * NDEF;
  for (int i = 0; i < 16; ++i)
    xs[i][tid] = dbase[(size_t)tid * NT + t0 + i];
  __syncthreads();
  for (int f = wave; f < 16; f += 8) {
    float s = 0.f;
#pragma unroll
    for (int j = 0; j < 8; ++j) {
      const float v = xs[f][lane + 64 * j];
      s = fmaf(v, v, s);
    }
#pragma unroll
    for (int off = 32; off; off >>= 1) s += __shfl_down(s, off);
    if (lane == 0) rno[f] = sqrtf(s);
  }
  __syncthreads();
  {
    char* ab = (char*)A_lds;
#pragma unroll
    for (int i = 0; i < 16; ++i) {
      const float xv = xs[i][tid] / (rno[i] + EPSN);
      xs[i][tid] = xv;
      *(unsigned short*)(ab + i * 1024 + ((tid * 2) ^ ((i & 7) << 4))) =
          f2bf(xv);
    }
  }
  __syncthreads();
  for (int f = wave; f < 16; f += 8) {
    float s = 0.f;
#pragma unroll
    for (int j = 0; j < 8; ++j)
      s = fmaf(xs[f][lane + 64 * j], Wl[lane + 64 * j], s);
#pragma unroll
    for (int off = 32; off; off >>= 1) s += __shfl_down(s, off);
    if (lane == 0) lks[f] = s;
  }
  __syncthreads();
  if (tid < 16) {
    const float v = lks[tid] + bl[0];
    leak[(size_t)be * NT + t0 + tid] = 0.1f + 0.98f / (1.f + expf(-v));
  }
  const int arow = lane & 15;
  const int kgrp = lane >> 4;
  const int r0 = kgrp * 4;
  const int abase = arow * (NC * 2);
  const int axor = (arow & 7) << 4;
  const int akoff = kgrp * 16;
  float bwv[4], bbv[4];
#pragma unroll
  for (int p = 0; p < 4; ++p) {
    const int cp = wave * 64 + p * 16 + (lane & 15);
    bwv[p] = bw[cp];
    bbv[p] = bb[cp];
  }
  const unsigned short* wfrag = Wmf2 + (size_t)wave * 32768 + lane * 8;
  f32x4 accw[4], accb[4];
#pragma unroll
  for (int p = 0; p < 4; ++p) {
    accw[p] = (f32x4){0.f, 0.f, 0.f, 0.f};
    accb[p] = (f32x4){0.f, 0.f, 0.f, 0.f};
  }
#pragma unroll
  for (int kt = 0; kt < 16; ++kt) {
    const short8v a = *(const short8v*)((const char*)A_lds + abase +
                                        (((kt * 64) + akoff) ^ axor));
#pragma unroll
    for (int p = 0; p < 4; ++p) {
      const short8v b0 = *(const short8v*)(wfrag + (kt * 4 + p) * 512);
      accw[p] = __builtin_amdgcn_mfma_f32_16x16x32_bf16(a, b0, accw[p], 0, 0, 0);
      const short8v b1 =
          *(const short8v*)(wfrag + (size_t)262144 + (kt * 4 + p) * 512);
      accb[p] = __builtin_amdgcn_mfma_f32_16x16x32_bf16(a, b1, accb[p], 0, 0, 0);
    }
  }
#pragma unroll
  for (int q = 0; q < 4; ++q) {
    const int row = r0 + q;
#pragma unroll
    for (int p = 0; p < 4; ++p) {
      const int cp = wave * 64 + p * 16 + (lane & 15);
      const size_t o = ((size_t)be * NT + t0 + row) * NC + cp;
      weights[o] = accw[p][q] + bwv[p];
      biases[o] = accb[p][q] + bbv[p];
    }
  }
}

// ---------------------------------------------------------------------------
// 16-row tile x (512x512) GEMM helper (f32, used by k_imp).
// ---------------------------------------------------------------------------
__device__ __forceinline__ void tile_gemm16(const float (*xs)[NC],
                                            const float* __restrict__ W,
                                            int tid, float acc[16]) {
#pragma unroll
  for (int i = 0; i < 16; ++i) acc[i] = 0.f;
  for (int k = 0; k < NC; k += 4) {
    const float w0 = W[(size_t)(k + 0) * NC + tid];
    const float w1 = W[(size_t)(k + 1) * NC + tid];
    const float w2 = W[(size_t)(k + 2) * NC + tid];
    const float w3 = W[(size_t)(k + 3) * NC + tid];
#pragma unroll
    for (int i = 0; i < 16; ++i) {
      const float4 a = *reinterpret_cast<const float4*>(&xs[i][k]);
      acc[i] = fmaf(a.x, w0, acc[i]);
      acc[i] = fmaf(a.y, w1, acc[i]);
      acc[i] = fmaf(a.z, w2, acc[i]);
      acc[i] = fmaf(a.w, w3, acc[i]);
    }
  }
}

// LN (+leaky) stats applied in-place on xs[16][NC] (k_imp only)
__device__ __forceinline__ void ln_leaky16(float (*xs)[NC],
                                           const float* __restrict__ g,
                                           const float* __restrict__ bt,
                                           int layer, int tid, float* mu_s,
                                           float* rs_s) {
  const int wave = tid >> 6, lane = tid & 63;
  for (int f = wave; f < 16; f += 8) {
    float s = 0.f, s2 = 0.f;
#pragma unroll
    for (int j = 0; j < 8; ++j) {
      const float v = xs[f][lane + 64 * j];
      s += v;
      s2 = fmaf(v, v, s2);
    }
#pragma unroll
    for (int off = 32; off; off >>= 1) {
      s += __shfl_down(s, off);
      s2 += __shfl_down(s2, off);
    }
    if (lane == 0) {
      const float mu = s * (1.f / NC);
      mu_s[f] = mu;
      rs_s[f] = rsqrtf(s2 * (1.f / NC) - mu * mu + 1e-5f);
    }
  }
  __syncthreads();
  const float gv = g[layer * NC + tid], btv = bt[layer * NC + tid];
#pragma unroll
  for (int i = 0; i < 16; ++i) {
    const float y = (xs[i][tid] - mu_s[i]) * rs_s[i] * gv + btv;
    xs[i][tid] = y > 0.f ? y : 0.2f * y;
  }
  __syncthreads();
}

// ---------------------------------------------------------------------------
// K3: windowed impulse -> mlp_imp -> unit_norm * window-norm -> emb stream.
// ---------------------------------------------------------------------------
__global__ __launch_bounds__(512) void k_imp(
    const float* __restrict__ impulse, const float* __restrict__ Ws,
    const float* __restrict__ bs, const float* __restrict__ g,
    const float* __restrict__ bt, float* __restrict__ embo) {
  __shared__ float xs[16][NC];
  __shared__ float wno[16], mu_s[16], rs_s[16], ono[16];
  const int tid = threadIdx.x;
  const int wave = tid >> 6, lane = tid & 63;
  const int be = blockIdx.x;
  const float* ib = impulse + (size_t)be * NIMP;
  for (int f = 0; f < 16; ++f) {
    const int s = f * 256 + tid;
    xs[f][tid] = (s < NIMP) ? ib[s] : 0.f;
  }
  __syncthreads();
  for (int f = wave; f < 16; f += 8) {
    float s = 0.f;
#pragma unroll
    for (int j = 0; j < 8; ++j) {
      const float v = xs[f][lane + 64 * j];
      s = fmaf(v, v, s);
    }
#pragma unroll
    for (int off = 32; off; off >>= 1) s += __shfl_down(s, off);
    if (lane == 0) wno[f] = sqrtf(s);
  }
  __syncthreads();
  float acc[16];
  for (int layer = 0; layer < 4; ++layer) {
    tile_gemm16(xs, Ws + (size_t)layer * NC * NC, tid, acc);
    __syncthreads();
    const float bv = bs[layer * NC + tid];
#pragma unroll
    for (int i = 0; i < 16; ++i) xs[i][tid] = acc[i] + bv;
    __syncthreads();
    if (layer < 3) ln_leaky16(xs, g, bt, layer, tid, mu_s, rs_s);
  }
  for (int f = wave; f < 16; f += 8) {
    float s = 0.f;
#pragma unroll
    for (int j = 0; j < 8; ++j) {
      const float v = xs[f][lane + 64 * j];
      s = fmaf(v, v, s);
    }
#pragma unroll
    for (int off = 32; off; off >>= 1) s += __shfl_down(s, off);
    if (lane == 0) ono[f] = sqrtf(s);
  }
  __syncthreads();
  for (int f = 0; f < 16; ++f)
    embo[((size_t)be * NF + f) * NC + tid] =
        xs[f][tid] / (ono[f] + EPSN) * wno[f];
}

// ---------------------------------------------------------------------------
// K4: the sequential scan, MFMA v9 = v8 + EARLY PREFETCH: the t+1
// weights/biases/embw loads are issued right after hw is computed (before the
// head reduction's barrier) — they retire during the barrier instead of
// blocking layer-0's vmcnt(8) (prefetch VMEM ops are older than the DMA
// chunks, so vmcnt counts them first). Ring/barrier structure unchanged.
// ---------------------------------------------------------------------------
__global__ __launch_bounds__(512) void k_scan(
    const float* __restrict__ weights, const float* __restrict__ biases,
    const float* __restrict__ leak, const float* __restrict__ embw,
    const unsigned short* __restrict__ Wmf, const float* __restrict__ bs,
    const float* __restrict__ g, const float* __restrict__ bt,
    float* __restrict__ olb, float* __restrict__ onb) {
  __shared__ __align__(16) unsigned short A_lds[16 * NC];     // 16KB
  __shared__ __align__(16) unsigned short B_lds[8][4][2048];  // 128KB
  __shared__ float ol_lds[SPB][NC];                           // 8KB
  __shared__ float redA[64];
  __shared__ float redB[32];
  __shared__ float st1[8][SPB], st2[8][SPB];
  __shared__ float lk_lds[SPB][NT];

  const int tid = threadIdx.x;
  const int wave = tid >> 6, lane = tid & 63;
  const int seq0 = blockIdx.x * SPB;

  {
    const int r = tid >> 7, tt = tid & 127;
    lk_lds[r][tt] = leak[(size_t)(seq0 + r) * NT + tt];
  }
  {
    unsigned* z = (unsigned*)(A_lds + SPB * NC);
    for (int i = tid; i < (16 - SPB) * NC / 2; i += 512) z[i] = 0u;
  }

  const int arow = lane & 15;
  const int kgrp = lane >> 4;
  const int abase = arow * (NC * 2);
  const int axor = (arow & 7) << 4;
  const int akoff = kgrp * 16;
  const bool crow = (kgrp == 0);

  float bsv[4][4], gv[3][4], btv[3][4];
#pragma unroll
  for (int p = 0; p < 4; ++p) {
    const int cp = wave * 64 + p * 16 + (lane & 15);
#pragma unroll
    for (int l = 0; l < 4; ++l) bsv[l][p] = bs[l * NC + cp];
#pragma unroll
    for (int l = 0; l < 3; ++l) {
      gv[l][p] = g[l * NC + cp];
      btv[l][p] = bt[l * NC + cp];
    }
  }
  const unsigned short* wfrag = Wmf + (size_t)wave * 32768 + lane * 8;

  auto issue_chunk = [&](int cc) {
    const int layer = cc >> 4, kt = cc & 15, slot = cc & 3;
#pragma unroll
    for (int p = 0; p < 4; ++p) {
      __builtin_amdgcn_global_load_lds(
          (const unsigned int*)(wfrag + (size_t)layer * 262144 +
                                (kt * 4 + p) * 512),
          (unsigned int*)&B_lds[wave][slot][p * 512], 16, 0, 0);
    }
  };

  float wpre[SPB], bpre[SPB], epre[SPB];
#pragma unroll
  for (int r = 0; r < SPB; ++r) {
    const size_t o = ((size_t)(seq0 + r) * NT) * NC + tid;
    wpre[r] = weights[o];
    bpre[r] = biases[o];
    epre[r] = embw[((size_t)(seq0 + r) * NF) * NC + tid];
  }

  __syncthreads();

  issue_chunk(0);
  issue_chunk(1);
  issue_chunk(2);

  float h[SPB], cn[SPB];
#pragma unroll
  for (int r = 0; r < SPB; ++r) { h[r] = 0.f; cn[r] = 0.f; }

#pragma unroll 1
  for (int t = 0; t < NT; ++t) {
    float hw[SPB];
    if (t < NF) {
#pragma unroll
      for (int r = 0; r < SPB; ++r) h[r] += epre[r];
      float v8[8], s8[8];
#pragma unroll
      for (int r = 0; r < SPB; ++r) {
        hw[r] = fmaf(h[r], wpre[r], bpre[r]);
        v8[r] = h[r] * h[r];
        v8[SPB + r] = hw[r] * hw[r];
      }
      // EARLY prefetch for t+1 (flies across the reduction barrier)
      if (t + 1 < NF) {
#pragma unroll
        for (int r = 0; r < SPB; ++r)
          epre[r] = embw[((size_t)(seq0 + r) * NF + t + 1) * NC + tid];
      }
      if (t + 1 < NT) {
#pragma unroll
        for (int r = 0; r < SPB; ++r) {
          const size_t o = ((size_t)(seq0 + r) * NT + t + 1) * NC + tid;
          wpre[r] = weights[o];
          bpre[r] = biases[o];
        }
      }
      blk_reduce1<8>(v8, s8, redA);
#pragma unroll
      for (int r = 0; r < SPB; ++r) {
        cn[r] = sqrtf(s8[r]);
        h[r] = hw[r] * (cn[r] / (sqrtf(s8[SPB + r]) + EPSN));
      }
    } else {
      float v4[SPB], s4[SPB];
#pragma unroll
      for (int r = 0; r < SPB; ++r) {
        hw[r] = fmaf(h[r], wpre[r], bpre[r]);
        v4[r] = hw[r] * hw[r];
      }
      // EARLY prefetch for t+1
      if (t + 1 < NT) {
#pragma unroll
        for (int r = 0; r < SPB; ++r) {
          const size_t o = ((size_t)(seq0 + r) * NT + t + 1) * NC + tid;
          wpre[r] = weights[o];
          bpre[r] = biases[o];
        }
      }
      blk_reduce1<SPB>(v4, s4, redA);
#pragma unroll
      for (int r = 0; r < SPB; ++r)
        h[r] = hw[r] * (cn[r] / (sqrtf(s4[r]) + EPSN));
    }
    // pack x -> A rows 0..3 (bf16, swizzled)
    {
      char* ab = (char*)A_lds;
#pragma unroll
      for (int r = 0; r < SPB; ++r)
        *(unsigned short*)(ab + r * 1024 + ((tid * 2) ^ ((r & 7) << 4))) =
            f2bf(h[r]);
    }
    bar_nodrain();

    // ---- 4 layers, unified DMA ring ----
#pragma unroll 1
    for (int layer = 0; layer < 4; ++layer) {
      f32x4 acc[4];
#pragma unroll
      for (int p = 0; p < 4; ++p) acc[p] = (f32x4){0.f, 0.f, 0.f, 0.f};
#pragma unroll
      for (int kt = 0; kt < 16; ++kt) {
        asm volatile("s_waitcnt vmcnt(8)" ::: "memory");
        const short8v a = *(const short8v*)((const char*)A_lds + abase +
                                            (((kt * 64) + akoff) ^ axor));
        const int slot = kt & 3;
#pragma unroll
        for (int p = 0; p < 4; ++p) {
          const short8v b =
              *(const short8v*)((const char*)&B_lds[wave][slot][0] + p * 1024 +
                                lane * 16);
          acc[p] =
              __builtin_amdgcn_mfma_f32_16x16x32_bf16(a, b, acc[p], 0, 0, 0);
        }
        issue_chunk((layer * 16 + kt + 3) & 63);
      }

      if (layer < 3) {
        float s1[SPB], s2[SPB];
#pragma unroll
        for (int q = 0; q < SPB; ++q) { s1[q] = 0.f; s2[q] = 0.f; }
#pragma unroll
        for (int p = 0; p < 4; ++p) {
#pragma unroll
          for (int q = 0; q < SPB; ++q) {
            const float y = acc[p][q] + bsv[layer][p];
            acc[p][q] = y;
            s1[q] += y;
            s2[q] = fmaf(y, y, s2[q]);
          }
        }
#pragma unroll
        for (int off = 1; off < 16; off <<= 1) {
#pragma unroll
          for (int q = 0; q < SPB; ++q) {
            s1[q] += __shfl_xor(s1[q], off);
            s2[q] += __shfl_xor(s2[q], off);
          }
        }
        if (lane == 0) {
#pragma unroll
          for (int q = 0; q < SPB; ++q) {
            st1[wave][q] = s1[q];
            st2[wave][q] = s2[q];
          }
        }
        bar_nodrain();
        float mu[SPB], rs[SPB];
#pragma unroll
        for (int q = 0; q < SPB; ++q) {
          float a1 = 0.f, a2 = 0.f;
#pragma unroll
          for (int w = 0; w < 8; ++w) {
            a1 += st1[w][q];
            a2 += st2[w][q];
          }
          mu[q] = a1 * (1.f / NC);
          rs[q] = rsqrtf(a2 * (1.f / NC) - mu[q] * mu[q] + 1e-5f);
        }
        if (crow) {
          char* ab = (char*)A_lds;
#pragma unroll
          for (int q = 0; q < SPB; ++q) {
#pragma unroll
            for (int p = 0; p < 4; ++p) {
              float y = (acc[p][q] - mu[q]) * rs[q] * gv[layer][p] +
                        btv[layer][p];
              y = y > 0.f ? y : 0.2f * y;
              const int cp = wave * 64 + p * 16 + (lane & 15);
              *(unsigned short*)(ab + q * 1024 +
                                 ((cp * 2) ^ ((q & 7) << 4))) = f2bf(y);
            }
          }
        }
        bar_nodrain();
      } else {
        // ---- final linear -> ol; epilogue ----
        float s2[SPB];
#pragma unroll
        for (int q = 0; q < SPB; ++q) s2[q] = 0.f;
#pragma unroll
        for (int p = 0; p < 4; ++p) {
#pragma unroll
          for (int q = 0; q < SPB; ++q) {
            const float y = acc[p][q] + bsv[3][p];
            acc[p][q] = y;
            s2[q] = fmaf(y, y, s2[q]);
          }
        }
#pragma unroll
        for (int off = 1; off < 16; off <<= 1) {
#pragma unroll
          for (int q = 0; q < SPB; ++q) s2[q] += __shfl_xor(s2[q], off);
        }
        if (lane == 0) {
#pragma unroll
          for (int q = 0; q < SPB; ++q) st2[wave][q] = s2[q];
        }
        if (crow) {
#pragma unroll
          for (int q = 0; q < SPB; ++q) {
#pragma unroll
            for (int p = 0; p < 4; ++p)
              ol_lds[q][wave * 64 + p * 16 + (lane & 15)] = acc[p][q];
          }
        }
        bar_nodrain();
        float sc[SPB], on[SPB];
#pragma unroll
        for (int r = 0; r < SPB; ++r) {
          float a2 = 0.f;
#pragma unroll
          for (int w = 0; w < 8; ++w) a2 += st2[w][r];
          const float no = sqrtf(a2);
          sc[r] = cn[r] * lk_lds[r][t] / (no + EPSN);
          on[r] = no * sc[r];
        }
        if (tid < SPB) onb[(size_t)(seq0 + tid) * NT + t] = on[tid];
        float v4[SPB], s4[SPB];
#pragma unroll
        for (int r = 0; r < SPB; ++r) {
          const float olv = ol_lds[r][tid] * sc[r];
          olb[((size_t)(seq0 + r) * NT + t) * NC + tid] = olv;
          h[r] -= olv;
          v4[r] = h[r] * h[r];
        }
        blk_reduce1<SPB>(v4, s4, redB);
#pragma unroll
        for (int r = 0; r < SPB; ++r) {
          h[r] *= (cn[r] - on[r]) / (sqrtf(s4[r]) + EPSN);
          cn[r] = fabsf(cn[r] - on[r]);  // ||h|| carried exactly
        }
      }
    }
  }
}

// ---------------------------------------------------------------------------
// K_zero: zero-init the output buffer (d_out is poisoned by the harness).
// ---------------------------------------------------------------------------
__global__ __launch_bounds__(1024) void k_zero(float* __restrict__ out) {
  out[(size_t)blockIdx.x * 1024 + threadIdx.x] = 0.f;
}

// ---------------------------------------------------------------------------
// K5: batched out-MLP, MFMA edition, FUSED overlap-add. Instead of writing
// ofb and running a separate k_oa pass, each block atomicAdds its 16 frames
// into out at hop 256. Every output sample receives exactly <=2 contributions
// (frames t1-1, t1), and two-term FP adds are order-invariant -> output is
// deterministic. Frame t=127's high half (samples >= 32768) is trimmed.
// ---------------------------------------------------------------------------
__global__ __launch_bounds__(512) void k_out(
    const float* __restrict__ olb, const float* __restrict__ onb,
    const unsigned short* __restrict__ Wmf, const float* __restrict__ bs,
    const float* __restrict__ g, const float* __restrict__ bt,
    float* __restrict__ out) {
  __shared__ __align__(16) unsigned short A_lds[16 * NC];  // 16KB
  __shared__ float st1[8][16], st2[8][16];
  __shared__ float on_l[16];
  const int tid = threadIdx.x;
  const int wave = tid >> 6, lane = tid & 63;
  const int m0 = blockIdx.x * 16;
  const int arow = lane & 15;
  const int kgrp = lane >> 4;
  const int r0 = kgrp * 4;
  const int abase = arow * (NC * 2);
  const int axor = (arow & 7) << 4;
  const int akoff = kgrp * 16;

  float bsv[4][4], gv[3][4], btv[3][4], hamv[4];
#pragma unroll
  for (int p = 0; p < 4; ++p) {
    const int cp = wave * 64 + p * 16 + (lane & 15);
#pragma unroll
    for (int l = 0; l < 4; ++l) bsv[l][p] = bs[l * NC + cp];
#pragma unroll
    for (int l = 0; l < 3; ++l) {
      gv[l][p] = g[l * NC + cp];
      btv[l][p] = bt[l * NC + cp];
    }
    hamv[p] =
        0.54f - 0.46f * cosf(6.283185307179586f * (float)cp / (float)NC);
  }
  if (tid < 16) on_l[tid] = onb[m0 + tid];
  {
    char* ab = (char*)A_lds;
    for (int i = 0; i < 16; ++i) {
      const float v = olb[(size_t)(m0 + i) * NC + tid];
      *(unsigned short*)(ab + i * 1024 + ((tid * 2) ^ ((i & 7) << 4))) =
          f2bf(v);
    }
  }
  __syncthreads();

  const unsigned short* wfrag = Wmf + (size_t)wave * 32768 + lane * 8;

#pragma unroll 1
  for (int layer = 0; layer < 4; ++layer) {
    f32x4 acc[4];
#pragma unroll
    for (int p = 0; p < 4; ++p) acc[p] = (f32x4){0.f, 0.f, 0.f, 0.f};
#pragma unroll
    for (int kt = 0; kt < 16; ++kt) {
      const short8v a = *(const short8v*)((const char*)A_lds + abase +
                                          (((kt * 64) + akoff) ^ axor));
#pragma unroll
      for (int p = 0; p < 4; ++p) {
        const short8v b = *(const short8v*)(wfrag + (size_t)layer * 262144 +
                                            (kt * 4 + p) * 512);
        acc[p] = __builtin_amdgcn_mfma_f32_16x16x32_bf16(a, b, acc[p], 0, 0, 0);
      }
    }
    if (layer < 3) {
      float s1[4], s2[4];
#pragma unroll
      for (int q = 0; q < 4; ++q) { s1[q] = 0.f; s2[q] = 0.f; }
#pragma unroll
      for (int p = 0; p < 4; ++p) {
#pragma unroll
        for (int q = 0; q < 4; ++q) {
          const float y = acc[p][q] + bsv[layer][p];
          acc[p][q] = y;
          s1[q] += y;
          s2[q] = fmaf(y, y, s2[q]);
        }
      }
#pragma unroll
      for (int off = 1; off < 16; off <<= 1) {
#pragma unroll
        for (int q = 0; q < 4; ++q) {
          s1[q] += __shfl_xor(s1[q], off);
          s2[q] += __shfl_xor(s2[q], off);
        }
      }
      if ((lane & 15) == 0) {
#pragma unroll
        for (int q = 0; q < 4; ++q) {
          st1[wave][r0 + q] = s1[q];
          st2[wave][r0 + q] = s2[q];
        }
      }
      __syncthreads();
      char* ab = (char*)A_lds;
#pragma unroll
      for (int q = 0; q < 4; ++q) {
        const int row = r0 + q;
        float a1 = 0.f, a2 = 0.f;
#pragma unroll
        for (int w = 0; w < 8; ++w) {
          a1 += st1[w][row];
          a2 += st2[w][row];
        }
        const float mu = a1 * (1.f / NC);
        const float rs = rsqrtf(a2 * (1.f / NC) - mu * mu + 1e-5f);
#pragma unroll
        for (int p = 0; p < 4; ++p) {
          float y = (acc[p][q] - mu) * rs * gv[layer][p] + btv[layer][p];
          y = y > 0.f ? y : 0.2f * y;
          const int cp = wave * 64 + p * 16 + (lane & 15);
          *(unsigned short*)(ab + row * 1024 +
                             ((cp * 2) ^ ((row & 7) << 4))) = f2bf(y);
        }
      }
      __syncthreads();
    } else {
      // bias, hamming, row-norm, scale by on, overlap-add into out
      float s2[4];
#pragma unroll
      for (int q = 0; q < 4; ++q) s2[q] = 0.f;
#pragma unroll
      for (int p = 0; p < 4; ++p) {
#pragma unroll
        for (int q = 0; q < 4; ++q) {
          float y = (acc[p][q] + bsv[3][p]) * hamv[p];
          acc[p][q] = y;
          s2[q] = fmaf(y, y, s2[q]);
        }
      }
#pragma unroll
      for (int off = 1; off < 16; off <<= 1) {
#pragma unroll
        for (int q = 0; q < 4; ++q) s2[q] += __shfl_xor(s2[q], off);
      }
      if ((lane & 15) == 0) {
#pragma unroll
        for (int q = 0; q < 4; ++q) st2[wave][r0 + q] = s2[q];
      }
      __syncthreads();
#pragma unroll
      for (int q = 0; q < 4; ++q) {
        const int row = r0 + q;          // global row m0+row = be*NT + t
        const int gr = m0 + row;
        const int be = gr >> 7;
        const int tt = gr & 127;
        float a2 = 0.f;
#pragma unroll
        for (int w = 0; w < 8; ++w) a2 += st2[w][row];
        const float inv = on_l[row] / (sqrtf(a2) + EPSN);
#pragma unroll
        for (int p = 0; p < 4; ++p) {
          const int cp = wave * 64 + p * 16 + (lane & 15);
          const int s = tt * 256 + cp;   // sample index within sequence
          if (s < NSAMP)
            atomicAdd(&out[(size_t)be * NSAMP + s], acc[p][q] * inv);
        }
      }
    }
  }
}

// ---------------------------------------------------------------------------
// Workspace (< 256 MiB): region A (deform->olb) 64 MiB, region B
// (weights, dead after k_scan) 64 MiB, region C (biases) 64 MiB, small
// buffers ~15 MiB.
// ---------------------------------------------------------------------------
extern "C" void kernel_launch(void* const* d_in, const int* in_sizes, int n_in,
                              void* d_out, int out_size, void* d_ws,
                              size_t ws_size, hipStream_t stream) {
  const float* embedding = (const float*)d_in[0];
  const float* impulse = (const float*)d_in[1];
  const float* W_def = (const float*)d_in[2];
  const float* b_def = (const float*)d_in[3];
  const float* W_w = (const float*)d_in[4];
  const float* b_w = (const float*)d_in[5];
  const float* W_b = (const float*)d_in[6];
  const float* b_b = (const float*)d_in[7];
  const float* W_l = (const float*)d_in[8];
  const float* b_l = (const float*)d_in[9];
  const float* Ws_imp = (const float*)d_in[10];
  const float* bs_imp = (const float*)d_in[11];
  const float* g_imp = (const float*)d_in[12];
  const float* bt_imp = (const float*)d_in[13];
  const float* Ws_lat = (const float*)d_in[14];
  const float* bs_lat = (const float*)d_in[15];
  const float* g_lat = (const float*)d_in[16];
  const float* bt_lat = (const float*)d_in[17];
  const float* Ws_out = (const float*)d_in[18];
  const float* bs_out = (const float*)d_in[19];
  const float* g_out = (const float*)d_in[20];
  const float* bt_out = (const float*)d_in[21];
  float* out = (float*)d_out;

  float* ws = (float*)d_ws;
  float* deform = ws;                  // region A (reused as olb)
  float* weights = deform + 16777216;  // region B
  float* biases = weights + 16777216;  // region C
  float* leakb = biases + 16777216;    // 32,768 f
  float* embw = leakb + 32768;         // 2,097,152 f
  float* onb = embw + 2097152;         // 32,768 f
  unsigned short* wmf = (unsigned short*)(onb + 32768);    // 1,048,576 us
  unsigned short* wmf_out = wmf + 1048576;                 // 1,048,576 us
  unsigned short* wmf_wb = wmf_out + 1048576;              // 524,288 us
  float* olb = deform;                 // alias: deform dead after k_wb

  k_cvt<<<2048, 64, 0, stream>>>(Ws_lat, wmf);
  k_cvt<<<2048, 64, 0, stream>>>(Ws_out, wmf_out);
  k_cvt<<<512, 64, 0, stream>>>(W_w, wmf_wb);
  k_cvt<<<512, 64, 0, stream>>>(W_b, wmf_wb + 262144);
  k_deform<<<dim3(256, 8), 256, 0, stream>>>(embedding, W_def, b_def, deform);
  k_wb<<<2048, 512, 0, stream>>>(deform, wmf_wb, b_w, b_b, W_l, b_l,
                                 weights, biases, leakb);
  k_imp<<<256, 512, 0, stream>>>(impulse, Ws_imp, bs_imp, g_imp, bt_imp, embw);
  k_zero<<<(BE * NSAMP) / 1024, 1024, 0, stream>>>(out);
  k_scan<<<NSCAN, 512, 0, stream>>>(weights, biases, leakb, embw, wmf, bs_lat,
                                    g_lat, bt_lat, olb, onb);
  k_out<<<2048, 512, 0, stream>>>(olb, onb, wmf_out, bs_out, g_out, bt_out,
                                  out);
}

// Round 14
// 4169.947 us; speedup vs baseline: 3.1879x; 1.0341x over previous
//
#include <hip/hip_runtime.h>
#include <math.h>

#define NB 4
#define NE 64
#define BE 256          // NB*NE
#define LAT 256
#define NC 512          // channels == window
#define NT 128          // n_frames
#define NDEF 65536      // NC*NT
#define NIMP 4096
#define NF 16           // impulse frames
#define EPSN 1e-8f
#define SPB 4           // sequences per scan block
#define NSCAN 64        // scan blocks (BE/SPB)
#define NSAMP 32768

typedef unsigned short ushort8 __attribute__((ext_vector_type(8)));
typedef short short8v __attribute__((ext_vector_type(8)));
typedef float f32x4 __attribute__((ext_vector_type(4)));

__device__ __forceinline__ unsigned short f2bf(float f) {
  const unsigned u = __float_as_uint(f);
  return (unsigned short)((u + 0x7FFFu + ((u >> 16) & 1u)) >> 16);  // RNE
}

// raw barrier WITHOUT the vmcnt(0) drain __syncthreads emits.
__device__ __forceinline__ void bar_nodrain() {
  asm volatile("s_waitcnt lgkmcnt(0)" ::: "memory");
  __builtin_amdgcn_s_barrier();
  __builtin_amdgcn_sched_barrier(0);
}

// ---------------------------------------------------------------------------
// single-raw-barrier block reduction (used only inside k_scan's t-loop).
// ---------------------------------------------------------------------------
template <int NR>
__device__ __forceinline__ void blk_reduce1(const float* v, float* out,
                                            float* red) {
  const int tid = threadIdx.x, wave = tid >> 6, lane = tid & 63;
  float s[NR];
#pragma unroll
  for (int i = 0; i < NR; ++i) s[i] = v[i];
#pragma unroll
  for (int off = 32; off; off >>= 1) {
#pragma unroll
    for (int i = 0; i < NR; ++i) s[i] += __shfl_down(s[i], off);
  }
  if (lane == 0) {
#pragma unroll
    for (int i = 0; i < NR; ++i) red[wave * NR + i] = s[i];
  }
  bar_nodrain();
#pragma unroll
  for (int i = 0; i < NR; ++i) {
    float a = 0.f;
#pragma unroll
    for (int w = 0; w < 8; ++w) a += red[w * NR + i];
    out[i] = a;
  }
}

// ---------------------------------------------------------------------------
// K0: swizzle an L-layer [512k][512n] f32 weight stack into fragment-major
// MFMA B-frag order, bf16 (validated template). grid = L*512, block 64.
// ---------------------------------------------------------------------------
__global__ __launch_bounds__(64) void k_cvt(const float* __restrict__ W,
                                            unsigned short* __restrict__ Wmf) {
  const int lane = threadIdx.x;
  const int gg = blockIdx.x;
  const int p = gg & 3;
  const int kt = (gg >> 2) & 15;
  const int wv = (gg >> 6) & 7;
  const int layer = gg >> 9;
  const int col = wv * 64 + p * 16 + (lane & 15);
  const int k0 = kt * 32 + (lane >> 4) * 8;
  ushort8 o;
#pragma unroll
  for (int j = 0; j < 8; ++j)
    o[j] = f2bf(W[((size_t)layer * NC + k0 + j) * NC + col]);
  *reinterpret_cast<ushort8*>(Wmf + ((size_t)gg * 64 + lane) * 8) = o;
}

// ---------------------------------------------------------------------------
// K0b: swizzle W_def ([256 k][65536 n] f32) into fragment-major bf16.
// Fragment (nb, wv, kt, p): Wd[ (((nb*8+wv)*8 + kt)*4 + p)*512 + lane*8 + j ]
//   = bf16( W[kt*32 + (lane>>4)*8 + j][nb*512 + wv*64 + p*16 + (lane&15)] )
// kt in 0..7 (K=256). grid 32768 (= nb*256 + wv*32 + kt*4 + p), block 64.
// ---------------------------------------------------------------------------
__global__ __launch_bounds__(64) void k_cvt_def(
    const float* __restrict__ W, unsigned short* __restrict__ Wd) {
  const int lane = threadIdx.x;
  const int gg = blockIdx.x;
  const int p = gg & 3;
  const int kt = (gg >> 2) & 7;
  const int wv = (gg >> 5) & 7;
  const int nb = gg >> 8;
  const int col = nb * 512 + wv * 64 + p * 16 + (lane & 15);
  const int k0 = kt * 32 + (lane >> 4) * 8;
  ushort8 o;
#pragma unroll
  for (int j = 0; j < 8; ++j)
    o[j] = f2bf(W[(size_t)(k0 + j) * NDEF + col]);
  *reinterpret_cast<ushort8*>(Wd + ((size_t)gg * 64 + lane) * 8) = o;
}

// ---------------------------------------------------------------------------
// K1: deform = embedding @ W_def + b_def, MFMA edition (K=256, kt=8).
// grid (128 n-blocks, 16 m-tiles), block 512. A = 16x256 bf16 tile packed
// from embedding; B streamed from k_cvt_def's fragment-major layout.
// ---------------------------------------------------------------------------
__global__ __launch_bounds__(512) void k_deform(
    const float* __restrict__ emb, const unsigned short* __restrict__ Wd,
    const float* __restrict__ bd, float* __restrict__ deform) {
  __shared__ __align__(16) unsigned short A_lds[16 * LAT];  // 8KB
  const int tid = threadIdx.x;
  const int wave = tid >> 6, lane = tid & 63;
  const int nb = blockIdx.x;
  const int m0 = blockIdx.y * 16;
  // pack A (coalesced reads; swizzled bf16 writes)
  {
    char* ab = (char*)A_lds;
#pragma unroll
    for (int rep = 0; rep < 8; ++rep) {
      const int idx = rep * 512 + tid;
      const int row = idx >> 8;
      const int k = idx & 255;
      *(unsigned short*)(ab + row * 512 + ((k * 2) ^ ((row & 7) << 4))) =
          f2bf(emb[(size_t)(m0 + row) * LAT + k]);
    }
  }
  __syncthreads();
  const int arow = lane & 15;
  const int kgrp = lane >> 4;
  const int r0 = kgrp * 4;
  const int abase = arow * 512;  // row stride 256 bf16 = 512B
  const int axor = (arow & 7) << 4;
  const int akoff = kgrp * 16;
  float bdv[4];
#pragma unroll
  for (int p = 0; p < 4; ++p)
    bdv[p] = bd[nb * 512 + wave * 64 + p * 16 + (lane & 15)];
  const unsigned short* wfrag =
      Wd + (size_t)(nb * 8 + wave) * 16384 + lane * 8;
  f32x4 acc[4];
#pragma unroll
  for (int p = 0; p < 4; ++p) acc[p] = (f32x4){0.f, 0.f, 0.f, 0.f};
#pragma unroll
  for (int kt = 0; kt < 8; ++kt) {
    const short8v a = *(const short8v*)((const char*)A_lds + abase +
                                        (((kt * 64) + akoff) ^ axor));
#pragma unroll
    for (int p = 0; p < 4; ++p) {
      const short8v b = *(const short8v*)(wfrag + (kt * 4 + p) * 512);
      acc[p] = __builtin_amdgcn_mfma_f32_16x16x32_bf16(a, b, acc[p], 0, 0, 0);
    }
  }
#pragma unroll
  for (int q = 0; q < 4; ++q) {
    const int row = r0 + q;
#pragma unroll
    for (int p = 0; p < 4; ++p) {
      const int col = nb * 512 + wave * 64 + p * 16 + (lane & 15);
      deform[(size_t)(m0 + row) * NDEF + col] = acc[p][q] + bdv[p];
    }
  }
}

// ---------------------------------------------------------------------------
// K2: per-(be,t) rows of deform: unit_norm, MFMA dual GEMM, leak.
// Staging now COALESCED: consecutive lanes read consecutive t (4 segments
// per wave vs 64 before); xs padded to [16][513] to keep the scalar-read
// phases bank-conflict-free.
// ---------------------------------------------------------------------------
__global__ __launch_bounds__(512) void k_wb(
    const float* __restrict__ deform, const unsigned short* __restrict__ Wmf2,
    const float* __restrict__ bw, const float* __restrict__ bb,
    const float* __restrict__ Wl, const float* __restrict__ bl,
    float* __restrict__ weights, float* __restrict__ biases,
    float* __restrict__ leak) {
  __shared__ float xs[16][NC + 1];                         // ~33KB
  __shared__ __align__(16) unsigned short A_lds[16 * NC];  // 16KB
  __shared__ float rno[16], lks[16];
  const int tid = threadIdx.x;
  const int wave = tid >> 6, lane = tid & 63;
  const int be = blockIdx.x >> 3;
  const int t0 = (blockIdx.x & 7) * 16;
  const float* dbase = deform + (size_t)be * NDEF;
#pragma unroll
  for (int rep = 0; rep < 16; ++rep) {
    const int idx = rep * 512 + tid;
    const int c = idx >> 4;
    const int f = idx & 15;
    xs[f][c] = dbase[(size_t)c * NT + t0 + f];
  }
  __syncthreads();
  for (int f = wave; f < 16; f += 8) {
    float s = 0.f;
#pragma unroll
    for (int j = 0; j < 8; ++j) {
      const float v = xs[f][lane + 64 * j];
      s = fmaf(v, v, s);
    }
#pragma unroll
    for (int off = 32; off; off >>= 1) s += __shfl_down(s, off);
    if (lane == 0) rno[f] = sqrtf(s);
  }
  __syncthreads();
  {
    char* ab = (char*)A_lds;
#pragma unroll
    for (int i = 0; i < 16; ++i) {
      const float xv = xs[i][tid] / (rno[i] + EPSN);
      xs[i][tid] = xv;
      *(unsigned short*)(ab + i * 1024 + ((tid * 2) ^ ((i & 7) << 4))) =
          f2bf(xv);
    }
  }
  __syncthreads();
  for (int f = wave; f < 16; f += 8) {
    float s = 0.f;
#pragma unroll
    for (int j = 0; j < 8; ++j)
      s = fmaf(xs[f][lane + 64 * j], Wl[lane + 64 * j], s);
#pragma unroll
    for (int off = 32; off; off >>= 1) s += __shfl_down(s, off);
    if (lane == 0) lks[f] = s;
  }
  __syncthreads();
  if (tid < 16) {
    const float v = lks[tid] + bl[0];
    leak[(size_t)be * NT + t0 + tid] = 0.1f + 0.98f / (1.f + expf(-v));
  }
  const int arow = lane & 15;
  const int kgrp = lane >> 4;
  const int r0 = kgrp * 4;
  const int abase = arow * (NC * 2);
  const int axor = (arow & 7) << 4;
  const int akoff = kgrp * 16;
  float bwv[4], bbv[4];
#pragma unroll
  for (int p = 0; p < 4; ++p) {
    const int cp = wave * 64 + p * 16 + (lane & 15);
    bwv[p] = bw[cp];
    bbv[p] = bb[cp];
  }
  const unsigned short* wfrag = Wmf2 + (size_t)wave * 32768 + lane * 8;
  f32x4 accw[4], accb[4];
#pragma unroll
  for (int p = 0; p < 4; ++p) {
    accw[p] = (f32x4){0.f, 0.f, 0.f, 0.f};
    accb[p] = (f32x4){0.f, 0.f, 0.f, 0.f};
  }
#pragma unroll
  for (int kt = 0; kt < 16; ++kt) {
    const short8v a = *(const short8v*)((const char*)A_lds + abase +
                                        (((kt * 64) + akoff) ^ axor));
#pragma unroll
    for (int p = 0; p < 4; ++p) {
      const short8v b0 = *(const short8v*)(wfrag + (kt * 4 + p) * 512);
      accw[p] = __builtin_amdgcn_mfma_f32_16x16x32_bf16(a, b0, accw[p], 0, 0, 0);
      const short8v b1 =
          *(const short8v*)(wfrag + (size_t)262144 + (kt * 4 + p) * 512);
      accb[p] = __builtin_amdgcn_mfma_f32_16x16x32_bf16(a, b1, accb[p], 0, 0, 0);
    }
  }
#pragma unroll
  for (int q = 0; q < 4; ++q) {
    const int row = r0 + q;
#pragma unroll
    for (int p = 0; p < 4; ++p) {
      const int cp = wave * 64 + p * 16 + (lane & 15);
      const size_t o = ((size_t)be * NT + t0 + row) * NC + cp;
      weights[o] = accw[p][q] + bwv[p];
      biases[o] = accb[p][q] + bbv[p];
    }
  }
}

// ---------------------------------------------------------------------------
// 16-row tile x (512x512) GEMM helper (f32, used by k_imp).
// ---------------------------------------------------------------------------
__device__ __forceinline__ void tile_gemm16(const float (*xs)[NC],
                                            const float* __restrict__ W,
                                            int tid, float acc[16]) {
#pragma unroll
  for (int i = 0; i < 16; ++i) acc[i] = 0.f;
  for (int k = 0; k < NC; k += 4) {
    const float w0 = W[(size_t)(k + 0) * NC + tid];
    const float w1 = W[(size_t)(k + 1) * NC + tid];
    const float w2 = W[(size_t)(k + 2) * NC + tid];
    const float w3 = W[(size_t)(k + 3) * NC + tid];
#pragma unroll
    for (int i = 0; i < 16; ++i) {
      const float4 a = *reinterpret_cast<const float4*>(&xs[i][k]);
      acc[i] = fmaf(a.x, w0, acc[i]);
      acc[i] = fmaf(a.y, w1, acc[i]);
      acc[i] = fmaf(a.z, w2, acc[i]);
      acc[i] = fmaf(a.w, w3, acc[i]);
    }
  }
}

// LN (+leaky) stats applied in-place on xs[16][NC] (k_imp only)
__device__ __forceinline__ void ln_leaky16(float (*xs)[NC],
                                           const float* __restrict__ g,
                                           const float* __restrict__ bt,
                                           int layer, int tid, float* mu_s,
                                           float* rs_s) {
  const int wave = tid >> 6, lane = tid & 63;
  for (int f = wave; f < 16; f += 8) {
    float s = 0.f, s2 = 0.f;
#pragma unroll
    for (int j = 0; j < 8; ++j) {
      const float v = xs[f][lane + 64 * j];
      s += v;
      s2 = fmaf(v, v, s2);
    }
#pragma unroll
    for (int off = 32; off; off >>= 1) {
      s += __shfl_down(s, off);
      s2 += __shfl_down(s2, off);
    }
    if (lane == 0) {
      const float mu = s * (1.f / NC);
      mu_s[f] = mu;
      rs_s[f] = rsqrtf(s2 * (1.f / NC) - mu * mu + 1e-5f);
    }
  }
  __syncthreads();
  const float gv = g[layer * NC + tid], btv = bt[layer * NC + tid];
#pragma unroll
  for (int i = 0; i < 16; ++i) {
    const float y = (xs[i][tid] - mu_s[i]) * rs_s[i] * gv + btv;
    xs[i][tid] = y > 0.f ? y : 0.2f * y;
  }
  __syncthreads();
}

// ---------------------------------------------------------------------------
// K3: windowed impulse -> mlp_imp -> unit_norm * window-norm -> emb stream.
// ---------------------------------------------------------------------------
__global__ __launch_bounds__(512) void k_imp(
    const float* __restrict__ impulse, const float* __restrict__ Ws,
    const float* __restrict__ bs, const float* __restrict__ g,
    const float* __restrict__ bt, float* __restrict__ embo) {
  __shared__ float xs[16][NC];
  __shared__ float wno[16], mu_s[16], rs_s[16], ono[16];
  const int tid = threadIdx.x;
  const int wave = tid >> 6, lane = tid & 63;
  const int be = blockIdx.x;
  const float* ib = impulse + (size_t)be * NIMP;
  for (int f = 0; f < 16; ++f) {
    const int s = f * 256 + tid;
    xs[f][tid] = (s < NIMP) ? ib[s] : 0.f;
  }
  __syncthreads();
  for (int f = wave; f < 16; f += 8) {
    float s = 0.f;
#pragma unroll
    for (int j = 0; j < 8; ++j) {
      const float v = xs[f][lane + 64 * j];
      s = fmaf(v, v, s);
    }
#pragma unroll
    for (int off = 32; off; off >>= 1) s += __shfl_down(s, off);
    if (lane == 0) wno[f] = sqrtf(s);
  }
  __syncthreads();
  float acc[16];
  for (int layer = 0; layer < 4; ++layer) {
    tile_gemm16(xs, Ws + (size_t)layer * NC * NC, tid, acc);
    __syncthreads();
    const float bv = bs[layer * NC + tid];
#pragma unroll
    for (int i = 0; i < 16; ++i) xs[i][tid] = acc[i] + bv;
    __syncthreads();
    if (layer < 3) ln_leaky16(xs, g, bt, layer, tid, mu_s, rs_s);
  }
  for (int f = wave; f < 16; f += 8) {
    float s = 0.f;
#pragma unroll
    for (int j = 0; j < 8; ++j) {
      const float v = xs[f][lane + 64 * j];
      s = fmaf(v, v, s);
    }
#pragma unroll
    for (int off = 32; off; off >>= 1) s += __shfl_down(s, off);
    if (lane == 0) ono[f] = sqrtf(s);
  }
  __syncthreads();
  for (int f = 0; f < 16; ++f)
    embo[((size_t)be * NF + f) * NC + tid] =
        xs[f][tid] / (ono[f] + EPSN) * wno[f];
}

// ---------------------------------------------------------------------------
// K4: the sequential scan, MFMA v9 (UNCHANGED from R13 — known good).
// ---------------------------------------------------------------------------
__global__ __launch_bounds__(512) void k_scan(
    const float* __restrict__ weights, const float* __restrict__ biases,
    const float* __restrict__ leak, const float* __restrict__ embw,
    const unsigned short* __restrict__ Wmf, const float* __restrict__ bs,
    const float* __restrict__ g, const float* __restrict__ bt,
    float* __restrict__ olb, float* __restrict__ onb) {
  __shared__ __align__(16) unsigned short A_lds[16 * NC];     // 16KB
  __shared__ __align__(16) unsigned short B_lds[8][4][2048];  // 128KB
  __shared__ float ol_lds[SPB][NC];                           // 8KB
  __shared__ float redA[64];
  __shared__ float redB[32];
  __shared__ float st1[8][SPB], st2[8][SPB];
  __shared__ float lk_lds[SPB][NT];

  const int tid = threadIdx.x;
  const int wave = tid >> 6, lane = tid & 63;
  const int seq0 = blockIdx.x * SPB;

  {
    const int r = tid >> 7, tt = tid & 127;
    lk_lds[r][tt] = leak[(size_t)(seq0 + r) * NT + tt];
  }
  {
    unsigned* z = (unsigned*)(A_lds + SPB * NC);
    for (int i = tid; i < (16 - SPB) * NC / 2; i += 512) z[i] = 0u;
  }

  const int arow = lane & 15;
  const int kgrp = lane >> 4;
  const int abase = arow * (NC * 2);
  const int axor = (arow & 7) << 4;
  const int akoff = kgrp * 16;
  const bool crow = (kgrp == 0);

  float bsv[4][4], gv[3][4], btv[3][4];
#pragma unroll
  for (int p = 0; p < 4; ++p) {
    const int cp = wave * 64 + p * 16 + (lane & 15);
#pragma unroll
    for (int l = 0; l < 4; ++l) bsv[l][p] = bs[l * NC + cp];
#pragma unroll
    for (int l = 0; l < 3; ++l) {
      gv[l][p] = g[l * NC + cp];
      btv[l][p] = bt[l * NC + cp];
    }
  }
  const unsigned short* wfrag = Wmf + (size_t)wave * 32768 + lane * 8;

  auto issue_chunk = [&](int cc) {
    const int layer = cc >> 4, kt = cc & 15, slot = cc & 3;
#pragma unroll
    for (int p = 0; p < 4; ++p) {
      __builtin_amdgcn_global_load_lds(
          (const unsigned int*)(wfrag + (size_t)layer * 262144 +
                                (kt * 4 + p) * 512),
          (unsigned int*)&B_lds[wave][slot][p * 512], 16, 0, 0);
    }
  };

  float wpre[SPB], bpre[SPB], epre[SPB];
#pragma unroll
  for (int r = 0; r < SPB; ++r) {
    const size_t o = ((size_t)(seq0 + r) * NT) * NC + tid;
    wpre[r] = weights[o];
    bpre[r] = biases[o];
    epre[r] = embw[((size_t)(seq0 + r) * NF) * NC + tid];
  }

  __syncthreads();

  issue_chunk(0);
  issue_chunk(1);
  issue_chunk(2);

  float h[SPB], cn[SPB];
#pragma unroll
  for (int r = 0; r < SPB; ++r) { h[r] = 0.f; cn[r] = 0.f; }

#pragma unroll 1
  for (int t = 0; t < NT; ++t) {
    float hw[SPB];
    if (t < NF) {
#pragma unroll
      for (int r = 0; r < SPB; ++r) h[r] += epre[r];
      float v8[8], s8[8];
#pragma unroll
      for (int r = 0; r < SPB; ++r) {
        hw[r] = fmaf(h[r], wpre[r], bpre[r]);
        v8[r] = h[r] * h[r];
        v8[SPB + r] = hw[r] * hw[r];
      }
      if (t + 1 < NF) {
#pragma unroll
        for (int r = 0; r < SPB; ++r)
          epre[r] = embw[((size_t)(seq0 + r) * NF + t + 1) * NC + tid];
      }
      if (t + 1 < NT) {
#pragma unroll
        for (int r = 0; r < SPB; ++r) {
          const size_t o = ((size_t)(seq0 + r) * NT + t + 1) * NC + tid;
          wpre[r] = weights[o];
          bpre[r] = biases[o];
        }
      }
      blk_reduce1<8>(v8, s8, redA);
#pragma unroll
      for (int r = 0; r < SPB; ++r) {
        cn[r] = sqrtf(s8[r]);
        h[r] = hw[r] * (cn[r] / (sqrtf(s8[SPB + r]) + EPSN));
      }
    } else {
      float v4[SPB], s4[SPB];
#pragma unroll
      for (int r = 0; r < SPB; ++r) {
        hw[r] = fmaf(h[r], wpre[r], bpre[r]);
        v4[r] = hw[r] * hw[r];
      }
      if (t + 1 < NT) {
#pragma unroll
        for (int r = 0; r < SPB; ++r) {
          const size_t o = ((size_t)(seq0 + r) * NT + t + 1) * NC + tid;
          wpre[r] = weights[o];
          bpre[r] = biases[o];
        }
      }
      blk_reduce1<SPB>(v4, s4, redA);
#pragma unroll
      for (int r = 0; r < SPB; ++r)
        h[r] = hw[r] * (cn[r] / (sqrtf(s4[r]) + EPSN));
    }
    {
      char* ab = (char*)A_lds;
#pragma unroll
      for (int r = 0; r < SPB; ++r)
        *(unsigned short*)(ab + r * 1024 + ((tid * 2) ^ ((r & 7) << 4))) =
            f2bf(h[r]);
    }
    bar_nodrain();

#pragma unroll 1
    for (int layer = 0; layer < 4; ++layer) {
      f32x4 acc[4];
#pragma unroll
      for (int p = 0; p < 4; ++p) acc[p] = (f32x4){0.f, 0.f, 0.f, 0.f};
#pragma unroll
      for (int kt = 0; kt < 16; ++kt) {
        asm volatile("s_waitcnt vmcnt(8)" ::: "memory");
        const short8v a = *(const short8v*)((const char*)A_lds + abase +
                                            (((kt * 64) + akoff) ^ axor));
        const int slot = kt & 3;
#pragma unroll
        for (int p = 0; p < 4; ++p) {
          const short8v b =
              *(const short8v*)((const char*)&B_lds[wave][slot][0] + p * 1024 +
                                lane * 16);
          acc[p] =
              __builtin_amdgcn_mfma_f32_16x16x32_bf16(a, b, acc[p], 0, 0, 0);
        }
        issue_chunk((layer * 16 + kt + 3) & 63);
      }

      if (layer < 3) {
        float s1[SPB], s2[SPB];
#pragma unroll
        for (int q = 0; q < SPB; ++q) { s1[q] = 0.f; s2[q] = 0.f; }
#pragma unroll
        for (int p = 0; p < 4; ++p) {
#pragma unroll
          for (int q = 0; q < SPB; ++q) {
            const float y = acc[p][q] + bsv[layer][p];
            acc[p][q] = y;
            s1[q] += y;
            s2[q] = fmaf(y, y, s2[q]);
          }
        }
#pragma unroll
        for (int off = 1; off < 16; off <<= 1) {
#pragma unroll
          for (int q = 0; q < SPB; ++q) {
            s1[q] += __shfl_xor(s1[q], off);
            s2[q] += __shfl_xor(s2[q], off);
          }
        }
        if (lane == 0) {
#pragma unroll
          for (int q = 0; q < SPB; ++q) {
            st1[wave][q] = s1[q];
            st2[wave][q] = s2[q];
          }
        }
        bar_nodrain();
        float mu[SPB], rs[SPB];
#pragma unroll
        for (int q = 0; q < SPB; ++q) {
          float a1 = 0.f, a2 = 0.f;
#pragma unroll
          for (int w = 0; w < 8; ++w) {
            a1 += st1[w][q];
            a2 += st2[w][q];
          }
          mu[q] = a1 * (1.f / NC);
          rs[q] = rsqrtf(a2 * (1.f / NC) - mu[q] * mu[q] + 1e-5f);
        }
        if (crow) {
          char* ab = (char*)A_lds;
#pragma unroll
          for (int q = 0; q < SPB; ++q) {
#pragma unroll
            for (int p = 0; p < 4; ++p) {
              float y = (acc[p][q] - mu[q]) * rs[q] * gv[layer][p] +
                        btv[layer][p];
              y = y > 0.f ? y : 0.2f * y;
              const int cp = wave * 64 + p * 16 + (lane & 15);
              *(unsigned short*)(ab + q * 1024 +
                                 ((cp * 2) ^ ((q & 7) << 4))) = f2bf(y);
            }
          }
        }
        bar_nodrain();
      } else {
        float s2[SPB];
#pragma unroll
        for (int q = 0; q < SPB; ++q) s2[q] = 0.f;
#pragma unroll
        for (int p = 0; p < 4; ++p) {
#pragma unroll
          for (int q = 0; q < SPB; ++q) {
            const float y = acc[p][q] + bsv[3][p];
            acc[p][q] = y;
            s2[q] = fmaf(y, y, s2[q]);
          }
        }
#pragma unroll
        for (int off = 1; off < 16; off <<= 1) {
#pragma unroll
          for (int q = 0; q < SPB; ++q) s2[q] += __shfl_xor(s2[q], off);
        }
        if (lane == 0) {
#pragma unroll
          for (int q = 0; q < SPB; ++q) st2[wave][q] = s2[q];
        }
        if (crow) {
#pragma unroll
          for (int q = 0; q < SPB; ++q) {
#pragma unroll
            for (int p = 0; p < 4; ++p)
              ol_lds[q][wave * 64 + p * 16 + (lane & 15)] = acc[p][q];
          }
        }
        bar_nodrain();
        float sc[SPB], on[SPB];
#pragma unroll
        for (int r = 0; r < SPB; ++r) {
          float a2 = 0.f;
#pragma unroll
          for (int w = 0; w < 8; ++w) a2 += st2[w][r];
          const float no = sqrtf(a2);
          sc[r] = cn[r] * lk_lds[r][t] / (no + EPSN);
          on[r] = no * sc[r];
        }
        if (tid < SPB) onb[(size_t)(seq0 + tid) * NT + t] = on[tid];
        float v4[SPB], s4[SPB];
#pragma unroll
        for (int r = 0; r < SPB; ++r) {
          const float olv = ol_lds[r][tid] * sc[r];
          olb[((size_t)(seq0 + r) * NT + t) * NC + tid] = olv;
          h[r] -= olv;
          v4[r] = h[r] * h[r];
        }
        blk_reduce1<SPB>(v4, s4, redB);
#pragma unroll
        for (int r = 0; r < SPB; ++r) {
          h[r] *= (cn[r] - on[r]) / (sqrtf(s4[r]) + EPSN);
          cn[r] = fabsf(cn[r] - on[r]);  // ||h|| carried exactly
        }
      }
    }
  }
}

// ---------------------------------------------------------------------------
// K_zero: zero-init the output buffer.
// ---------------------------------------------------------------------------
__global__ __launch_bounds__(1024) void k_zero(float* __restrict__ out) {
  out[(size_t)blockIdx.x * 1024 + threadIdx.x] = 0.f;
}

// ---------------------------------------------------------------------------
// K5: batched out-MLP, MFMA + fused overlap-add (UNCHANGED from R13).
// ---------------------------------------------------------------------------
__global__ __launch_bounds__(512) void k_out(
    const float* __restrict__ olb, const float* __restrict__ onb,
    const unsigned short* __restrict__ Wmf, const float* __restrict__ bs,
    const float* __restrict__ g, const float* __restrict__ bt,
    float* __restrict__ out) {
  __shared__ __align__(16) unsigned short A_lds[16 * NC];  // 16KB
  __shared__ float st1[8][16], st2[8][16];
  __shared__ float on_l[16];
  const int tid = threadIdx.x;
  const int wave = tid >> 6, lane = tid & 63;
  const int m0 = blockIdx.x * 16;
  const int arow = lane & 15;
  const int kgrp = lane >> 4;
  const int r0 = kgrp * 4;
  const int abase = arow * (NC * 2);
  const int axor = (arow & 7) << 4;
  const int akoff = kgrp * 16;

  float bsv[4][4], gv[3][4], btv[3][4], hamv[4];
#pragma unroll
  for (int p = 0; p < 4; ++p) {
    const int cp = wave * 64 + p * 16 + (lane & 15);
#pragma unroll
    for (int l = 0; l < 4; ++l) bsv[l][p] = bs[l * NC + cp];
#pragma unroll
    for (int l = 0; l < 3; ++l) {
      gv[l][p] = g[l * NC + cp];
      btv[l][p] = bt[l * NC + cp];
    }
    hamv[p] =
        0.54f - 0.46f * cosf(6.283185307179586f * (float)cp / (float)NC);
  }
  if (tid < 16) on_l[tid] = onb[m0 + tid];
  {
    char* ab = (char*)A_lds;
    for (int i = 0; i < 16; ++i) {
      const float v = olb[(size_t)(m0 + i) * NC + tid];
      *(unsigned short*)(ab + i * 1024 + ((tid * 2) ^ ((i & 7) << 4))) =
          f2bf(v);
    }
  }
  __syncthreads();

  const unsigned short* wfrag = Wmf + (size_t)wave * 32768 + lane * 8;

#pragma unroll 1
  for (int layer = 0; layer < 4; ++layer) {
    f32x4 acc[4];
#pragma unroll
    for (int p = 0; p < 4; ++p) acc[p] = (f32x4){0.f, 0.f, 0.f, 0.f};
#pragma unroll
    for (int kt = 0; kt < 16; ++kt) {
      const short8v a = *(const short8v*)((const char*)A_lds + abase +
                                          (((kt * 64) + akoff) ^ axor));
#pragma unroll
      for (int p = 0; p < 4; ++p) {
        const short8v b = *(const short8v*)(wfrag + (size_t)layer * 262144 +
                                            (kt * 4 + p) * 512);
        acc[p] = __builtin_amdgcn_mfma_f32_16x16x32_bf16(a, b, acc[p], 0, 0, 0);
      }
    }
    if (layer < 3) {
      float s1[4], s2[4];
#pragma unroll
      for (int q = 0; q < 4; ++q) { s1[q] = 0.f; s2[q] = 0.f; }
#pragma unroll
      for (int p = 0; p < 4; ++p) {
#pragma unroll
        for (int q = 0; q < 4; ++q) {
          const float y = acc[p][q] + bsv[layer][p];
          acc[p][q] = y;
          s1[q] += y;
          s2[q] = fmaf(y, y, s2[q]);
        }
      }
#pragma unroll
      for (int off = 1; off < 16; off <<= 1) {
#pragma unroll
        for (int q = 0; q < 4; ++q) {
          s1[q] += __shfl_xor(s1[q], off);
          s2[q] += __shfl_xor(s2[q], off);
        }
      }
      if ((lane & 15) == 0) {
#pragma unroll
        for (int q = 0; q < 4; ++q) {
          st1[wave][r0 + q] = s1[q];
          st2[wave][r0 + q] = s2[q];
        }
      }
      __syncthreads();
      char* ab = (char*)A_lds;
#pragma unroll
      for (int q = 0; q < 4; ++q) {
        const int row = r0 + q;
        float a1 = 0.f, a2 = 0.f;
#pragma unroll
        for (int w = 0; w < 8; ++w) {
          a1 += st1[w][row];
          a2 += st2[w][row];
        }
        const float mu = a1 * (1.f / NC);
        const float rs = rsqrtf(a2 * (1.f / NC) - mu * mu + 1e-5f);
#pragma unroll
        for (int p = 0; p < 4; ++p) {
          float y = (acc[p][q] - mu) * rs * gv[layer][p] + btv[layer][p];
          y = y > 0.f ? y : 0.2f * y;
          const int cp = wave * 64 + p * 16 + (lane & 15);
          *(unsigned short*)(ab + row * 1024 +
                             ((cp * 2) ^ ((row & 7) << 4))) = f2bf(y);
        }
      }
      __syncthreads();
    } else {
      float s2[4];
#pragma unroll
      for (int q = 0; q < 4; ++q) s2[q] = 0.f;
#pragma unroll
      for (int p = 0; p < 4; ++p) {
#pragma unroll
        for (int q = 0; q < 4; ++q) {
          float y = (acc[p][q] + bsv[3][p]) * hamv[p];
          acc[p][q] = y;
          s2[q] = fmaf(y, y, s2[q]);
        }
      }
#pragma unroll
      for (int off = 1; off < 16; off <<= 1) {
#pragma unroll
        for (int q = 0; q < 4; ++q) s2[q] += __shfl_xor(s2[q], off);
      }
      if ((lane & 15) == 0) {
#pragma unroll
        for (int q = 0; q < 4; ++q) st2[wave][r0 + q] = s2[q];
      }
      __syncthreads();
#pragma unroll
      for (int q = 0; q < 4; ++q) {
        const int row = r0 + q;
        const int gr = m0 + row;
        const int be = gr >> 7;
        const int tt = gr & 127;
        float a2 = 0.f;
#pragma unroll
        for (int w = 0; w < 8; ++w) a2 += st2[w][row];
        const float inv = on_l[row] / (sqrtf(a2) + EPSN);
#pragma unroll
        for (int p = 0; p < 4; ++p) {
          const int cp = wave * 64 + p * 16 + (lane & 15);
          const int s = tt * 256 + cp;
          if (s < NSAMP)
            atomicAdd(&out[(size_t)be * NSAMP + s], acc[p][q] * inv);
        }
      }
    }
  }
}

// ---------------------------------------------------------------------------
// Workspace (< 256 MiB): region A (deform->olb) 64 MiB, region B
// (wmf_def -> weights) 64 MiB, region C (biases) 64 MiB, small ~15 MiB.
// wmf_def aliases region B: consumed by k_deform, which completes (stream
// order) before k_wb writes weights there.
// ---------------------------------------------------------------------------
extern "C" void kernel_launch(void* const* d_in, const int* in_sizes, int n_in,
                              void* d_out, int out_size, void* d_ws,
                              size_t ws_size, hipStream_t stream) {
  const float* embedding = (const float*)d_in[0];
  const float* impulse = (const float*)d_in[1];
  const float* W_def = (const float*)d_in[2];
  const float* b_def = (const float*)d_in[3];
  const float* W_w = (const float*)d_in[4];
  const float* b_w = (const float*)d_in[5];
  const float* W_b = (const float*)d_in[6];
  const float* b_b = (const float*)d_in[7];
  const float* W_l = (const float*)d_in[8];
  const float* b_l = (const float*)d_in[9];
  const float* Ws_imp = (const float*)d_in[10];
  const float* bs_imp = (const float*)d_in[11];
  const float* g_imp = (const float*)d_in[12];
  const float* bt_imp = (const float*)d_in[13];
  const float* Ws_lat = (const float*)d_in[14];
  const float* bs_lat = (const float*)d_in[15];
  const float* g_lat = (const float*)d_in[16];
  const float* bt_lat = (const float*)d_in[17];
  const float* Ws_out = (const float*)d_in[18];
  const float* bs_out = (const float*)d_in[19];
  const float* g_out = (const float*)d_in[20];
  const float* bt_out = (const float*)d_in[21];
  float* out = (float*)d_out;

  float* ws = (float*)d_ws;
  float* deform = ws;                  // region A (reused as olb)
  float* weights = deform + 16777216;  // region B (first used as wmf_def)
  float* biases = weights + 16777216;  // region C
  float* leakb = biases + 16777216;    // 32,768 f
  float* embw = leakb + 32768;         // 2,097,152 f
  float* onb = embw + 2097152;         // 32,768 f
  unsigned short* wmf = (unsigned short*)(onb + 32768);    // 1,048,576 us
  unsigned short* wmf_out = wmf + 1048576;                 // 1,048,576 us
  unsigned short* wmf_wb = wmf_out + 1048576;              // 524,288 us
  unsigned short* wmf_def = (unsigned short*)weights;      // alias region B
  float* olb = deform;                 // alias: deform dead after k_wb

  k_cvt<<<2048, 64, 0, stream>>>(Ws_lat, wmf);
  k_cvt<<<2048, 64, 0, stream>>>(Ws_out, wmf_out);
  k_cvt<<<512, 64, 0, stream>>>(W_w, wmf_wb);
  k_cvt<<<512, 64, 0, stream>>>(W_b, wmf_wb + 262144);
  k_cvt_def<<<32768, 64, 0, stream>>>(W_def, wmf_def);
  k_deform<<<dim3(128, 16), 512, 0, stream>>>(embedding, wmf_def, b_def,
                                              deform);
  k_wb<<<2048, 512, 0, stream>>>(deform, wmf_wb, b_w, b_b, W_l, b_l,
                                 weights, biases, leakb);
  k_imp<<<256, 512, 0, stream>>>(impulse, Ws_imp, bs_imp, g_imp, bt_imp, embw);
  k_zero<<<(BE * NSAMP) / 1024, 1024, 0, stream>>>(out);
  k_scan<<<NSCAN, 512, 0, stream>>>(weights, biases, leakb, embw, wmf, bs_lat,
                                    g_lat, bt_lat, olb, onb);
  k_out<<<2048, 512, 0, stream>>>(olb, onb, wmf_out, bs_out, g_out, bt_out,
                                  out);
}

// Round 15
// 4013.622 us; speedup vs baseline: 3.3120x; 1.0389x over previous
//
#include <hip/hip_runtime.h>
#include <math.h>

#define NB 4
#define NE 64
#define BE 256          // NB*NE
#define LAT 256
#define NC 512          // channels == window
#define NT 128          // n_frames
#define NDEF 65536      // NC*NT
#define NIMP 4096
#define NF 16           // impulse frames
#define EPSN 1e-8f
#define SPB 4           // sequences per scan block
#define NSCAN 64        // scan blocks (BE/SPB)
#define NSAMP 32768

typedef unsigned short ushort8 __attribute__((ext_vector_type(8)));
typedef short short8v __attribute__((ext_vector_type(8)));
typedef float f32x4 __attribute__((ext_vector_type(4)));

__device__ __forceinline__ unsigned short f2bf(float f) {
  const unsigned u = __float_as_uint(f);
  return (unsigned short)((u + 0x7FFFu + ((u >> 16) & 1u)) >> 16);  // RNE
}

// raw barrier WITHOUT the vmcnt(0) drain __syncthreads emits.
__device__ __forceinline__ void bar_nodrain() {
  asm volatile("s_waitcnt lgkmcnt(0)" ::: "memory");
  __builtin_amdgcn_s_barrier();
  __builtin_amdgcn_sched_barrier(0);
}

// ---------------------------------------------------------------------------
// single-raw-barrier block reduction (used only inside k_scan's t-loop).
// ---------------------------------------------------------------------------
template <int NR>
__device__ __forceinline__ void blk_reduce1(const float* v, float* out,
                                            float* red) {
  const int tid = threadIdx.x, wave = tid >> 6, lane = tid & 63;
  float s[NR];
#pragma unroll
  for (int i = 0; i < NR; ++i) s[i] = v[i];
#pragma unroll
  for (int off = 32; off; off >>= 1) {
#pragma unroll
    for (int i = 0; i < NR; ++i) s[i] += __shfl_down(s[i], off);
  }
  if (lane == 0) {
#pragma unroll
    for (int i = 0; i < NR; ++i) red[wave * NR + i] = s[i];
  }
  bar_nodrain();
#pragma unroll
  for (int i = 0; i < NR; ++i) {
    float a = 0.f;
#pragma unroll
    for (int w = 0; w < 8; ++w) a += red[w * NR + i];
    out[i] = a;
  }
}

// ---------------------------------------------------------------------------
// K0: swizzle an L-layer [512k][512n] f32 weight stack into fragment-major
// MFMA B-frag order, bf16 (validated template). grid = L*512, block 64.
// Used for Ws_lat, Ws_out, Ws_imp (L=4) and W_w / W_b (L=1 each).
// ---------------------------------------------------------------------------
__global__ __launch_bounds__(64) void k_cvt(const float* __restrict__ W,
                                            unsigned short* __restrict__ Wmf) {
  const int lane = threadIdx.x;
  const int gg = blockIdx.x;
  const int p = gg & 3;
  const int kt = (gg >> 2) & 15;
  const int wv = (gg >> 6) & 7;
  const int layer = gg >> 9;
  const int col = wv * 64 + p * 16 + (lane & 15);
  const int k0 = kt * 32 + (lane >> 4) * 8;
  ushort8 o;
#pragma unroll
  for (int j = 0; j < 8; ++j)
    o[j] = f2bf(W[((size_t)layer * NC + k0 + j) * NC + col]);
  *reinterpret_cast<ushort8*>(Wmf + ((size_t)gg * 64 + lane) * 8) = o;
}

// ---------------------------------------------------------------------------
// K0b: swizzle W_def ([256 k][65536 n] f32) into fragment-major bf16.
// ---------------------------------------------------------------------------
__global__ __launch_bounds__(64) void k_cvt_def(
    const float* __restrict__ W, unsigned short* __restrict__ Wd) {
  const int lane = threadIdx.x;
  const int gg = blockIdx.x;
  const int p = gg & 3;
  const int kt = (gg >> 2) & 7;
  const int wv = (gg >> 5) & 7;
  const int nb = gg >> 8;
  const int col = nb * 512 + wv * 64 + p * 16 + (lane & 15);
  const int k0 = kt * 32 + (lane >> 4) * 8;
  ushort8 o;
#pragma unroll
  for (int j = 0; j < 8; ++j)
    o[j] = f2bf(W[(size_t)(k0 + j) * NDEF + col]);
  *reinterpret_cast<ushort8*>(Wd + ((size_t)gg * 64 + lane) * 8) = o;
}

// ---------------------------------------------------------------------------
// K1: deform = embedding @ W_def + b_def, MFMA edition (UNCHANGED from R14).
// ---------------------------------------------------------------------------
__global__ __launch_bounds__(512) void k_deform(
    const float* __restrict__ emb, const unsigned short* __restrict__ Wd,
    const float* __restrict__ bd, float* __restrict__ deform) {
  __shared__ __align__(16) unsigned short A_lds[16 * LAT];  // 8KB
  const int tid = threadIdx.x;
  const int wave = tid >> 6, lane = tid & 63;
  const int nb = blockIdx.x;
  const int m0 = blockIdx.y * 16;
  {
    char* ab = (char*)A_lds;
#pragma unroll
    for (int rep = 0; rep < 8; ++rep) {
      const int idx = rep * 512 + tid;
      const int row = idx >> 8;
      const int k = idx & 255;
      *(unsigned short*)(ab + row * 512 + ((k * 2) ^ ((row & 7) << 4))) =
          f2bf(emb[(size_t)(m0 + row) * LAT + k]);
    }
  }
  __syncthreads();
  const int arow = lane & 15;
  const int kgrp = lane >> 4;
  const int r0 = kgrp * 4;
  const int abase = arow * 512;
  const int axor = (arow & 7) << 4;
  const int akoff = kgrp * 16;
  float bdv[4];
#pragma unroll
  for (int p = 0; p < 4; ++p)
    bdv[p] = bd[nb * 512 + wave * 64 + p * 16 + (lane & 15)];
  const unsigned short* wfrag =
      Wd + (size_t)(nb * 8 + wave) * 16384 + lane * 8;
  f32x4 acc[4];
#pragma unroll
  for (int p = 0; p < 4; ++p) acc[p] = (f32x4){0.f, 0.f, 0.f, 0.f};
#pragma unroll
  for (int kt = 0; kt < 8; ++kt) {
    const short8v a = *(const short8v*)((const char*)A_lds + abase +
                                        (((kt * 64) + akoff) ^ axor));
#pragma unroll
    for (int p = 0; p < 4; ++p) {
      const short8v b = *(const short8v*)(wfrag + (kt * 4 + p) * 512);
      acc[p] = __builtin_amdgcn_mfma_f32_16x16x32_bf16(a, b, acc[p], 0, 0, 0);
    }
  }
#pragma unroll
  for (int q = 0; q < 4; ++q) {
    const int row = r0 + q;
#pragma unroll
    for (int p = 0; p < 4; ++p) {
      const int col = nb * 512 + wave * 64 + p * 16 + (lane & 15);
      deform[(size_t)(m0 + row) * NDEF + col] = acc[p][q] + bdv[p];
    }
  }
}

// ---------------------------------------------------------------------------
// K2: per-(be,t) rows of deform: unit_norm, MFMA dual GEMM, leak
// (UNCHANGED from R14).
// ---------------------------------------------------------------------------
__global__ __launch_bounds__(512) void k_wb(
    const float* __restrict__ deform, const unsigned short* __restrict__ Wmf2,
    const float* __restrict__ bw, const float* __restrict__ bb,
    const float* __restrict__ Wl, const float* __restrict__ bl,
    float* __restrict__ weights, float* __restrict__ biases,
    float* __restrict__ leak) {
  __shared__ float xs[16][NC + 1];                         // ~33KB
  __shared__ __align__(16) unsigned short A_lds[16 * NC];  // 16KB
  __shared__ float rno[16], lks[16];
  const int tid = threadIdx.x;
  const int wave = tid >> 6, lane = tid & 63;
  const int be = blockIdx.x >> 3;
  const int t0 = (blockIdx.x & 7) * 16;
  const float* dbase = deform + (size_t)be * NDEF;
#pragma unroll
  for (int rep = 0; rep < 16; ++rep) {
    const int idx = rep * 512 + tid;
    const int c = idx >> 4;
    const int f = idx & 15;
    xs[f][c] = dbase[(size_t)c * NT + t0 + f];
  }
  __syncthreads();
  for (int f = wave; f < 16; f += 8) {
    float s = 0.f;
#pragma unroll
    for (int j = 0; j < 8; ++j) {
      const float v = xs[f][lane + 64 * j];
      s = fmaf(v, v, s);
    }
#pragma unroll
    for (int off = 32; off; off >>= 1) s += __shfl_down(s, off);
    if (lane == 0) rno[f] = sqrtf(s);
  }
  __syncthreads();
  {
    char* ab = (char*)A_lds;
#pragma unroll
    for (int i = 0; i < 16; ++i) {
      const float xv = xs[i][tid] / (rno[i] + EPSN);
      xs[i][tid] = xv;
      *(unsigned short*)(ab + i * 1024 + ((tid * 2) ^ ((i & 7) << 4))) =
          f2bf(xv);
    }
  }
  __syncthreads();
  for (int f = wave; f < 16; f += 8) {
    float s = 0.f;
#pragma unroll
    for (int j = 0; j < 8; ++j)
      s = fmaf(xs[f][lane + 64 * j], Wl[lane + 64 * j], s);
#pragma unroll
    for (int off = 32; off; off >>= 1) s += __shfl_down(s, off);
    if (lane == 0) lks[f] = s;
  }
  __syncthreads();
  if (tid < 16) {
    const float v = lks[tid] + bl[0];
    leak[(size_t)be * NT + t0 + tid] = 0.1f + 0.98f / (1.f + expf(-v));
  }
  const int arow = lane & 15;
  const int kgrp = lane >> 4;
  const int r0 = kgrp * 4;
  const int abase = arow * (NC * 2);
  const int axor = (arow & 7) << 4;
  const int akoff = kgrp * 16;
  float bwv[4], bbv[4];
#pragma unroll
  for (int p = 0; p < 4; ++p) {
    const int cp = wave * 64 + p * 16 + (lane & 15);
    bwv[p] = bw[cp];
    bbv[p] = bb[cp];
  }
  const unsigned short* wfrag = Wmf2 + (size_t)wave * 32768 + lane * 8;
  f32x4 accw[4], accb[4];
#pragma unroll
  for (int p = 0; p < 4; ++p) {
    accw[p] = (f32x4){0.f, 0.f, 0.f, 0.f};
    accb[p] = (f32x4){0.f, 0.f, 0.f, 0.f};
  }
#pragma unroll
  for (int kt = 0; kt < 16; ++kt) {
    const short8v a = *(const short8v*)((const char*)A_lds + abase +
                                        (((kt * 64) + akoff) ^ axor));
#pragma unroll
    for (int p = 0; p < 4; ++p) {
      const short8v b0 = *(const short8v*)(wfrag + (kt * 4 + p) * 512);
      accw[p] = __builtin_amdgcn_mfma_f32_16x16x32_bf16(a, b0, accw[p], 0, 0, 0);
      const short8v b1 =
          *(const short8v*)(wfrag + (size_t)262144 + (kt * 4 + p) * 512);
      accb[p] = __builtin_amdgcn_mfma_f32_16x16x32_bf16(a, b1, accb[p], 0, 0, 0);
    }
  }
#pragma unroll
  for (int q = 0; q < 4; ++q) {
    const int row = r0 + q;
#pragma unroll
    for (int p = 0; p < 4; ++p) {
      const int cp = wave * 64 + p * 16 + (lane & 15);
      const size_t o = ((size_t)be * NT + t0 + row) * NC + cp;
      weights[o] = accw[p][q] + bwv[p];
      biases[o] = accb[p][q] + bbv[p];
    }
  }
}

// ---------------------------------------------------------------------------
// K3: windowed impulse -> mlp_imp (MFMA) -> unit_norm * window-norm -> embo.
// Same validated template as k_out minus hamming/on: stage windows (f32),
// wno per frame, pack bf16 A, 4 MFMA layers with 16-lane LN stats, epilogue
// unit_norm(y) * wno. grid 256 (one per be), block 512.
// ---------------------------------------------------------------------------
__global__ __launch_bounds__(512) void k_imp(
    const float* __restrict__ impulse, const unsigned short* __restrict__ Wmf,
    const float* __restrict__ bs, const float* __restrict__ g,
    const float* __restrict__ bt, float* __restrict__ embo) {
  __shared__ float xs[16][NC];                             // 32KB (staging)
  __shared__ __align__(16) unsigned short A_lds[16 * NC];  // 16KB
  __shared__ float st1[8][16], st2[8][16];
  __shared__ float wno[16];
  const int tid = threadIdx.x;
  const int wave = tid >> 6, lane = tid & 63;
  const int be = blockIdx.x;
  const int arow = lane & 15;
  const int kgrp = lane >> 4;
  const int r0 = kgrp * 4;
  const int abase = arow * (NC * 2);
  const int axor = (arow & 7) << 4;
  const int akoff = kgrp * 16;

  float bsv[4][4], gv[3][4], btv[3][4];
#pragma unroll
  for (int p = 0; p < 4; ++p) {
    const int cp = wave * 64 + p * 16 + (lane & 15);
#pragma unroll
    for (int l = 0; l < 4; ++l) bsv[l][p] = bs[l * NC + cp];
#pragma unroll
    for (int l = 0; l < 3; ++l) {
      gv[l][p] = g[l * NC + cp];
      btv[l][p] = bt[l * NC + cp];
    }
  }
  const float* ib = impulse + (size_t)be * NIMP;
  for (int f = 0; f < 16; ++f) {
    const int s = f * 256 + tid;
    xs[f][tid] = (s < NIMP) ? ib[s] : 0.f;
  }
  __syncthreads();
  // window norms (f32, unchanged numerics)
  for (int f = wave; f < 16; f += 8) {
    float s = 0.f;
#pragma unroll
    for (int j = 0; j < 8; ++j) {
      const float v = xs[f][lane + 64 * j];
      s = fmaf(v, v, s);
    }
#pragma unroll
    for (int off = 32; off; off >>= 1) s += __shfl_down(s, off);
    if (lane == 0) wno[f] = sqrtf(s);
  }
  __syncthreads();
  // pack A (bf16, swizzled)
  {
    char* ab = (char*)A_lds;
#pragma unroll
    for (int i = 0; i < 16; ++i)
      *(unsigned short*)(ab + i * 1024 + ((tid * 2) ^ ((i & 7) << 4))) =
          f2bf(xs[i][tid]);
  }
  __syncthreads();

  const unsigned short* wfrag = Wmf + (size_t)wave * 32768 + lane * 8;

#pragma unroll 1
  for (int layer = 0; layer < 4; ++layer) {
    f32x4 acc[4];
#pragma unroll
    for (int p = 0; p < 4; ++p) acc[p] = (f32x4){0.f, 0.f, 0.f, 0.f};
#pragma unroll
    for (int kt = 0; kt < 16; ++kt) {
      const short8v a = *(const short8v*)((const char*)A_lds + abase +
                                          (((kt * 64) + akoff) ^ axor));
#pragma unroll
      for (int p = 0; p < 4; ++p) {
        const short8v b = *(const short8v*)(wfrag + (size_t)layer * 262144 +
                                            (kt * 4 + p) * 512);
        acc[p] = __builtin_amdgcn_mfma_f32_16x16x32_bf16(a, b, acc[p], 0, 0, 0);
      }
    }
    if (layer < 3) {
      float s1[4], s2[4];
#pragma unroll
      for (int q = 0; q < 4; ++q) { s1[q] = 0.f; s2[q] = 0.f; }
#pragma unroll
      for (int p = 0; p < 4; ++p) {
#pragma unroll
        for (int q = 0; q < 4; ++q) {
          const float y = acc[p][q] + bsv[layer][p];
          acc[p][q] = y;
          s1[q] += y;
          s2[q] = fmaf(y, y, s2[q]);
        }
      }
#pragma unroll
      for (int off = 1; off < 16; off <<= 1) {
#pragma unroll
        for (int q = 0; q < 4; ++q) {
          s1[q] += __shfl_xor(s1[q], off);
          s2[q] += __shfl_xor(s2[q], off);
        }
      }
      if ((lane & 15) == 0) {
#pragma unroll
        for (int q = 0; q < 4; ++q) {
          st1[wave][r0 + q] = s1[q];
          st2[wave][r0 + q] = s2[q];
        }
      }
      __syncthreads();
      char* ab = (char*)A_lds;
#pragma unroll
      for (int q = 0; q < 4; ++q) {
        const int row = r0 + q;
        float a1 = 0.f, a2 = 0.f;
#pragma unroll
        for (int w = 0; w < 8; ++w) {
          a1 += st1[w][row];
          a2 += st2[w][row];
        }
        const float mu = a1 * (1.f / NC);
        const float rs = rsqrtf(a2 * (1.f / NC) - mu * mu + 1e-5f);
#pragma unroll
        for (int p = 0; p < 4; ++p) {
          float y = (acc[p][q] - mu) * rs * gv[layer][p] + btv[layer][p];
          y = y > 0.f ? y : 0.2f * y;
          const int cp = wave * 64 + p * 16 + (lane & 15);
          *(unsigned short*)(ab + row * 1024 +
                             ((cp * 2) ^ ((row & 7) << 4))) = f2bf(y);
        }
      }
      __syncthreads();
    } else {
      // bias, row-norm, scale by wno, store embo
      float s2[4];
#pragma unroll
      for (int q = 0; q < 4; ++q) s2[q] = 0.f;
#pragma unroll
      for (int p = 0; p < 4; ++p) {
#pragma unroll
        for (int q = 0; q < 4; ++q) {
          const float y = acc[p][q] + bsv[3][p];
          acc[p][q] = y;
          s2[q] = fmaf(y, y, s2[q]);
        }
      }
#pragma unroll
      for (int off = 1; off < 16; off <<= 1) {
#pragma unroll
        for (int q = 0; q < 4; ++q) s2[q] += __shfl_xor(s2[q], off);
      }
      if ((lane & 15) == 0) {
#pragma unroll
        for (int q = 0; q < 4; ++q) st2[wave][r0 + q] = s2[q];
      }
      __syncthreads();
#pragma unroll
      for (int q = 0; q < 4; ++q) {
        const int row = r0 + q;
        float a2 = 0.f;
#pragma unroll
        for (int w = 0; w < 8; ++w) a2 += st2[w][row];
        const float inv = wno[row] / (sqrtf(a2) + EPSN);
#pragma unroll
        for (int p = 0; p < 4; ++p) {
          const int cp = wave * 64 + p * 16 + (lane & 15);
          embo[((size_t)be * NF + row) * NC + cp] = acc[p][q] * inv;
        }
      }
    }
  }
}

// ---------------------------------------------------------------------------
// K4: the sequential scan, MFMA v9 (UNCHANGED from R13/R14 — known good).
// ---------------------------------------------------------------------------
__global__ __launch_bounds__(512) void k_scan(
    const float* __restrict__ weights, const float* __restrict__ biases,
    const float* __restrict__ leak, const float* __restrict__ embw,
    const unsigned short* __restrict__ Wmf, const float* __restrict__ bs,
    const float* __restrict__ g, const float* __restrict__ bt,
    float* __restrict__ olb, float* __restrict__ onb) {
  __shared__ __align__(16) unsigned short A_lds[16 * NC];     // 16KB
  __shared__ __align__(16) unsigned short B_lds[8][4][2048];  // 128KB
  __shared__ float ol_lds[SPB][NC];                           // 8KB
  __shared__ float redA[64];
  __shared__ float redB[32];
  __shared__ float st1[8][SPB], st2[8][SPB];
  __shared__ float lk_lds[SPB][NT];

  const int tid = threadIdx.x;
  const int wave = tid >> 6, lane = tid & 63;
  const int seq0 = blockIdx.x * SPB;

  {
    const int r = tid >> 7, tt = tid & 127;
    lk_lds[r][tt] = leak[(size_t)(seq0 + r) * NT + tt];
  }
  {
    unsigned* z = (unsigned*)(A_lds + SPB * NC);
    for (int i = tid; i < (16 - SPB) * NC / 2; i += 512) z[i] = 0u;
  }

  const int arow = lane & 15;
  const int kgrp = lane >> 4;
  const int abase = arow * (NC * 2);
  const int axor = (arow & 7) << 4;
  const int akoff = kgrp * 16;
  const bool crow = (kgrp == 0);

  float bsv[4][4], gv[3][4], btv[3][4];
#pragma unroll
  for (int p = 0; p < 4; ++p) {
    const int cp = wave * 64 + p * 16 + (lane & 15);
#pragma unroll
    for (int l = 0; l < 4; ++l) bsv[l][p] = bs[l * NC + cp];
#pragma unroll
    for (int l = 0; l < 3; ++l) {
      gv[l][p] = g[l * NC + cp];
      btv[l][p] = bt[l * NC + cp];
    }
  }
  const unsigned short* wfrag = Wmf + (size_t)wave * 32768 + lane * 8;

  auto issue_chunk = [&](int cc) {
    const int layer = cc >> 4, kt = cc & 15, slot = cc & 3;
#pragma unroll
    for (int p = 0; p < 4; ++p) {
      __builtin_amdgcn_global_load_lds(
          (const unsigned int*)(wfrag + (size_t)layer * 262144 +
                                (kt * 4 + p) * 512),
          (unsigned int*)&B_lds[wave][slot][p * 512], 16, 0, 0);
    }
  };

  float wpre[SPB], bpre[SPB], epre[SPB];
#pragma unroll
  for (int r = 0; r < SPB; ++r) {
    const size_t o = ((size_t)(seq0 + r) * NT) * NC + tid;
    wpre[r] = weights[o];
    bpre[r] = biases[o];
    epre[r] = embw[((size_t)(seq0 + r) * NF) * NC + tid];
  }

  __syncthreads();

  issue_chunk(0);
  issue_chunk(1);
  issue_chunk(2);

  float h[SPB], cn[SPB];
#pragma unroll
  for (int r = 0; r < SPB; ++r) { h[r] = 0.f; cn[r] = 0.f; }

#pragma unroll 1
  for (int t = 0; t < NT; ++t) {
    float hw[SPB];
    if (t < NF) {
#pragma unroll
      for (int r = 0; r < SPB; ++r) h[r] += epre[r];
      float v8[8], s8[8];
#pragma unroll
      for (int r = 0; r < SPB; ++r) {
        hw[r] = fmaf(h[r], wpre[r], bpre[r]);
        v8[r] = h[r] * h[r];
        v8[SPB + r] = hw[r] * hw[r];
      }
      if (t + 1 < NF) {
#pragma unroll
        for (int r = 0; r < SPB; ++r)
          epre[r] = embw[((size_t)(seq0 + r) * NF + t + 1) * NC + tid];
      }
      if (t + 1 < NT) {
#pragma unroll
        for (int r = 0; r < SPB; ++r) {
          const size_t o = ((size_t)(seq0 + r) * NT + t + 1) * NC + tid;
          wpre[r] = weights[o];
          bpre[r] = biases[o];
        }
      }
      blk_reduce1<8>(v8, s8, redA);
#pragma unroll
      for (int r = 0; r < SPB; ++r) {
        cn[r] = sqrtf(s8[r]);
        h[r] = hw[r] * (cn[r] / (sqrtf(s8[SPB + r]) + EPSN));
      }
    } else {
      float v4[SPB], s4[SPB];
#pragma unroll
      for (int r = 0; r < SPB; ++r) {
        hw[r] = fmaf(h[r], wpre[r], bpre[r]);
        v4[r] = hw[r] * hw[r];
      }
      if (t + 1 < NT) {
#pragma unroll
        for (int r = 0; r < SPB; ++r) {
          const size_t o = ((size_t)(seq0 + r) * NT + t + 1) * NC + tid;
          wpre[r] = weights[o];
          bpre[r] = biases[o];
        }
      }
      blk_reduce1<SPB>(v4, s4, redA);
#pragma unroll
      for (int r = 0; r < SPB; ++r)
        h[r] = hw[r] * (cn[r] / (sqrtf(s4[r]) + EPSN));
    }
    {
      char* ab = (char*)A_lds;
#pragma unroll
      for (int r = 0; r < SPB; ++r)
        *(unsigned short*)(ab + r * 1024 + ((tid * 2) ^ ((r & 7) << 4))) =
            f2bf(h[r]);
    }
    bar_nodrain();

#pragma unroll 1
    for (int layer = 0; layer < 4; ++layer) {
      f32x4 acc[4];
#pragma unroll
      for (int p = 0; p < 4; ++p) acc[p] = (f32x4){0.f, 0.f, 0.f, 0.f};
#pragma unroll
      for (int kt = 0; kt < 16; ++kt) {
        asm volatile("s_waitcnt vmcnt(8)" ::: "memory");
        const short8v a = *(const short8v*)((const char*)A_lds + abase +
                                            (((kt * 64) + akoff) ^ axor));
        const int slot = kt & 3;
#pragma unroll
        for (int p = 0; p < 4; ++p) {
          const short8v b =
              *(const short8v*)((const char*)&B_lds[wave][slot][0] + p * 1024 +
                                lane * 16);
          acc[p] =
              __builtin_amdgcn_mfma_f32_16x16x32_bf16(a, b, acc[p], 0, 0, 0);
        }
        issue_chunk((layer * 16 + kt + 3) & 63);
      }

      if (layer < 3) {
        float s1[SPB], s2[SPB];
#pragma unroll
        for (int q = 0; q < SPB; ++q) { s1[q] = 0.f; s2[q] = 0.f; }
#pragma unroll
        for (int p = 0; p < 4; ++p) {
#pragma unroll
          for (int q = 0; q < SPB; ++q) {
            const float y = acc[p][q] + bsv[layer][p];
            acc[p][q] = y;
            s1[q] += y;
            s2[q] = fmaf(y, y, s2[q]);
          }
        }
#pragma unroll
        for (int off = 1; off < 16; off <<= 1) {
#pragma unroll
          for (int q = 0; q < SPB; ++q) {
            s1[q] += __shfl_xor(s1[q], off);
            s2[q] += __shfl_xor(s2[q], off);
          }
        }
        if (lane == 0) {
#pragma unroll
          for (int q = 0; q < SPB; ++q) {
            st1[wave][q] = s1[q];
            st2[wave][q] = s2[q];
          }
        }
        bar_nodrain();
        float mu[SPB], rs[SPB];
#pragma unroll
        for (int q = 0; q < SPB; ++q) {
          float a1 = 0.f, a2 = 0.f;
#pragma unroll
          for (int w = 0; w < 8; ++w) {
            a1 += st1[w][q];
            a2 += st2[w][q];
          }
          mu[q] = a1 * (1.f / NC);
          rs[q] = rsqrtf(a2 * (1.f / NC) - mu[q] * mu[q] + 1e-5f);
        }
        if (crow) {
          char* ab = (char*)A_lds;
#pragma unroll
          for (int q = 0; q < SPB; ++q) {
#pragma unroll
            for (int p = 0; p < 4; ++p) {
              float y = (acc[p][q] - mu[q]) * rs[q] * gv[layer][p] +
                        btv[layer][p];
              y = y > 0.f ? y : 0.2f * y;
              const int cp = wave * 64 + p * 16 + (lane & 15);
              *(unsigned short*)(ab + q * 1024 +
                                 ((cp * 2) ^ ((q & 7) << 4))) = f2bf(y);
            }
          }
        }
        bar_nodrain();
      } else {
        float s2[SPB];
#pragma unroll
        for (int q = 0; q < SPB; ++q) s2[q] = 0.f;
#pragma unroll
        for (int p = 0; p < 4; ++p) {
#pragma unroll
          for (int q = 0; q < SPB; ++q) {
            const float y = acc[p][q] + bsv[3][p];
            acc[p][q] = y;
            s2[q] = fmaf(y, y, s2[q]);
          }
        }
#pragma unroll
        for (int off = 1; off < 16; off <<= 1) {
#pragma unroll
          for (int q = 0; q < SPB; ++q) s2[q] += __shfl_xor(s2[q], off);
        }
        if (lane == 0) {
#pragma unroll
          for (int q = 0; q < SPB; ++q) st2[wave][q] = s2[q];
        }
        if (crow) {
#pragma unroll
          for (int q = 0; q < SPB; ++q) {
#pragma unroll
            for (int p = 0; p < 4; ++p)
              ol_lds[q][wave * 64 + p * 16 + (lane & 15)] = acc[p][q];
          }
        }
        bar_nodrain();
        float sc[SPB], on[SPB];
#pragma unroll
        for (int r = 0; r < SPB; ++r) {
          float a2 = 0.f;
#pragma unroll
          for (int w = 0; w < 8; ++w) a2 += st2[w][r];
          const float no = sqrtf(a2);
          sc[r] = cn[r] * lk_lds[r][t] / (no + EPSN);
          on[r] = no * sc[r];
        }
        if (tid < SPB) onb[(size_t)(seq0 + tid) * NT + t] = on[tid];
        float v4[SPB], s4[SPB];
#pragma unroll
        for (int r = 0; r < SPB; ++r) {
          const float olv = ol_lds[r][tid] * sc[r];
          olb[((size_t)(seq0 + r) * NT + t) * NC + tid] = olv;
          h[r] -= olv;
          v4[r] = h[r] * h[r];
        }
        blk_reduce1<SPB>(v4, s4, redB);
#pragma unroll
        for (int r = 0; r < SPB; ++r) {
          h[r] *= (cn[r] - on[r]) / (sqrtf(s4[r]) + EPSN);
          cn[r] = fabsf(cn[r] - on[r]);  // ||h|| carried exactly
        }
      }
    }
  }
}

// ---------------------------------------------------------------------------
// K_zero: zero-init the output buffer.
// ---------------------------------------------------------------------------
__global__ __launch_bounds__(1024) void k_zero(float* __restrict__ out) {
  out[(size_t)blockIdx.x * 1024 + threadIdx.x] = 0.f;
}

// ---------------------------------------------------------------------------
// K5: batched out-MLP, MFMA + fused overlap-add (UNCHANGED from R13/R14).
// ---------------------------------------------------------------------------
__global__ __launch_bounds__(512) void k_out(
    const float* __restrict__ olb, const float* __restrict__ onb,
    const unsigned short* __restrict__ Wmf, const float* __restrict__ bs,
    const float* __restrict__ g, const float* __restrict__ bt,
    float* __restrict__ out) {
  __shared__ __align__(16) unsigned short A_lds[16 * NC];  // 16KB
  __shared__ float st1[8][16], st2[8][16];
  __shared__ float on_l[16];
  const int tid = threadIdx.x;
  const int wave = tid >> 6, lane = tid & 63;
  const int m0 = blockIdx.x * 16;
  const int arow = lane & 15;
  const int kgrp = lane >> 4;
  const int r0 = kgrp * 4;
  const int abase = arow * (NC * 2);
  const int axor = (arow & 7) << 4;
  const int akoff = kgrp * 16;

  float bsv[4][4], gv[3][4], btv[3][4], hamv[4];
#pragma unroll
  for (int p = 0; p < 4; ++p) {
    const int cp = wave * 64 + p * 16 + (lane & 15);
#pragma unroll
    for (int l = 0; l < 4; ++l) bsv[l][p] = bs[l * NC + cp];
#pragma unroll
    for (int l = 0; l < 3; ++l) {
      gv[l][p] = g[l * NC + cp];
      btv[l][p] = bt[l * NC + cp];
    }
    hamv[p] =
        0.54f - 0.46f * cosf(6.283185307179586f * (float)cp / (float)NC);
  }
  if (tid < 16) on_l[tid] = onb[m0 + tid];
  {
    char* ab = (char*)A_lds;
    for (int i = 0; i < 16; ++i) {
      const float v = olb[(size_t)(m0 + i) * NC + tid];
      *(unsigned short*)(ab + i * 1024 + ((tid * 2) ^ ((i & 7) << 4))) =
          f2bf(v);
    }
  }
  __syncthreads();

  const unsigned short* wfrag = Wmf + (size_t)wave * 32768 + lane * 8;

#pragma unroll 1
  for (int layer = 0; layer < 4; ++layer) {
    f32x4 acc[4];
#pragma unroll
    for (int p = 0; p < 4; ++p) acc[p] = (f32x4){0.f, 0.f, 0.f, 0.f};
#pragma unroll
    for (int kt = 0; kt < 16; ++kt) {
      const short8v a = *(const short8v*)((const char*)A_lds + abase +
                                          (((kt * 64) + akoff) ^ axor));
#pragma unroll
      for (int p = 0; p < 4; ++p) {
        const short8v b = *(const short8v*)(wfrag + (size_t)layer * 262144 +
                                            (kt * 4 + p) * 512);
        acc[p] = __builtin_amdgcn_mfma_f32_16x16x32_bf16(a, b, acc[p], 0, 0, 0);
      }
    }
    if (layer < 3) {
      float s1[4], s2[4];
#pragma unroll
      for (int q = 0; q < 4; ++q) { s1[q] = 0.f; s2[q] = 0.f; }
#pragma unroll
      for (int p = 0; p < 4; ++p) {
#pragma unroll
        for (int q = 0; q < 4; ++q) {
          const float y = acc[p][q] + bsv[layer][p];
          acc[p][q] = y;
          s1[q] += y;
          s2[q] = fmaf(y, y, s2[q]);
        }
      }
#pragma unroll
      for (int off = 1; off < 16; off <<= 1) {
#pragma unroll
        for (int q = 0; q < 4; ++q) {
          s1[q] += __shfl_xor(s1[q], off);
          s2[q] += __shfl_xor(s2[q], off);
        }
      }
      if ((lane & 15) == 0) {
#pragma unroll
        for (int q = 0; q < 4; ++q) {
          st1[wave][r0 + q] = s1[q];
          st2[wave][r0 + q] = s2[q];
        }
      }
      __syncthreads();
      char* ab = (char*)A_lds;
#pragma unroll
      for (int q = 0; q < 4; ++q) {
        const int row = r0 + q;
        float a1 = 0.f, a2 = 0.f;
#pragma unroll
        for (int w = 0; w < 8; ++w) {
          a1 += st1[w][row];
          a2 += st2[w][row];
        }
        const float mu = a1 * (1.f / NC);
        const float rs = rsqrtf(a2 * (1.f / NC) - mu * mu + 1e-5f);
#pragma unroll
        for (int p = 0; p < 4; ++p) {
          float y = (acc[p][q] - mu) * rs * gv[layer][p] + btv[layer][p];
          y = y > 0.f ? y : 0.2f * y;
          const int cp = wave * 64 + p * 16 + (lane & 15);
          *(unsigned short*)(ab + row * 1024 +
                             ((cp * 2) ^ ((row & 7) << 4))) = f2bf(y);
        }
      }
      __syncthreads();
    } else {
      float s2[4];
#pragma unroll
      for (int q = 0; q < 4; ++q) s2[q] = 0.f;
#pragma unroll
      for (int p = 0; p < 4; ++p) {
#pragma unroll
        for (int q = 0; q < 4; ++q) {
          float y = (acc[p][q] + bsv[3][p]) * hamv[p];
          acc[p][q] = y;
          s2[q] = fmaf(y, y, s2[q]);
        }
      }
#pragma unroll
      for (int off = 1; off < 16; off <<= 1) {
#pragma unroll
        for (int q = 0; q < 4; ++q) s2[q] += __shfl_xor(s2[q], off);
      }
      if ((lane & 15) == 0) {
#pragma unroll
        for (int q = 0; q < 4; ++q) st2[wave][r0 + q] = s2[q];
      }
      __syncthreads();
#pragma unroll
      for (int q = 0; q < 4; ++q) {
        const int row = r0 + q;
        const int gr = m0 + row;
        const int be = gr >> 7;
        const int tt = gr & 127;
        float a2 = 0.f;
#pragma unroll
        for (int w = 0; w < 8; ++w) a2 += st2[w][row];
        const float inv = on_l[row] / (sqrtf(a2) + EPSN);
#pragma unroll
        for (int p = 0; p < 4; ++p) {
          const int cp = wave * 64 + p * 16 + (lane & 15);
          const int s = tt * 256 + cp;
          if (s < NSAMP)
            atomicAdd(&out[(size_t)be * NSAMP + s], acc[p][q] * inv);
        }
      }
    }
  }
}

// ---------------------------------------------------------------------------
// Workspace (< 256 MiB): region A (deform->olb) 64 MiB, region B
// (wmf_def -> weights) 64 MiB, region C (biases) 64 MiB, small ~17 MiB.
// ---------------------------------------------------------------------------
extern "C" void kernel_launch(void* const* d_in, const int* in_sizes, int n_in,
                              void* d_out, int out_size, void* d_ws,
                              size_t ws_size, hipStream_t stream) {
  const float* embedding = (const float*)d_in[0];
  const float* impulse = (const float*)d_in[1];
  const float* W_def = (const float*)d_in[2];
  const float* b_def = (const float*)d_in[3];
  const float* W_w = (const float*)d_in[4];
  const float* b_w = (const float*)d_in[5];
  const float* W_b = (const float*)d_in[6];
  const float* b_b = (const float*)d_in[7];
  const float* W_l = (const float*)d_in[8];
  const float* b_l = (const float*)d_in[9];
  const float* Ws_imp = (const float*)d_in[10];
  const float* bs_imp = (const float*)d_in[11];
  const float* g_imp = (const float*)d_in[12];
  const float* bt_imp = (const float*)d_in[13];
  const float* Ws_lat = (const float*)d_in[14];
  const float* bs_lat = (const float*)d_in[15];
  const float* g_lat = (const float*)d_in[16];
  const float* bt_lat = (const float*)d_in[17];
  const float* Ws_out = (const float*)d_in[18];
  const float* bs_out = (const float*)d_in[19];
  const float* g_out = (const float*)d_in[20];
  const float* bt_out = (const float*)d_in[21];
  float* out = (float*)d_out;

  float* ws = (float*)d_ws;
  float* deform = ws;                  // region A (reused as olb)
  float* weights = deform + 16777216;  // region B (first used as wmf_def)
  float* biases = weights + 16777216;  // region C
  float* leakb = biases + 16777216;    // 32,768 f
  float* embw = leakb + 32768;         // 2,097,152 f
  float* onb = embw + 2097152;         // 32,768 f
  unsigned short* wmf = (unsigned short*)(onb + 32768);    // 1,048,576 us
  unsigned short* wmf_out = wmf + 1048576;                 // 1,048,576 us
  unsigned short* wmf_wb = wmf_out + 1048576;              // 524,288 us
  unsigned short* wmf_imp = wmf_wb + 524288;               // 1,048,576 us
  unsigned short* wmf_def = (unsigned short*)weights;      // alias region B
  float* olb = deform;                 // alias: deform dead after k_wb

  k_cvt<<<2048, 64, 0, stream>>>(Ws_lat, wmf);
  k_cvt<<<2048, 64, 0, stream>>>(Ws_out, wmf_out);
  k_cvt<<<512, 64, 0, stream>>>(W_w, wmf_wb);
  k_cvt<<<512, 64, 0, stream>>>(W_b, wmf_wb + 262144);
  k_cvt<<<2048, 64, 0, stream>>>(Ws_imp, wmf_imp);
  k_cvt_def<<<32768, 64, 0, stream>>>(W_def, wmf_def);
  k_deform<<<dim3(128, 16), 512, 0, stream>>>(embedding, wmf_def, b_def,
                                              deform);
  k_wb<<<2048, 512, 0, stream>>>(deform, wmf_wb, b_w, b_b, W_l, b_l,
                                 weights, biases, leakb);
  k_imp<<<256, 512, 0, stream>>>(impulse, wmf_imp, bs_imp, g_imp, bt_imp,
                                 embw);
  k_zero<<<(BE * NSAMP) / 1024, 1024, 0, stream>>>(out);
  k_scan<<<NSCAN, 512, 0, stream>>>(weights, biases, leakb, embw, wmf, bs_lat,
                                    g_lat, bt_lat, olb, onb);
  k_out<<<2048, 512, 0, stream>>>(olb, onb, wmf_out, bs_out, g_out, bt_out,
                                  out);
}